// Round 1
// baseline (8075.315 us; speedup 1.0000x reference)
//
#include <hip/hip_runtime.h>
#include <math.h>

// Problem constants
#define BB 4
#define CC 192
#define HH 96
#define WW 96
#define PP (HH*WW)          // 9216
#define C2 (2*CC)           // 384

__device__ __forceinline__ float sigmoidf_(float x) { return 1.f / (1.f + expf(-x)); }

// ---------------- conv 1x1:  out[b,co,p] = bias + sum_ci w[co,ci] * f(in[b,ci,p]) ----------
// grid: (9, COUT/16, B); block 256; each thread does 4 consecutive p (float4).
template<int CIN, bool RELU, bool HASB>
__global__ __launch_bounds__(256) void conv1x1_kernel(
    const float* __restrict__ in, const float* __restrict__ w,
    const float* __restrict__ bias, float* __restrict__ out,
    long in_bs, long out_bs)
{
    int b = blockIdx.z;
    int co0 = blockIdx.y * 16;
    int p = blockIdx.x * 1024 + threadIdx.x * 4;
    const float* ip = in + (long)b * in_bs + p;
    float4 acc[16];
#pragma unroll
    for (int j = 0; j < 16; ++j) acc[j] = make_float4(0.f, 0.f, 0.f, 0.f);
#pragma unroll 4
    for (int ci = 0; ci < CIN; ++ci) {
        float4 xv = *(const float4*)(ip + (long)ci * PP);
        if (RELU) {
            xv.x = fmaxf(xv.x, 0.f); xv.y = fmaxf(xv.y, 0.f);
            xv.z = fmaxf(xv.z, 0.f); xv.w = fmaxf(xv.w, 0.f);
        }
#pragma unroll
        for (int j = 0; j < 16; ++j) {
            float wv = w[(long)(co0 + j) * CIN + ci];
            acc[j].x += wv * xv.x; acc[j].y += wv * xv.y;
            acc[j].z += wv * xv.z; acc[j].w += wv * xv.w;
        }
    }
#pragma unroll
    for (int j = 0; j < 16; ++j) {
        if (HASB) {
            float bb = bias[co0 + j];
            acc[j].x += bb; acc[j].y += bb; acc[j].z += bb; acc[j].w += bb;
        }
        *(float4*)(out + (long)b * out_bs + (long)(co0 + j) * PP + p) = acc[j];
    }
}

// ---------------- grouped conv 3x3, groups=192, 2in->2out, pad 1 -------------------------
// grid: (36, 384, B); block 256
__global__ __launch_bounds__(256) void dwconv_kernel(
    const float* __restrict__ in, const float* __restrict__ w, float* __restrict__ out)
{
    int b = blockIdx.z, co = blockIdx.y;
    int p = blockIdx.x * 256 + threadIdx.x;
    int oy = p / WW, ox = p - oy * WW;
    int g = co >> 1;
    const float* w18 = w + (long)co * 18;
    float acc = 0.f;
#pragma unroll
    for (int i = 0; i < 2; ++i) {
        const float* ipl = in + ((long)(b * C2 + 2 * g + i)) * PP;
#pragma unroll
        for (int ky = 0; ky < 3; ++ky) {
            int yy = oy - 1 + ky;
            if ((unsigned)yy < (unsigned)HH) {
#pragma unroll
                for (int kx = 0; kx < 3; ++kx) {
                    int xx = ox - 1 + kx;
                    if ((unsigned)xx < (unsigned)WW)
                        acc += w18[i * 9 + ky * 3 + kx] * ipl[yy * WW + xx];
                }
            }
        }
    }
    out[((long)(b * C2 + co)) * PP + p] = acc;
}

// ---------------- avg pool 2x2 over implicit cat([q,y]) ----------------------------------
// grid: 13824; block 256; out (B,384,48,48)
__global__ __launch_bounds__(256) void avgpool_kernel(
    const float* __restrict__ qkv2, const float* __restrict__ y, float* __restrict__ out)
{
    int i = blockIdx.x * 256 + threadIdx.x;     // over 4*384*2304
    int bc = i / 2304; int r = i - bc * 2304;
    int b = bc / C2; int c = bc - b * C2;
    int oy = r / 48, ox = r - oy * 48;
    const float* base = (c < CC) ? qkv2 + ((long)(b * C2 + c)) * PP
                                 : y + ((long)(b * CC + (c - CC))) * PP;
    const float* ipl = base + (oy * 2) * WW + ox * 2;
    out[i] = 0.25f * (ipl[0] + ipl[1] + ipl[WW] + ipl[WW + 1]);
}

// ---------------- conv 3x3 valid on 48x48 -> 46x46, Cin=Cout=384 -------------------------
// grid: (96, B); block (8,8,4): tz = co within group of 4
__global__ __launch_bounds__(256) void conv48_kernel(
    const float* __restrict__ in, const float* __restrict__ w, float* __restrict__ out)
{
    __shared__ float tile[50 * 50];
    int b = blockIdx.y;
    int tz = threadIdx.z;
    int co = blockIdx.x * 4 + tz;
    int tx = threadIdx.x, ty = threadIdx.y;
    int tid = (tz * 8 + ty) * 8 + tx;
    int oy0 = ty * 6, ox0 = tx * 6;
    float acc[36];
#pragma unroll
    for (int i = 0; i < 36; ++i) acc[i] = 0.f;
    for (int ci = 0; ci < C2; ++ci) {
        __syncthreads();
        const float* ipl = in + ((long)(b * C2 + ci)) * 2304;
        for (int idx = tid; idx < 2500; idx += 256) {
            int r = idx / 50, c = idx - r * 50;
            tile[idx] = (r < 48 && c < 48) ? ipl[r * 48 + c] : 0.f;
        }
        __syncthreads();
        const float* wp = w + ((long)co * C2 + ci) * 9;
        float w9[9];
#pragma unroll
        for (int k = 0; k < 9; ++k) w9[k] = wp[k];
#pragma unroll
        for (int r = 0; r < 8; ++r) {
            float rv[8];
#pragma unroll
            for (int c = 0; c < 8; ++c) rv[c] = tile[(oy0 + r) * 50 + ox0 + c];
#pragma unroll
            for (int ky = 0; ky < 3; ++ky) {
                int oy = r - ky;
                if (oy < 0 || oy > 5) continue;
#pragma unroll
                for (int ox = 0; ox < 6; ++ox) {
#pragma unroll
                    for (int kx = 0; kx < 3; ++kx)
                        acc[oy * 6 + ox] += w9[ky * 3 + kx] * rv[ox + kx];
                }
            }
        }
    }
#pragma unroll
    for (int r = 0; r < 6; ++r) {
#pragma unroll
        for (int c = 0; c < 6; ++c) {
            int oy = oy0 + r, ox = ox0 + c;
            if (oy < 46 && ox < 46)
                out[((long)(b * C2 + co)) * 2116 + oy * 46 + ox] = acc[r * 6 + c];
        }
    }
}

// ---------------- conv 3x3 pad1 on 96x96, Cin=384, 2 co per block ------------------------
// MODE 0: plain, input = p0 (contiguous, 384ch, b-stride 384*PP)
// MODE 1: input is implicit cat(q from p0[b-stride 384*PP, ch 0..191], y from p1),
//         epilogue: out = acc * sigmoid(cat[b,co] + k2out[b,co, nearest])
// grid: (COUT/2, B); block (16,16)
template<int MODE>
__global__ __launch_bounds__(256) void conv96_kernel(
    const float* __restrict__ p0, const float* __restrict__ p1,
    const float* __restrict__ w, float* __restrict__ out,
    const float* __restrict__ k2out, int COUT)
{
    __shared__ float tile[98 * 98];
    int b = blockIdx.y;
    int co0 = blockIdx.x * 2;
    int tx = threadIdx.x, ty = threadIdx.y;
    int tid = ty * 16 + tx;
    int oy0 = ty * 6, ox0 = tx * 6;
    float acc0[36], acc1[36];
#pragma unroll
    for (int i = 0; i < 36; ++i) { acc0[i] = 0.f; acc1[i] = 0.f; }
    for (int ci = 0; ci < C2; ++ci) {
        const float* ipl;
        if (MODE == 1 && ci >= CC) ipl = p1 + ((long)(b * CC + (ci - CC))) * PP;
        else                        ipl = p0 + ((long)(b * C2 + ci)) * PP;
        __syncthreads();
        for (int idx = tid; idx < 9604; idx += 256) {
            int r = idx / 98, c = idx - r * 98;
            int sy = r - 1, sx = c - 1;
            tile[idx] = (sy >= 0 && sy < HH && sx >= 0 && sx < WW) ? ipl[sy * WW + sx] : 0.f;
        }
        __syncthreads();
        const float* wp0 = w + ((long)(co0)     * C2 + ci) * 9;
        const float* wp1 = w + ((long)(co0 + 1) * C2 + ci) * 9;
        float wa[9], wb[9];
#pragma unroll
        for (int k = 0; k < 9; ++k) { wa[k] = wp0[k]; wb[k] = wp1[k]; }
#pragma unroll
        for (int r = 0; r < 8; ++r) {
            float rv[8];
#pragma unroll
            for (int c = 0; c < 8; ++c) rv[c] = tile[(oy0 + r) * 98 + ox0 + c];
#pragma unroll
            for (int ky = 0; ky < 3; ++ky) {
                int oy = r - ky;
                if (oy < 0 || oy > 5) continue;
#pragma unroll
                for (int ox = 0; ox < 6; ++ox) {
#pragma unroll
                    for (int kx = 0; kx < 3; ++kx) {
                        float rvv = rv[ox + kx];
                        acc0[oy * 6 + ox] += wa[ky * 3 + kx] * rvv;
                        acc1[oy * 6 + ox] += wb[ky * 3 + kx] * rvv;
                    }
                }
            }
        }
    }
#pragma unroll
    for (int j = 0; j < 2; ++j) {
        int co = co0 + j;
        const float* gsrc = nullptr;
        if (MODE == 1) {
            gsrc = (co < CC) ? p0 + ((long)(b * C2 + co)) * PP
                             : p1 + ((long)(b * CC + (co - CC))) * PP;
        }
#pragma unroll
        for (int r = 0; r < 6; ++r) {
#pragma unroll
            for (int c = 0; c < 6; ++c) {
                int oy = oy0 + r, ox = ox0 + c;
                float v = (j == 0) ? acc0[r * 6 + c] : acc1[r * 6 + c];
                if (MODE == 1) {
                    int iy = (oy * 46) / 96, ix = (ox * 46) / 96;
                    float kv = k2out[((long)(b * C2 + co)) * 2116 + iy * 46 + ix];
                    v = v * sigmoidf_(gsrc[oy * WW + ox] + kv);
                }
                out[((long)b * COUT + co) * PP + oy * WW + ox] = v;
            }
        }
    }
}

// ---------------- k4 conv: sc (384ch) -> offset (18ch), 3x3 pad1 -------------------------
// grid: (36, B); block (16,16); each block does a 16x16 spatial tile for all 18 co
__global__ __launch_bounds__(256) void k4_kernel(
    const float* __restrict__ sc, const float* __restrict__ w, float* __restrict__ out)
{
    __shared__ float t[18][18];
    int b = blockIdx.y;
    int tileid = blockIdx.x;
    int ty0 = (tileid / 6) * 16, tx0 = (tileid - (tileid / 6) * 6) * 16;
    int oy = ty0 + threadIdx.y, ox = tx0 + threadIdx.x;
    int tid = threadIdx.y * 16 + threadIdx.x;
    float acc[18];
#pragma unroll
    for (int co = 0; co < 18; ++co) acc[co] = 0.f;
    for (int ci = 0; ci < C2; ++ci) {
        const float* ipl = sc + ((long)(b * C2 + ci)) * PP;
        __syncthreads();
        for (int idx = tid; idx < 324; idx += 256) {
            int r = idx / 18, c = idx - r * 18;
            int sy = ty0 + r - 1, sx = tx0 + c - 1;
            t[r][c] = (sy >= 0 && sy < HH && sx >= 0 && sx < WW) ? ipl[sy * WW + sx] : 0.f;
        }
        __syncthreads();
        float rv[9];
#pragma unroll
        for (int ky = 0; ky < 3; ++ky)
#pragma unroll
            for (int kx = 0; kx < 3; ++kx)
                rv[ky * 3 + kx] = t[threadIdx.y + ky][threadIdx.x + kx];
        const float* wp = w + (long)ci * 9;
#pragma unroll
        for (int co = 0; co < 18; ++co) {
            const float* wc = wp + (long)co * (C2 * 9);
#pragma unroll
            for (int k = 0; k < 9; ++k) acc[co] += wc[k] * rv[k];
        }
    }
#pragma unroll
    for (int co = 0; co < 18; ++co)
        out[((long)(b * 18 + co)) * PP + oy * WW + ox] = acc[co];
}

// ---------------- deformable conv ---------------------------------------------------------
// grid: (36, 8, B); block 256; one thread = one pixel, one group (24 out channels)
__global__ __launch_bounds__(256) void deform_kernel(
    const float* __restrict__ q, const float* __restrict__ offs,
    const float* __restrict__ w, const float* __restrict__ bias, float* __restrict__ out)
{
    int b = blockIdx.z, g = blockIdx.y;
    int p = blockIdx.x * 256 + threadIdx.x;
    int oy = p / WW, ox = p - oy * WW;
    const float* ob = offs + (long)b * 18 * PP;
    float acc[24];
#pragma unroll
    for (int o = 0; o < 24; ++o) acc[o] = 0.f;
    for (int k = 0; k < 9; ++k) {
        float dy = ob[(2 * k) * PP + p];
        float dx = ob[(2 * k + 1) * PP + p];
        float mk = sigmoidf_(ob[k * PP + p]);
        float py = dy + (float)(oy - 1 + k / 3);
        float px = dx + (float)(ox - 1 + (k % 3));
        float fy = floorf(py), fx = floorf(px);
        int y0 = (int)fy, x0 = (int)fx;
        float ly = py - fy, lx = px - fx;
        float w00 = (1.f - ly) * (1.f - lx), w01 = (1.f - ly) * lx;
        float w10 = ly * (1.f - lx), w11 = ly * lx;
        bool vy0 = (y0 >= 0 && y0 <= HH - 1), vy1 = (y0 + 1 >= 0 && y0 + 1 <= HH - 1);
        bool vx0 = (x0 >= 0 && x0 <= WW - 1), vx1 = (x0 + 1 >= 0 && x0 + 1 <= WW - 1);
        w00 *= (vy0 && vx0) ? 1.f : 0.f;
        w01 *= (vy0 && vx1) ? 1.f : 0.f;
        w10 *= (vy1 && vx0) ? 1.f : 0.f;
        w11 *= (vy1 && vx1) ? 1.f : 0.f;
        int y0c = min(max(y0, 0), HH - 1), y1c = min(max(y0 + 1, 0), HH - 1);
        int x0c = min(max(x0, 0), WW - 1), x1c = min(max(x0 + 1, 0), WW - 1);
        int i00 = y0c * WW + x0c, i01 = y0c * WW + x1c;
        int i10 = y1c * WW + x0c, i11 = y1c * WW + x1c;
        float vals[24];
#pragma unroll
        for (int ci = 0; ci < 24; ++ci) {
            const float* qp = q + ((long)(b * C2 + g * 24 + ci)) * PP;
            vals[ci] = (w00 * qp[i00] + w01 * qp[i01] + w10 * qp[i10] + w11 * qp[i11]) * mk;
        }
        const float* wg = w + (long)g * 24 * 216 + k;
#pragma unroll
        for (int o = 0; o < 24; ++o) {
            const float* wr = wg + (long)o * 216;
            float s = acc[o];
#pragma unroll
            for (int ci = 0; ci < 24; ++ci) s += wr[ci * 9] * vals[ci];
            acc[o] = s;
        }
    }
#pragma unroll
    for (int o = 0; o < 24; ++o)
        out[((long)(b * CC + g * 24 + o)) * PP + p] = acc[o] + bias[g * 24 + o];
}

// ---------------- L2 norms of q and k rows -----------------------------------------------
// grid: (192, B, 2); block 256
__global__ __launch_bounds__(256) void norm_kernel(
    const float* __restrict__ q, const float* __restrict__ kb, float* __restrict__ norms)
{
    int c = blockIdx.x, b = blockIdx.y, which = blockIdx.z;
    const float* src = (which == 0) ? q + ((long)(b * C2 + c)) * PP
                                    : kb + ((long)(b * CC + c)) * PP;
    float s = 0.f;
    for (int n = threadIdx.x * 4; n < PP; n += 1024) {
        float4 v = *(const float4*)(src + n);
        s += v.x * v.x + v.y * v.y + v.z * v.z + v.w * v.w;
    }
    __shared__ float red[256];
    red[threadIdx.x] = s;
    __syncthreads();
    for (int st = 128; st > 0; st >>= 1) {
        if (threadIdx.x < st) red[threadIdx.x] += red[threadIdx.x + st];
        __syncthreads();
    }
    if (threadIdx.x == 0)
        norms[((long)which * BB + b) * CC + c] = fmaxf(sqrtf(red[0]), 1e-12f);
}

// ---------------- attention logits + softmax ---------------------------------------------
// grid: (24, 8, B); block 256; one block computes attn[b,h,c,:]
__global__ __launch_bounds__(256) void attn_kernel(
    const float* __restrict__ q, const float* __restrict__ kb,
    const float* __restrict__ norms, const float* __restrict__ temp,
    float* __restrict__ attn)
{
    int c = blockIdx.x, h = blockIdx.y, b = blockIdx.z;
    const float* qp = q + ((long)(b * C2 + h * 24 + c)) * PP;
    const float* kbase = kb + ((long)(b * CC + h * 24)) * PP;
    float part[24];
#pragma unroll
    for (int d = 0; d < 24; ++d) part[d] = 0.f;
    for (int n = threadIdx.x * 4; n < PP; n += 1024) {
        float4 qv = *(const float4*)(qp + n);
#pragma unroll
        for (int d = 0; d < 24; ++d) {
            float4 kv = *(const float4*)(kbase + (long)d * PP + n);
            part[d] += qv.x * kv.x + qv.y * kv.y + qv.z * kv.z + qv.w * kv.w;
        }
    }
    __shared__ float lred[4][24];
    __shared__ float logits[24];
    int lane = threadIdx.x & 63, wv = threadIdx.x >> 6;
#pragma unroll
    for (int d = 0; d < 24; ++d) {
        float x = part[d];
        for (int off = 32; off > 0; off >>= 1) x += __shfl_down(x, off, 64);
        if (lane == 0) lred[wv][d] = x;
    }
    __syncthreads();
    if (threadIdx.x < 24) {
        int d = threadIdx.x;
        float tot = lred[0][d] + lred[1][d] + lred[2][d] + lred[3][d];
        float nq = norms[(long)b * CC + h * 24 + c];
        float nk = norms[(long)(BB + b) * CC + h * 24 + d];
        logits[d] = tot / (nq * nk) * temp[h];
    }
    __syncthreads();
    if (threadIdx.x < 24) {
        int d = threadIdx.x;
        float mx = -3.4e38f;
#pragma unroll
        for (int j = 0; j < 24; ++j) mx = fmaxf(mx, logits[j]);
        float sum = 0.f;
#pragma unroll
        for (int j = 0; j < 24; ++j) sum += expf(logits[j] - mx);
        attn[(((long)(b * 8 + h) * 24) + c) * 24 + d] = expf(logits[d] - mx) / sum;
    }
}

// ---------------- attn @ v ----------------------------------------------------------------
// grid: (9, 192, B); block 256 (float4 over n)
__global__ __launch_bounds__(256) void attn_apply_kernel(
    const float* __restrict__ attn, const float* __restrict__ qkv2, float* __restrict__ out)
{
    int b = blockIdx.z, ch = blockIdx.y;
    int h = ch / 24, c = ch - h * 24;
    int n = blockIdx.x * 1024 + threadIdx.x * 4;
    const float* arow = attn + (((long)(b * 8 + h) * 24) + c) * 24;
    const float* vbase = qkv2 + ((long)(b * C2) + CC + h * 24) * PP;
    float4 acc = make_float4(0.f, 0.f, 0.f, 0.f);
#pragma unroll
    for (int d = 0; d < 24; ++d) {
        float a = arow[d];
        float4 vv = *(const float4*)(vbase + (long)d * PP + n);
        acc.x += a * vv.x; acc.y += a * vv.y; acc.z += a * vv.z; acc.w += a * vv.w;
    }
    *(float4*)(out + ((long)(b * CC + ch)) * PP + n) = acc;
}

// =========================================================================================
extern "C" void kernel_launch(void* const* d_in, const int* in_sizes, int n_in,
                              void* d_out, int out_size, void* d_ws, size_t ws_size,
                              hipStream_t stream)
{
    const float* x          = (const float*)d_in[0];
    const float* y          = (const float*)d_in[1];
    const float* temp       = (const float*)d_in[2];
    const float* qkv_w      = (const float*)d_in[3];
    const float* qkv_conv_w = (const float*)d_in[4];
    const float* proj_w     = (const float*)d_in[5];
    const float* k2_w       = (const float*)d_in[6];
    const float* k3_w       = (const float*)d_in[7];
    const float* k4_w       = (const float*)d_in[8];
    const float* deform_w   = (const float*)d_in[9];
    const float* deform_b   = (const float*)d_in[10];
    const float* pw_w       = (const float*)d_in[11];
    const float* pw_b       = (const float*)d_in[12];

    float* ws = (float*)d_ws;
    const long SZ_FULL = (long)BB * C2 * PP;     // 14,155,776
    const long SZ_HALF = (long)BB * CC * PP;     //  7,077,888
    float* bufA   = ws;                               // qkv1 / sc / (kbuf | feat,attnout)
    float* qkv2   = ws + SZ_FULL;
    float* pooled = ws + 2 * SZ_FULL;                 // 3,538,944
    float* k2out  = pooled + (long)BB * C2 * 2304;    // 3,250,176
    float* offs   = k2out + (long)BB * C2 * 2116;     //   663,552
    float* norms  = offs + (long)BB * 18 * PP;        //     1,536
    float* attnm  = norms + 2 * BB * CC;              //    18,432

    float* qkv1    = bufA;
    float* sc      = bufA;
    float* kbuf    = bufA;              // first half, written after sc is dead
    float* feat    = bufA + SZ_HALF;    // second half, written after sc is dead
    float* attnout = bufA + SZ_HALF;    // reuses feat space after k is computed

    // 1. qkv = conv1x1(x, qkv_w): (B,384,96,96)
    conv1x1_kernel<CC, false, false><<<dim3(9, 24, BB), 256, 0, stream>>>(
        x, qkv_w, nullptr, qkv1, (long)CC * PP, (long)C2 * PP);
    // 2. qkv = grouped 3x3 (groups=192)
    dwconv_kernel<<<dim3(36, C2, BB), 256, 0, stream>>>(qkv1, qkv_conv_w, qkv2);
    // 3. pooled = avgpool2(cat[q,y])
    avgpool_kernel<<<dim3(13824), 256, 0, stream>>>(qkv2, y, pooled);
    // 4. k2out = conv3x3 valid (48->46)
    conv48_kernel<<<dim3(96, BB), dim3(8, 8, 4), 0, stream>>>(pooled, k2_w, k2out);
    // 5. sc = conv3x3(cat, k3_w) * sigmoid(cat + resize(k2out))
    conv96_kernel<1><<<dim3(C2 / 2, BB), dim3(16, 16), 0, stream>>>(
        qkv2, y, k3_w, sc, k2out, C2);
    // 6. offset = conv3x3(sc, k4_w): (B,18,96,96)
    k4_kernel<<<dim3(36, BB), dim3(16, 16), 0, stream>>>(sc, k4_w, offs);
    // 7. feat = deform_conv(q, offset, mask, deform_w, deform_b)
    deform_kernel<<<dim3(36, 8, BB), 256, 0, stream>>>(qkv2, offs, deform_w, deform_b, feat);
    // 8. k = conv1x1(relu(feat), pw_w) + pw_b
    conv1x1_kernel<CC, true, true><<<dim3(9, 12, BB), 256, 0, stream>>>(
        feat, pw_w, pw_b, kbuf, (long)CC * PP, (long)CC * PP);
    // 9. norms of q-heads and k-heads
    norm_kernel<<<dim3(CC, BB, 2), 256, 0, stream>>>(qkv2, kbuf, norms);
    // 10. attn = softmax(qh.khT / (|q||k|) * temp)
    attn_kernel<<<dim3(24, 8, BB), 256, 0, stream>>>(qkv2, kbuf, norms, temp, attnm);
    // 11. attnout = attn @ vh
    attn_apply_kernel<<<dim3(9, CC, BB), 256, 0, stream>>>(attnm, qkv2, attnout);
    // 12. out = conv1x1(attnout, proj_w)
    conv1x1_kernel<CC, false, false><<<dim3(9, 12, BB), 256, 0, stream>>>(
        attnout, proj_w, nullptr, (float*)d_out, (long)CC * PP, (long)CC * PP);
}

// Round 2
// 3647.728 us; speedup vs baseline: 2.2138x; 2.2138x over previous
//
#include <hip/hip_runtime.h>
#include <math.h>

// Problem constants
#define BB 4
#define CC 192
#define HH 96
#define WW 96
#define PP (HH*WW)          // 9216
#define C2 (2*CC)           // 384

typedef unsigned short ushort_t;
typedef __bf16 bf16_t;
typedef bf16_t bf16x8 __attribute__((ext_vector_type(8)));
typedef float floatx16 __attribute__((ext_vector_type(16)));

__device__ __forceinline__ float sigmoidf_(float x) { return 1.f / (1.f + expf(-x)); }

__device__ __forceinline__ ushort_t f2bf(float f) {
    unsigned u = __builtin_bit_cast(unsigned, f);
    unsigned r = (u + 0x7fffu + ((u >> 16) & 1u)) >> 16;
    return (ushort_t)r;
}

// ---------------- conv 1x1:  out[b,co,p] = bias + sum_ci w[co,ci] * f(in[b,ci,p]) ----------
template<int CIN, bool RELU, bool HASB>
__global__ __launch_bounds__(256) void conv1x1_kernel(
    const float* __restrict__ in, const float* __restrict__ w,
    const float* __restrict__ bias, float* __restrict__ out,
    long in_bs, long out_bs)
{
    int b = blockIdx.z;
    int co0 = blockIdx.y * 16;
    int p = blockIdx.x * 1024 + threadIdx.x * 4;
    const float* ip = in + (long)b * in_bs + p;
    float4 acc[16];
#pragma unroll
    for (int j = 0; j < 16; ++j) acc[j] = make_float4(0.f, 0.f, 0.f, 0.f);
#pragma unroll 4
    for (int ci = 0; ci < CIN; ++ci) {
        float4 xv = *(const float4*)(ip + (long)ci * PP);
        if (RELU) {
            xv.x = fmaxf(xv.x, 0.f); xv.y = fmaxf(xv.y, 0.f);
            xv.z = fmaxf(xv.z, 0.f); xv.w = fmaxf(xv.w, 0.f);
        }
#pragma unroll
        for (int j = 0; j < 16; ++j) {
            float wv = w[(long)(co0 + j) * CIN + ci];
            acc[j].x += wv * xv.x; acc[j].y += wv * xv.y;
            acc[j].z += wv * xv.z; acc[j].w += wv * xv.w;
        }
    }
#pragma unroll
    for (int j = 0; j < 16; ++j) {
        if (HASB) {
            float bb = bias[co0 + j];
            acc[j].x += bb; acc[j].y += bb; acc[j].z += bb; acc[j].w += bb;
        }
        *(float4*)(out + (long)b * out_bs + (long)(co0 + j) * PP + p) = acc[j];
    }
}

// ---------------- grouped conv 3x3, groups=192, 2in->2out, pad 1 -------------------------
__global__ __launch_bounds__(256) void dwconv_kernel(
    const float* __restrict__ in, const float* __restrict__ w, float* __restrict__ out)
{
    int b = blockIdx.z, co = blockIdx.y;
    int p = blockIdx.x * 256 + threadIdx.x;
    int oy = p / WW, ox = p - oy * WW;
    int g = co >> 1;
    const float* w18 = w + (long)co * 18;
    float acc = 0.f;
#pragma unroll
    for (int i = 0; i < 2; ++i) {
        const float* ipl = in + ((long)(b * C2 + 2 * g + i)) * PP;
#pragma unroll
        for (int ky = 0; ky < 3; ++ky) {
            int yy = oy - 1 + ky;
            if ((unsigned)yy < (unsigned)HH) {
#pragma unroll
                for (int kx = 0; kx < 3; ++kx) {
                    int xx = ox - 1 + kx;
                    if ((unsigned)xx < (unsigned)WW)
                        acc += w18[i * 9 + ky * 3 + kx] * ipl[yy * WW + xx];
                }
            }
        }
    }
    out[((long)(b * C2 + co)) * PP + p] = acc;
}

// ---------------- avg pool 2x2 over implicit cat([q,y]) ----------------------------------
__global__ __launch_bounds__(256) void avgpool_kernel(
    const float* __restrict__ qkv2, const float* __restrict__ y, float* __restrict__ out)
{
    int i = blockIdx.x * 256 + threadIdx.x;
    int bc = i / 2304; int r = i - bc * 2304;
    int b = bc / C2; int c = bc - b * C2;
    int oy = r / 48, ox = r - oy * 48;
    const float* base = (c < CC) ? qkv2 + ((long)(b * C2 + c)) * PP
                                 : y + ((long)(b * CC + (c - CC))) * PP;
    const float* ipl = base + (oy * 2) * WW + ox * 2;
    out[i] = 0.25f * (ipl[0] + ipl[1] + ipl[WW] + ipl[WW + 1]);
}

// ---------------- conv 3x3 valid on 48x48 -> 46x46, Cin=Cout=384 -------------------------
__global__ __launch_bounds__(256) void conv48_kernel(
    const float* __restrict__ in, const float* __restrict__ w, float* __restrict__ out)
{
    __shared__ float tile[50 * 50];
    int b = blockIdx.y;
    int tz = threadIdx.z;
    int co = blockIdx.x * 4 + tz;
    int tx = threadIdx.x, ty = threadIdx.y;
    int tid = (tz * 8 + ty) * 8 + tx;
    int oy0 = ty * 6, ox0 = tx * 6;
    float acc[36];
#pragma unroll
    for (int i = 0; i < 36; ++i) acc[i] = 0.f;
    for (int ci = 0; ci < C2; ++ci) {
        __syncthreads();
        const float* ipl = in + ((long)(b * C2 + ci)) * 2304;
        for (int idx = tid; idx < 2500; idx += 256) {
            int r = idx / 50, c = idx - r * 50;
            tile[idx] = (r < 48 && c < 48) ? ipl[r * 48 + c] : 0.f;
        }
        __syncthreads();
        const float* wp = w + ((long)co * C2 + ci) * 9;
        float w9[9];
#pragma unroll
        for (int k = 0; k < 9; ++k) w9[k] = wp[k];
#pragma unroll
        for (int r = 0; r < 8; ++r) {
            float rv[8];
#pragma unroll
            for (int c = 0; c < 8; ++c) rv[c] = tile[(oy0 + r) * 50 + ox0 + c];
#pragma unroll
            for (int ky = 0; ky < 3; ++ky) {
                int oy = r - ky;
                if (oy < 0 || oy > 5) continue;
#pragma unroll
                for (int ox = 0; ox < 6; ++ox) {
#pragma unroll
                    for (int kx = 0; kx < 3; ++kx)
                        acc[oy * 6 + ox] += w9[ky * 3 + kx] * rv[ox + kx];
                }
            }
        }
    }
#pragma unroll
    for (int r = 0; r < 6; ++r) {
#pragma unroll
        for (int c = 0; c < 6; ++c) {
            int oy = oy0 + r, ox = ox0 + c;
            if (oy < 46 && ox < 46)
                out[((long)(b * C2 + co)) * 2116 + oy * 46 + ox] = acc[r * 6 + c];
        }
    }
}

// ---------------- cvt_cat: catb[b][px][ci] bf16 from cat(q=qkv2[0:192], y) ----------------
// grid (144, BB); block 256; tile = 64 px x 384 ci with LDS transpose
__global__ __launch_bounds__(256) void cvt_cat_kernel(
    const float* __restrict__ qkv2, const float* __restrict__ y, ushort_t* __restrict__ catb)
{
    __shared__ __align__(16) ushort_t sT[64 * 392];
    int b = blockIdx.y;
    int px0 = blockIdx.x * 64;
    int t = threadIdx.x;
    for (int idx = t; idx < 384 * 64; idx += 256) {
        int ci = idx >> 6, px = idx & 63;
        const float* src = (ci < CC) ? qkv2 + ((long)(b * C2 + ci)) * PP
                                     : y + ((long)(b * CC + ci - CC)) * PP;
        sT[px * 392 + ci] = f2bf(src[px0 + px]);
    }
    __syncthreads();
    int px = t >> 2, qr = t & 3;
    ushort_t* dst = catb + ((long)b * PP + px0 + px) * C2 + qr * 96;
    const ushort_t* srcl = sT + px * 392 + qr * 96;
#pragma unroll
    for (int k = 0; k < 96; k += 8)
        *(uint4*)(dst + k) = *(const uint4*)(srcl + k);
}

// ---------------- prep_w: Wb[tap][co][ci] bf16 from k3_w[co][ci][tap] ---------------------
__global__ __launch_bounds__(256) void prep_w_kernel(
    const float* __restrict__ w, ushort_t* __restrict__ wb)
{
    int i = blockIdx.x * 256 + threadIdx.x;        // tap*384*384 + co*384 + ci
    int ci = i % 384; int r = i / 384; int co = r % 384; int tap = r / 384;
    wb[i] = f2bf(w[((long)co * 384 + ci) * 9 + tap]);
}

// ---------------- conv96 MFMA: sc = conv3x3(cat) * sigmoid(cat + resize(k2out)) ----------
// grid (48 row-pairs, 3 co-groups, B); block 256 (4 waves)
// block: M=128 co x N=192 px (2 rows x 96); wave: 2 co-tiles x 3 n-tiles of 32
__global__ __launch_bounds__(256) void conv96_mfma_kernel(
    const ushort_t* __restrict__ catb, const ushort_t* __restrict__ wb,
    const float* __restrict__ qkv2, const float* __restrict__ yy,
    const float* __restrict__ k2out, float* __restrict__ out)
{
    __shared__ __align__(16) ushort_t sB[392 * 20];   // [r*98+col][20], rows y0-1..y0+2
    __shared__ __align__(16) ushort_t sW[1152 * 20];  // [tap*128+co][20]
    int b = blockIdx.z;
    int co0 = blockIdx.y * 128;
    int y0 = blockIdx.x * 2;
    int t = threadIdx.x;
    int w = t >> 6, lane = t & 63;
    int n = lane & 31, q = lane >> 5;
    int wc = w & 1;     // co-half
    int wr = w >> 1;    // row within pair

    floatx16 acc[2][3];
#pragma unroll
    for (int a = 0; a < 2; ++a)
#pragma unroll
        for (int xg = 0; xg < 3; ++xg) acc[a][xg] = (floatx16)(0.f);

    const ushort_t* catb_b = catb + (long)b * PP * C2;

    for (int ci0 = 0; ci0 < C2; ci0 += 16) {
        __syncthreads();
        // stage input: 392 cells x 16 ci (32 B each)
        for (int c = t; c < 392; c += 256) {
            int r = c / 98, col = c - r * 98;
            int iy = y0 - 1 + r, ix = col - 1;
            ushort_t* d = sB + c * 20;
            if (iy >= 0 && iy < HH && ix >= 0 && ix < WW) {
                const ushort_t* s = catb_b + ((long)(iy * WW + ix)) * C2 + ci0;
                uint4 v0 = *(const uint4*)(s);
                uint4 v1 = *(const uint4*)(s + 8);
                *(uint2*)(d + 0)  = make_uint2(v0.x, v0.y);
                *(uint2*)(d + 4)  = make_uint2(v0.z, v0.w);
                *(uint2*)(d + 8)  = make_uint2(v1.x, v1.y);
                *(uint2*)(d + 12) = make_uint2(v1.z, v1.w);
            } else {
                uint2 z = make_uint2(0u, 0u);
                *(uint2*)(d + 0) = z; *(uint2*)(d + 4) = z;
                *(uint2*)(d + 8) = z; *(uint2*)(d + 12) = z;
            }
        }
        // stage weights: 1152 cells x 16 ci
        for (int c = t; c < 1152; c += 256) {
            int tap = c >> 7, co = c & 127;
            const ushort_t* s = wb + ((long)(tap * C2 + co0 + co)) * C2 + ci0;
            ushort_t* d = sW + c * 20;
            uint4 v0 = *(const uint4*)(s);
            uint4 v1 = *(const uint4*)(s + 8);
            *(uint2*)(d + 0)  = make_uint2(v0.x, v0.y);
            *(uint2*)(d + 4)  = make_uint2(v0.z, v0.w);
            *(uint2*)(d + 8)  = make_uint2(v1.x, v1.y);
            *(uint2*)(d + 12) = make_uint2(v1.z, v1.w);
        }
        __syncthreads();
#pragma unroll
        for (int ky = 0; ky < 3; ++ky) {
#pragma unroll
            for (int kx = 0; kx < 3; ++kx) {
                int tap = ky * 3 + kx;
                bf16x8 af[2], bfm[3];
#pragma unroll
                for (int a = 0; a < 2; ++a) {
                    const ushort_t* p = sW + (tap * 128 + (wc * 2 + a) * 32 + n) * 20 + q * 8;
                    uint2 lo = *(const uint2*)(p);
                    uint2 hi = *(const uint2*)(p + 4);
                    af[a] = __builtin_bit_cast(bf16x8, make_uint4(lo.x, lo.y, hi.x, hi.y));
                }
#pragma unroll
                for (int xg = 0; xg < 3; ++xg) {
                    int col = xg * 32 + n + kx;
                    const ushort_t* p = sB + ((wr + ky) * 98 + col) * 20 + q * 8;
                    uint2 lo = *(const uint2*)(p);
                    uint2 hi = *(const uint2*)(p + 4);
                    bfm[xg] = __builtin_bit_cast(bf16x8, make_uint4(lo.x, lo.y, hi.x, hi.y));
                }
#pragma unroll
                for (int a = 0; a < 2; ++a)
#pragma unroll
                    for (int xg = 0; xg < 3; ++xg)
                        acc[a][xg] = __builtin_amdgcn_mfma_f32_32x32x16_bf16(
                            af[a], bfm[xg], acc[a][xg], 0, 0, 0);
            }
        }
    }

    // epilogue: out = acc * sigmoid(cat + nearest(k2out))
    int yl = y0 + wr;
    int iy46 = (yl * 46) / 96;
#pragma unroll
    for (int a = 0; a < 2; ++a) {
        int cobase = co0 + (wc * 2 + a) * 32;
#pragma unroll
        for (int xg = 0; xg < 3; ++xg) {
#pragma unroll
            for (int r = 0; r < 16; ++r) {
                int row = (r & 3) + 8 * (r >> 2) + 4 * q;
                int co = cobase + row;
                int x = xg * 32 + n;
                const float* gsrc = (co < CC) ? qkv2 + ((long)(b * C2 + co)) * PP
                                              : yy + ((long)(b * CC + co - CC)) * PP;
                int ix46 = (x * 46) / 96;
                float kv = k2out[((long)(b * C2 + co)) * 2116 + iy46 * 46 + ix46];
                float g = gsrc[yl * WW + x] + kv;
                float v = acc[a][xg][r] * sigmoidf_(g);
                out[((long)(b * C2 + co)) * PP + yl * WW + x] = v;
            }
        }
    }
}

// ---------------- k4 conv: sc (384ch) -> offset (18ch), 3x3 pad1 -------------------------
__global__ __launch_bounds__(256) void k4_kernel(
    const float* __restrict__ sc, const float* __restrict__ w, float* __restrict__ out)
{
    __shared__ float t[18][18];
    int b = blockIdx.y;
    int tileid = blockIdx.x;
    int ty0 = (tileid / 6) * 16, tx0 = (tileid - (tileid / 6) * 6) * 16;
    int oy = ty0 + threadIdx.y, ox = tx0 + threadIdx.x;
    int tid = threadIdx.y * 16 + threadIdx.x;
    float acc[18];
#pragma unroll
    for (int co = 0; co < 18; ++co) acc[co] = 0.f;
    for (int ci = 0; ci < C2; ++ci) {
        const float* ipl = sc + ((long)(b * C2 + ci)) * PP;
        __syncthreads();
        for (int idx = tid; idx < 324; idx += 256) {
            int r = idx / 18, c = idx - r * 18;
            int sy = ty0 + r - 1, sx = tx0 + c - 1;
            t[r][c] = (sy >= 0 && sy < HH && sx >= 0 && sx < WW) ? ipl[sy * WW + sx] : 0.f;
        }
        __syncthreads();
        float rv[9];
#pragma unroll
        for (int ky = 0; ky < 3; ++ky)
#pragma unroll
            for (int kx = 0; kx < 3; ++kx)
                rv[ky * 3 + kx] = t[threadIdx.y + ky][threadIdx.x + kx];
        const float* wp = w + (long)ci * 9;
#pragma unroll
        for (int co = 0; co < 18; ++co) {
            const float* wc = wp + (long)co * (C2 * 9);
#pragma unroll
            for (int k = 0; k < 9; ++k) acc[co] += wc[k] * rv[k];
        }
    }
#pragma unroll
    for (int co = 0; co < 18; ++co)
        out[((long)(b * 18 + co)) * PP + oy * WW + ox] = acc[co];
}

// ---------------- deformable conv ---------------------------------------------------------
__global__ __launch_bounds__(256) void deform_kernel(
    const float* __restrict__ q, const float* __restrict__ offs,
    const float* __restrict__ w, const float* __restrict__ bias, float* __restrict__ out)
{
    int b = blockIdx.z, g = blockIdx.y;
    int p = blockIdx.x * 256 + threadIdx.x;
    int oy = p / WW, ox = p - oy * WW;
    const float* ob = offs + (long)b * 18 * PP;
    float acc[24];
#pragma unroll
    for (int o = 0; o < 24; ++o) acc[o] = 0.f;
    for (int k = 0; k < 9; ++k) {
        float dy = ob[(2 * k) * PP + p];
        float dx = ob[(2 * k + 1) * PP + p];
        float mk = sigmoidf_(ob[k * PP + p]);
        float py = dy + (float)(oy - 1 + k / 3);
        float px = dx + (float)(ox - 1 + (k % 3));
        float fy = floorf(py), fx = floorf(px);
        int y0 = (int)fy, x0 = (int)fx;
        float ly = py - fy, lx = px - fx;
        float w00 = (1.f - ly) * (1.f - lx), w01 = (1.f - ly) * lx;
        float w10 = ly * (1.f - lx), w11 = ly * lx;
        bool vy0 = (y0 >= 0 && y0 <= HH - 1), vy1 = (y0 + 1 >= 0 && y0 + 1 <= HH - 1);
        bool vx0 = (x0 >= 0 && x0 <= WW - 1), vx1 = (x0 + 1 >= 0 && x0 + 1 <= WW - 1);
        w00 *= (vy0 && vx0) ? 1.f : 0.f;
        w01 *= (vy0 && vx1) ? 1.f : 0.f;
        w10 *= (vy1 && vx0) ? 1.f : 0.f;
        w11 *= (vy1 && vx1) ? 1.f : 0.f;
        int y0c = min(max(y0, 0), HH - 1), y1c = min(max(y0 + 1, 0), HH - 1);
        int x0c = min(max(x0, 0), WW - 1), x1c = min(max(x0 + 1, 0), WW - 1);
        int i00 = y0c * WW + x0c, i01 = y0c * WW + x1c;
        int i10 = y1c * WW + x0c, i11 = y1c * WW + x1c;
        float vals[24];
#pragma unroll
        for (int ci = 0; ci < 24; ++ci) {
            const float* qp = q + ((long)(b * C2 + g * 24 + ci)) * PP;
            vals[ci] = (w00 * qp[i00] + w01 * qp[i01] + w10 * qp[i10] + w11 * qp[i11]) * mk;
        }
        const float* wg = w + (long)g * 24 * 216 + k;
#pragma unroll
        for (int o = 0; o < 24; ++o) {
            const float* wr = wg + (long)o * 216;
            float s = acc[o];
#pragma unroll
            for (int ci = 0; ci < 24; ++ci) s += wr[ci * 9] * vals[ci];
            acc[o] = s;
        }
    }
#pragma unroll
    for (int o = 0; o < 24; ++o)
        out[((long)(b * CC + g * 24 + o)) * PP + p] = acc[o] + bias[g * 24 + o];
}

// ---------------- L2 norms of q and k rows -----------------------------------------------
__global__ __launch_bounds__(256) void norm_kernel(
    const float* __restrict__ q, const float* __restrict__ kb, float* __restrict__ norms)
{
    int c = blockIdx.x, b = blockIdx.y, which = blockIdx.z;
    const float* src = (which == 0) ? q + ((long)(b * C2 + c)) * PP
                                    : kb + ((long)(b * CC + c)) * PP;
    float s = 0.f;
    for (int n = threadIdx.x * 4; n < PP; n += 1024) {
        float4 v = *(const float4*)(src + n);
        s += v.x * v.x + v.y * v.y + v.z * v.z + v.w * v.w;
    }
    __shared__ float red[256];
    red[threadIdx.x] = s;
    __syncthreads();
    for (int st = 128; st > 0; st >>= 1) {
        if (threadIdx.x < st) red[threadIdx.x] += red[threadIdx.x + st];
        __syncthreads();
    }
    if (threadIdx.x == 0)
        norms[((long)which * BB + b) * CC + c] = fmaxf(sqrtf(red[0]), 1e-12f);
}

// ---------------- attention logits + softmax ---------------------------------------------
__global__ __launch_bounds__(256) void attn_kernel(
    const float* __restrict__ q, const float* __restrict__ kb,
    const float* __restrict__ norms, const float* __restrict__ temp,
    float* __restrict__ attn)
{
    int c = blockIdx.x, h = blockIdx.y, b = blockIdx.z;
    const float* qp = q + ((long)(b * C2 + h * 24 + c)) * PP;
    const float* kbase = kb + ((long)(b * CC + h * 24)) * PP;
    float part[24];
#pragma unroll
    for (int d = 0; d < 24; ++d) part[d] = 0.f;
    for (int n = threadIdx.x * 4; n < PP; n += 1024) {
        float4 qv = *(const float4*)(qp + n);
#pragma unroll
        for (int d = 0; d < 24; ++d) {
            float4 kv = *(const float4*)(kbase + (long)d * PP + n);
            part[d] += qv.x * kv.x + qv.y * kv.y + qv.z * kv.z + qv.w * kv.w;
        }
    }
    __shared__ float lred[4][24];
    __shared__ float logits[24];
    int lane = threadIdx.x & 63, wv = threadIdx.x >> 6;
#pragma unroll
    for (int d = 0; d < 24; ++d) {
        float x = part[d];
        for (int off = 32; off > 0; off >>= 1) x += __shfl_down(x, off, 64);
        if (lane == 0) lred[wv][d] = x;
    }
    __syncthreads();
    if (threadIdx.x < 24) {
        int d = threadIdx.x;
        float tot = lred[0][d] + lred[1][d] + lred[2][d] + lred[3][d];
        float nq = norms[(long)b * CC + h * 24 + c];
        float nk = norms[(long)(BB + b) * CC + h * 24 + d];
        logits[d] = tot / (nq * nk) * temp[h];
    }
    __syncthreads();
    if (threadIdx.x < 24) {
        int d = threadIdx.x;
        float mx = -3.4e38f;
#pragma unroll
        for (int j = 0; j < 24; ++j) mx = fmaxf(mx, logits[j]);
        float sum = 0.f;
#pragma unroll
        for (int j = 0; j < 24; ++j) sum += expf(logits[j] - mx);
        attn[(((long)(b * 8 + h) * 24) + c) * 24 + d] = expf(logits[d] - mx) / sum;
    }
}

// ---------------- attn @ v ----------------------------------------------------------------
__global__ __launch_bounds__(256) void attn_apply_kernel(
    const float* __restrict__ attn, const float* __restrict__ qkv2, float* __restrict__ out)
{
    int b = blockIdx.z, ch = blockIdx.y;
    int h = ch / 24, c = ch - h * 24;
    int n = blockIdx.x * 1024 + threadIdx.x * 4;
    const float* arow = attn + (((long)(b * 8 + h) * 24) + c) * 24;
    const float* vbase = qkv2 + ((long)(b * C2) + CC + h * 24) * PP;
    float4 acc = make_float4(0.f, 0.f, 0.f, 0.f);
#pragma unroll
    for (int d = 0; d < 24; ++d) {
        float a = arow[d];
        float4 vv = *(const float4*)(vbase + (long)d * PP + n);
        acc.x += a * vv.x; acc.y += a * vv.y; acc.z += a * vv.z; acc.w += a * vv.w;
    }
    *(float4*)(out + ((long)(b * CC + ch)) * PP + n) = acc;
}

// =========================================================================================
extern "C" void kernel_launch(void* const* d_in, const int* in_sizes, int n_in,
                              void* d_out, int out_size, void* d_ws, size_t ws_size,
                              hipStream_t stream)
{
    const float* x          = (const float*)d_in[0];
    const float* y          = (const float*)d_in[1];
    const float* temp       = (const float*)d_in[2];
    const float* qkv_w      = (const float*)d_in[3];
    const float* qkv_conv_w = (const float*)d_in[4];
    const float* proj_w     = (const float*)d_in[5];
    const float* k2_w       = (const float*)d_in[6];
    const float* k3_w       = (const float*)d_in[7];
    const float* k4_w       = (const float*)d_in[8];
    const float* deform_w   = (const float*)d_in[9];
    const float* deform_b   = (const float*)d_in[10];
    const float* pw_w       = (const float*)d_in[11];
    const float* pw_b       = (const float*)d_in[12];

    float* ws = (float*)d_ws;
    const long SZ_FULL = (long)BB * C2 * PP;     // 14,155,776
    const long SZ_HALF = (long)BB * CC * PP;     //  7,077,888

    float* bufA   = ws;                                   // qkv1 / sc / (kbuf | feat,attnout)
    float* qkv2   = ws + SZ_FULL;
    float* k2out  = ws + 2 * SZ_FULL;                     // B*384*2116 = 3,250,176
    float* ovl    = k2out + (long)BB * C2 * 2116;         // overlay region start
    // overlay region (time-multiplexed):
    //   pooled  (disp 3-4):   3,538,944 f
    //   catb    (disp 6-7):   14,155,776 bf16 = 7,077,888 f-equiv
    //   offs/norms/attnm (disp 8+): inside first 683,520 f
    float* pooled = ovl;
    ushort_t* catb = (ushort_t*)ovl;
    float* offs   = ovl;                                  // B*18*PP = 663,552
    float* norms  = offs + (long)BB * 18 * PP;            // 1,536
    float* attnm  = norms + 2 * BB * CC;                  // 18,432
    ushort_t* wbuf = (ushort_t*)(ovl + SZ_HALF);          // 1,327,104 bf16 = 663,552 f

    float* qkv1    = bufA;
    float* sc      = bufA;
    float* kbuf    = bufA;
    float* feat    = bufA + SZ_HALF;
    float* attnout = bufA + SZ_HALF;

    // 1. qkv = conv1x1(x, qkv_w)
    conv1x1_kernel<CC, false, false><<<dim3(9, 24, BB), 256, 0, stream>>>(
        x, qkv_w, nullptr, qkv1, (long)CC * PP, (long)C2 * PP);
    // 2. qkv = grouped 3x3 (groups=192)
    dwconv_kernel<<<dim3(36, C2, BB), 256, 0, stream>>>(qkv1, qkv_conv_w, qkv2);
    // 3. pooled = avgpool2(cat[q,y])
    avgpool_kernel<<<dim3(13824), 256, 0, stream>>>(qkv2, y, pooled);
    // 4. k2out = conv3x3 valid (48->46)
    conv48_kernel<<<dim3(96, BB), dim3(8, 8, 4), 0, stream>>>(pooled, k2_w, k2out);
    // 5. weight prep (bf16 [tap][co][ci])
    prep_w_kernel<<<dim3(9 * 384 * 384 / 256), 256, 0, stream>>>(k3_w, wbuf);
    // 6. catb = bf16 transposed cat (overlays dead pooled)
    cvt_cat_kernel<<<dim3(144, BB), 256, 0, stream>>>(qkv2, y, catb);
    // 7. sc = conv3x3(cat,k3) * sigmoid(cat + resize(k2out))  -- MFMA
    conv96_mfma_kernel<<<dim3(48, 3, BB), 256, 0, stream>>>(
        catb, wbuf, qkv2, y, k2out, sc);
    // 8. offset = conv3x3(sc, k4_w) (overlays dead catb)
    k4_kernel<<<dim3(36, BB), dim3(16, 16), 0, stream>>>(sc, k4_w, offs);
    // 9. feat = deform_conv(q, offset, mask, deform_w, deform_b)
    deform_kernel<<<dim3(36, 8, BB), 256, 0, stream>>>(qkv2, offs, deform_w, deform_b, feat);
    // 10. k = conv1x1(relu(feat), pw_w) + pw_b
    conv1x1_kernel<CC, true, true><<<dim3(9, 12, BB), 256, 0, stream>>>(
        feat, pw_w, pw_b, kbuf, (long)CC * PP, (long)CC * PP);
    // 11. norms
    norm_kernel<<<dim3(CC, BB, 2), 256, 0, stream>>>(qkv2, kbuf, norms);
    // 12. attn
    attn_kernel<<<dim3(24, 8, BB), 256, 0, stream>>>(qkv2, kbuf, norms, temp, attnm);
    // 13. attnout = attn @ v
    attn_apply_kernel<<<dim3(9, CC, BB), 256, 0, stream>>>(attnm, qkv2, attnout);
    // 14. out = conv1x1(attnout, proj_w)
    conv1x1_kernel<CC, false, false><<<dim3(9, 12, BB), 256, 0, stream>>>(
        attnout, proj_w, nullptr, (float*)d_out, (long)CC * PP, (long)CC * PP);
}

// Round 3
// 2154.003 us; speedup vs baseline: 3.7490x; 1.6935x over previous
//
#include <hip/hip_runtime.h>
#include <math.h>

// Problem constants
#define BB 4
#define CC 192
#define HH 96
#define WW 96
#define PP (HH*WW)          // 9216
#define C2 (2*CC)           // 384

typedef unsigned short ushort_t;
typedef __bf16 bf16_t;
typedef bf16_t bf16x8 __attribute__((ext_vector_type(8)));
typedef float floatx16 __attribute__((ext_vector_type(16)));

__device__ __forceinline__ float sigmoidf_(float x) { return 1.f / (1.f + expf(-x)); }

__device__ __forceinline__ ushort_t f2bf(float f) {
    unsigned u = __builtin_bit_cast(unsigned, f);
    unsigned r = (u + 0x7fffu + ((u >> 16) & 1u)) >> 16;
    return (ushort_t)r;
}

// ---------------- conv 1x1:  out[b,co,p] = bias + sum_ci w[co,ci] * f(in[b,ci,p]) ----------
template<int CIN, bool RELU, bool HASB>
__global__ __launch_bounds__(256) void conv1x1_kernel(
    const float* __restrict__ in, const float* __restrict__ w,
    const float* __restrict__ bias, float* __restrict__ out,
    long in_bs, long out_bs)
{
    int b = blockIdx.z;
    int co0 = blockIdx.y * 16;
    int p = blockIdx.x * 1024 + threadIdx.x * 4;
    const float* ip = in + (long)b * in_bs + p;
    float4 acc[16];
#pragma unroll
    for (int j = 0; j < 16; ++j) acc[j] = make_float4(0.f, 0.f, 0.f, 0.f);
#pragma unroll 4
    for (int ci = 0; ci < CIN; ++ci) {
        float4 xv = *(const float4*)(ip + (long)ci * PP);
        if (RELU) {
            xv.x = fmaxf(xv.x, 0.f); xv.y = fmaxf(xv.y, 0.f);
            xv.z = fmaxf(xv.z, 0.f); xv.w = fmaxf(xv.w, 0.f);
        }
#pragma unroll
        for (int j = 0; j < 16; ++j) {
            float wv = w[(long)(co0 + j) * CIN + ci];
            acc[j].x += wv * xv.x; acc[j].y += wv * xv.y;
            acc[j].z += wv * xv.z; acc[j].w += wv * xv.w;
        }
    }
#pragma unroll
    for (int j = 0; j < 16; ++j) {
        if (HASB) {
            float bb = bias[co0 + j];
            acc[j].x += bb; acc[j].y += bb; acc[j].z += bb; acc[j].w += bb;
        }
        *(float4*)(out + (long)b * out_bs + (long)(co0 + j) * PP + p) = acc[j];
    }
}

// ---------------- grouped conv 3x3, groups=192, 2in->2out, pad 1 -------------------------
__global__ __launch_bounds__(256) void dwconv_kernel(
    const float* __restrict__ in, const float* __restrict__ w, float* __restrict__ out)
{
    int b = blockIdx.z, co = blockIdx.y;
    int p = blockIdx.x * 256 + threadIdx.x;
    int oy = p / WW, ox = p - oy * WW;
    int g = co >> 1;
    const float* w18 = w + (long)co * 18;
    float acc = 0.f;
#pragma unroll
    for (int i = 0; i < 2; ++i) {
        const float* ipl = in + ((long)(b * C2 + 2 * g + i)) * PP;
#pragma unroll
        for (int ky = 0; ky < 3; ++ky) {
            int yy = oy - 1 + ky;
            if ((unsigned)yy < (unsigned)HH) {
#pragma unroll
                for (int kx = 0; kx < 3; ++kx) {
                    int xx = ox - 1 + kx;
                    if ((unsigned)xx < (unsigned)WW)
                        acc += w18[i * 9 + ky * 3 + kx] * ipl[yy * WW + xx];
                }
            }
        }
    }
    out[((long)(b * C2 + co)) * PP + p] = acc;
}

// ---------------- fused avgpool 2x2 + bf16 + transpose: poolb[b][px48][ci] ---------------
// grid (36, BB); block 256
__global__ __launch_bounds__(256) void avgpool_bf16_kernel(
    const float* __restrict__ qkv2, const float* __restrict__ y, ushort_t* __restrict__ poolb)
{
    __shared__ __align__(16) ushort_t sT[64 * 392];
    int b = blockIdx.y;
    int px0 = blockIdx.x * 64;
    int t = threadIdx.x;
    for (int idx = t; idx < 384 * 64; idx += 256) {
        int ci = idx >> 6, px = idx & 63;
        int p = px0 + px;
        int oy = p / 48, ox = p - oy * 48;
        const float* base = (ci < CC) ? qkv2 + ((long)(b * C2 + ci)) * PP
                                      : y + ((long)(b * CC + ci - CC)) * PP;
        const float* ipl = base + (oy * 2) * WW + ox * 2;
        float v = 0.25f * (ipl[0] + ipl[1] + ipl[WW] + ipl[WW + 1]);
        sT[px * 392 + ci] = f2bf(v);
    }
    __syncthreads();
    int px = t >> 2, qr = t & 3;
    ushort_t* dst = poolb + ((long)b * 2304 + px0 + px) * C2 + qr * 96;
    const ushort_t* srcl = sT + px * 392 + qr * 96;
#pragma unroll
    for (int k = 0; k < 96; k += 8)
        *(uint4*)(dst + k) = *(const uint4*)(srcl + k);
}

// ---------------- conv48 MFMA: valid 3x3 on 48x48 -> 46x46, Cin=Cout=384 -----------------
// grid (12 row-quads, 3 co-groups, B); block 256 (4 waves)
// block: M=128 co x N=192 px-slots (4 rows x 46 cols = 184 valid)
__global__ __launch_bounds__(256) void conv48_mfma_kernel(
    const ushort_t* __restrict__ poolb, const ushort_t* __restrict__ wb,
    float* __restrict__ out)
{
    __shared__ __align__(16) ushort_t sB[288 * 20];   // 6 rows x 48 cols, 16 ci each
    __shared__ __align__(16) ushort_t sW[1152 * 20];  // 9 taps x 128 co, 16 ci each
    int b = blockIdx.z;
    int co0 = blockIdx.y * 128;
    int y0 = blockIdx.x * 4;
    int t = threadIdx.x;
    int w = t >> 6, lane = t & 63;
    int n = lane & 31, q = lane >> 5;
    int wc = w & 1, wn = w >> 1;

    int pidx[3], rr[3], ccx[3];
#pragma unroll
    for (int xg = 0; xg < 3; ++xg) {
        int p = (wn * 3 + xg) * 32 + n;
        int pc = min(p, 183);
        pidx[xg] = p;
        rr[xg] = pc / 46;
        ccx[xg] = pc - rr[xg] * 46;
    }

    floatx16 acc[2][3];
#pragma unroll
    for (int a = 0; a < 2; ++a)
#pragma unroll
        for (int xg = 0; xg < 3; ++xg) acc[a][xg] = (floatx16)(0.f);

    const ushort_t* poolb_b = poolb + (long)b * 2304 * C2;

    for (int ci0 = 0; ci0 < C2; ci0 += 16) {
        __syncthreads();
        for (int c = t; c < 288; c += 256) {
            int r = c / 48, col = c - r * 48;
            int iy = y0 + r;
            ushort_t* d = sB + c * 20;
            if (iy < 48) {
                const ushort_t* s = poolb_b + ((long)(iy * 48 + col)) * C2 + ci0;
                uint4 v0 = *(const uint4*)(s);
                uint4 v1 = *(const uint4*)(s + 8);
                *(uint2*)(d + 0)  = make_uint2(v0.x, v0.y);
                *(uint2*)(d + 4)  = make_uint2(v0.z, v0.w);
                *(uint2*)(d + 8)  = make_uint2(v1.x, v1.y);
                *(uint2*)(d + 12) = make_uint2(v1.z, v1.w);
            } else {
                uint2 z = make_uint2(0u, 0u);
                *(uint2*)(d + 0) = z; *(uint2*)(d + 4) = z;
                *(uint2*)(d + 8) = z; *(uint2*)(d + 12) = z;
            }
        }
        for (int c = t; c < 1152; c += 256) {
            int tap = c >> 7, co = c & 127;
            const ushort_t* s = wb + ((long)(tap * C2 + co0 + co)) * C2 + ci0;
            ushort_t* d = sW + c * 20;
            uint4 v0 = *(const uint4*)(s);
            uint4 v1 = *(const uint4*)(s + 8);
            *(uint2*)(d + 0)  = make_uint2(v0.x, v0.y);
            *(uint2*)(d + 4)  = make_uint2(v0.z, v0.w);
            *(uint2*)(d + 8)  = make_uint2(v1.x, v1.y);
            *(uint2*)(d + 12) = make_uint2(v1.z, v1.w);
        }
        __syncthreads();
#pragma unroll
        for (int ky = 0; ky < 3; ++ky) {
#pragma unroll
            for (int kx = 0; kx < 3; ++kx) {
                int tap = ky * 3 + kx;
                bf16x8 af[2], bfm[3];
#pragma unroll
                for (int a = 0; a < 2; ++a) {
                    const ushort_t* p = sW + (tap * 128 + (wc * 2 + a) * 32 + n) * 20 + q * 8;
                    uint2 lo = *(const uint2*)(p);
                    uint2 hi = *(const uint2*)(p + 4);
                    af[a] = __builtin_bit_cast(bf16x8, make_uint4(lo.x, lo.y, hi.x, hi.y));
                }
#pragma unroll
                for (int xg = 0; xg < 3; ++xg) {
                    int cell = (rr[xg] + ky) * 48 + ccx[xg] + kx;
                    const ushort_t* p = sB + cell * 20 + q * 8;
                    uint2 lo = *(const uint2*)(p);
                    uint2 hi = *(const uint2*)(p + 4);
                    bfm[xg] = __builtin_bit_cast(bf16x8, make_uint4(lo.x, lo.y, hi.x, hi.y));
                }
#pragma unroll
                for (int a = 0; a < 2; ++a)
#pragma unroll
                    for (int xg = 0; xg < 3; ++xg)
                        acc[a][xg] = __builtin_amdgcn_mfma_f32_32x32x16_bf16(
                            af[a], bfm[xg], acc[a][xg], 0, 0, 0);
            }
        }
    }

#pragma unroll
    for (int a = 0; a < 2; ++a) {
        int cobase = co0 + (wc * 2 + a) * 32;
#pragma unroll
        for (int xg = 0; xg < 3; ++xg) {
            int oy = y0 + rr[xg], ox = ccx[xg];
            if (pidx[xg] >= 184 || oy >= 46) continue;
#pragma unroll
            for (int r = 0; r < 16; ++r) {
                int row = (r & 3) + 8 * (r >> 2) + 4 * q;
                out[((long)(b * C2 + cobase + row)) * 2116 + oy * 46 + ox] = acc[a][xg][r];
            }
        }
    }
}

// ---------------- cvt_cat: catb[b][px][ci] bf16 from cat(q=qkv2[0:192], y) ----------------
__global__ __launch_bounds__(256) void cvt_cat_kernel(
    const float* __restrict__ qkv2, const float* __restrict__ y, ushort_t* __restrict__ catb)
{
    __shared__ __align__(16) ushort_t sT[64 * 392];
    int b = blockIdx.y;
    int px0 = blockIdx.x * 64;
    int t = threadIdx.x;
    for (int idx = t; idx < 384 * 64; idx += 256) {
        int ci = idx >> 6, px = idx & 63;
        const float* src = (ci < CC) ? qkv2 + ((long)(b * C2 + ci)) * PP
                                     : y + ((long)(b * CC + ci - CC)) * PP;
        sT[px * 392 + ci] = f2bf(src[px0 + px]);
    }
    __syncthreads();
    int px = t >> 2, qr = t & 3;
    ushort_t* dst = catb + ((long)b * PP + px0 + px) * C2 + qr * 96;
    const ushort_t* srcl = sT + px * 392 + qr * 96;
#pragma unroll
    for (int k = 0; k < 96; k += 8)
        *(uint4*)(dst + k) = *(const uint4*)(srcl + k);
}

// ---------------- prep_w: Wb[tap][co][ci] bf16 from w[co][ci][tap]  (384x384x9) -----------
__global__ __launch_bounds__(256) void prep_w_kernel(
    const float* __restrict__ w, ushort_t* __restrict__ wb)
{
    int i = blockIdx.x * 256 + threadIdx.x;
    int ci = i % 384; int r = i / 384; int co = r % 384; int tap = r / 384;
    wb[i] = f2bf(w[((long)co * 384 + ci) * 9 + tap]);
}

// ---------------- conv96 MFMA: sc = conv3x3(cat) * sigmoid(cat + resize(k2out)) ----------
__global__ __launch_bounds__(256) void conv96_mfma_kernel(
    const ushort_t* __restrict__ catb, const ushort_t* __restrict__ wb,
    const float* __restrict__ qkv2, const float* __restrict__ yy,
    const float* __restrict__ k2out, float* __restrict__ out)
{
    __shared__ __align__(16) ushort_t sB[392 * 20];
    __shared__ __align__(16) ushort_t sW[1152 * 20];
    int b = blockIdx.z;
    int co0 = blockIdx.y * 128;
    int y0 = blockIdx.x * 2;
    int t = threadIdx.x;
    int w = t >> 6, lane = t & 63;
    int n = lane & 31, q = lane >> 5;
    int wc = w & 1;
    int wr = w >> 1;

    floatx16 acc[2][3];
#pragma unroll
    for (int a = 0; a < 2; ++a)
#pragma unroll
        for (int xg = 0; xg < 3; ++xg) acc[a][xg] = (floatx16)(0.f);

    const ushort_t* catb_b = catb + (long)b * PP * C2;

    for (int ci0 = 0; ci0 < C2; ci0 += 16) {
        __syncthreads();
        for (int c = t; c < 392; c += 256) {
            int r = c / 98, col = c - r * 98;
            int iy = y0 - 1 + r, ix = col - 1;
            ushort_t* d = sB + c * 20;
            if (iy >= 0 && iy < HH && ix >= 0 && ix < WW) {
                const ushort_t* s = catb_b + ((long)(iy * WW + ix)) * C2 + ci0;
                uint4 v0 = *(const uint4*)(s);
                uint4 v1 = *(const uint4*)(s + 8);
                *(uint2*)(d + 0)  = make_uint2(v0.x, v0.y);
                *(uint2*)(d + 4)  = make_uint2(v0.z, v0.w);
                *(uint2*)(d + 8)  = make_uint2(v1.x, v1.y);
                *(uint2*)(d + 12) = make_uint2(v1.z, v1.w);
            } else {
                uint2 z = make_uint2(0u, 0u);
                *(uint2*)(d + 0) = z; *(uint2*)(d + 4) = z;
                *(uint2*)(d + 8) = z; *(uint2*)(d + 12) = z;
            }
        }
        for (int c = t; c < 1152; c += 256) {
            int tap = c >> 7, co = c & 127;
            const ushort_t* s = wb + ((long)(tap * C2 + co0 + co)) * C2 + ci0;
            ushort_t* d = sW + c * 20;
            uint4 v0 = *(const uint4*)(s);
            uint4 v1 = *(const uint4*)(s + 8);
            *(uint2*)(d + 0)  = make_uint2(v0.x, v0.y);
            *(uint2*)(d + 4)  = make_uint2(v0.z, v0.w);
            *(uint2*)(d + 8)  = make_uint2(v1.x, v1.y);
            *(uint2*)(d + 12) = make_uint2(v1.z, v1.w);
        }
        __syncthreads();
#pragma unroll
        for (int ky = 0; ky < 3; ++ky) {
#pragma unroll
            for (int kx = 0; kx < 3; ++kx) {
                int tap = ky * 3 + kx;
                bf16x8 af[2], bfm[3];
#pragma unroll
                for (int a = 0; a < 2; ++a) {
                    const ushort_t* p = sW + (tap * 128 + (wc * 2 + a) * 32 + n) * 20 + q * 8;
                    uint2 lo = *(const uint2*)(p);
                    uint2 hi = *(const uint2*)(p + 4);
                    af[a] = __builtin_bit_cast(bf16x8, make_uint4(lo.x, lo.y, hi.x, hi.y));
                }
#pragma unroll
                for (int xg = 0; xg < 3; ++xg) {
                    int col = xg * 32 + n + kx;
                    const ushort_t* p = sB + ((wr + ky) * 98 + col) * 20 + q * 8;
                    uint2 lo = *(const uint2*)(p);
                    uint2 hi = *(const uint2*)(p + 4);
                    bfm[xg] = __builtin_bit_cast(bf16x8, make_uint4(lo.x, lo.y, hi.x, hi.y));
                }
#pragma unroll
                for (int a = 0; a < 2; ++a)
#pragma unroll
                    for (int xg = 0; xg < 3; ++xg)
                        acc[a][xg] = __builtin_amdgcn_mfma_f32_32x32x16_bf16(
                            af[a], bfm[xg], acc[a][xg], 0, 0, 0);
            }
        }
    }

    int yl = y0 + wr;
    int iy46 = (yl * 46) / 96;
#pragma unroll
    for (int a = 0; a < 2; ++a) {
        int cobase = co0 + (wc * 2 + a) * 32;
#pragma unroll
        for (int xg = 0; xg < 3; ++xg) {
#pragma unroll
            for (int r = 0; r < 16; ++r) {
                int row = (r & 3) + 8 * (r >> 2) + 4 * q;
                int co = cobase + row;
                int x = xg * 32 + n;
                const float* gsrc = (co < CC) ? qkv2 + ((long)(b * C2 + co)) * PP
                                              : yy + ((long)(b * CC + co - CC)) * PP;
                int ix46 = (x * 46) / 96;
                float kv = k2out[((long)(b * C2 + co)) * 2116 + iy46 * 46 + ix46];
                float g = gsrc[yl * WW + x] + kv;
                float v = acc[a][xg][r] * sigmoidf_(g);
                out[((long)(b * C2 + co)) * PP + yl * WW + x] = v;
            }
        }
    }
}

// ---------------- k4 conv: sc (384ch) -> offset (18ch), 3x3 pad1 -------------------------
__global__ __launch_bounds__(256) void k4_kernel(
    const float* __restrict__ sc, const float* __restrict__ w, float* __restrict__ out)
{
    __shared__ float t[18][18];
    int b = blockIdx.y;
    int tileid = blockIdx.x;
    int ty0 = (tileid / 6) * 16, tx0 = (tileid - (tileid / 6) * 6) * 16;
    int oy = ty0 + threadIdx.y, ox = tx0 + threadIdx.x;
    int tid = threadIdx.y * 16 + threadIdx.x;
    float acc[18];
#pragma unroll
    for (int co = 0; co < 18; ++co) acc[co] = 0.f;
    for (int ci = 0; ci < C2; ++ci) {
        const float* ipl = sc + ((long)(b * C2 + ci)) * PP;
        __syncthreads();
        for (int idx = tid; idx < 324; idx += 256) {
            int r = idx / 18, c = idx - r * 18;
            int sy = ty0 + r - 1, sx = tx0 + c - 1;
            t[r][c] = (sy >= 0 && sy < HH && sx >= 0 && sx < WW) ? ipl[sy * WW + sx] : 0.f;
        }
        __syncthreads();
        float rv[9];
#pragma unroll
        for (int ky = 0; ky < 3; ++ky)
#pragma unroll
            for (int kx = 0; kx < 3; ++kx)
                rv[ky * 3 + kx] = t[threadIdx.y + ky][threadIdx.x + kx];
        const float* wp = w + (long)ci * 9;
#pragma unroll
        for (int co = 0; co < 18; ++co) {
            const float* wc = wp + (long)co * (C2 * 9);
#pragma unroll
            for (int k = 0; k < 9; ++k) acc[co] += wc[k] * rv[k];
        }
    }
#pragma unroll
    for (int co = 0; co < 18; ++co)
        out[((long)(b * 18 + co)) * PP + oy * WW + ox] = acc[co];
}

// ---------------- deformable conv ---------------------------------------------------------
__global__ __launch_bounds__(256) void deform_kernel(
    const float* __restrict__ q, const float* __restrict__ offs,
    const float* __restrict__ w, const float* __restrict__ bias, float* __restrict__ out)
{
    int b = blockIdx.z, g = blockIdx.y;
    int p = blockIdx.x * 256 + threadIdx.x;
    int oy = p / WW, ox = p - oy * WW;
    const float* ob = offs + (long)b * 18 * PP;
    float acc[24];
#pragma unroll
    for (int o = 0; o < 24; ++o) acc[o] = 0.f;
    for (int k = 0; k < 9; ++k) {
        float dy = ob[(2 * k) * PP + p];
        float dx = ob[(2 * k + 1) * PP + p];
        float mk = sigmoidf_(ob[k * PP + p]);
        float py = dy + (float)(oy - 1 + k / 3);
        float px = dx + (float)(ox - 1 + (k % 3));
        float fy = floorf(py), fx = floorf(px);
        int y0 = (int)fy, x0 = (int)fx;
        float ly = py - fy, lx = px - fx;
        float w00 = (1.f - ly) * (1.f - lx), w01 = (1.f - ly) * lx;
        float w10 = ly * (1.f - lx), w11 = ly * lx;
        bool vy0 = (y0 >= 0 && y0 <= HH - 1), vy1 = (y0 + 1 >= 0 && y0 + 1 <= HH - 1);
        bool vx0 = (x0 >= 0 && x0 <= WW - 1), vx1 = (x0 + 1 >= 0 && x0 + 1 <= WW - 1);
        w00 *= (vy0 && vx0) ? 1.f : 0.f;
        w01 *= (vy0 && vx1) ? 1.f : 0.f;
        w10 *= (vy1 && vx0) ? 1.f : 0.f;
        w11 *= (vy1 && vx1) ? 1.f : 0.f;
        int y0c = min(max(y0, 0), HH - 1), y1c = min(max(y0 + 1, 0), HH - 1);
        int x0c = min(max(x0, 0), WW - 1), x1c = min(max(x0 + 1, 0), WW - 1);
        int i00 = y0c * WW + x0c, i01 = y0c * WW + x1c;
        int i10 = y1c * WW + x0c, i11 = y1c * WW + x1c;
        float vals[24];
#pragma unroll
        for (int ci = 0; ci < 24; ++ci) {
            const float* qp = q + ((long)(b * C2 + g * 24 + ci)) * PP;
            vals[ci] = (w00 * qp[i00] + w01 * qp[i01] + w10 * qp[i10] + w11 * qp[i11]) * mk;
        }
        const float* wg = w + (long)g * 24 * 216 + k;
#pragma unroll
        for (int o = 0; o < 24; ++o) {
            const float* wr = wg + (long)o * 216;
            float s = acc[o];
#pragma unroll
            for (int ci = 0; ci < 24; ++ci) s += wr[ci * 9] * vals[ci];
            acc[o] = s;
        }
    }
#pragma unroll
    for (int o = 0; o < 24; ++o)
        out[((long)(b * CC + g * 24 + o)) * PP + p] = acc[o] + bias[g * 24 + o];
}

// ---------------- L2 norms of q and k rows -----------------------------------------------
__global__ __launch_bounds__(256) void norm_kernel(
    const float* __restrict__ q, const float* __restrict__ kb, float* __restrict__ norms)
{
    int c = blockIdx.x, b = blockIdx.y, which = blockIdx.z;
    const float* src = (which == 0) ? q + ((long)(b * C2 + c)) * PP
                                    : kb + ((long)(b * CC + c)) * PP;
    float s = 0.f;
    for (int n = threadIdx.x * 4; n < PP; n += 1024) {
        float4 v = *(const float4*)(src + n);
        s += v.x * v.x + v.y * v.y + v.z * v.z + v.w * v.w;
    }
    __shared__ float red[256];
    red[threadIdx.x] = s;
    __syncthreads();
    for (int st = 128; st > 0; st >>= 1) {
        if (threadIdx.x < st) red[threadIdx.x] += red[threadIdx.x + st];
        __syncthreads();
    }
    if (threadIdx.x == 0)
        norms[((long)which * BB + b) * CC + c] = fmaxf(sqrtf(red[0]), 1e-12f);
}

// ---------------- attention logits + softmax ---------------------------------------------
__global__ __launch_bounds__(256) void attn_kernel(
    const float* __restrict__ q, const float* __restrict__ kb,
    const float* __restrict__ norms, const float* __restrict__ temp,
    float* __restrict__ attn)
{
    int c = blockIdx.x, h = blockIdx.y, b = blockIdx.z;
    const float* qp = q + ((long)(b * C2 + h * 24 + c)) * PP;
    const float* kbase = kb + ((long)(b * CC + h * 24)) * PP;
    float part[24];
#pragma unroll
    for (int d = 0; d < 24; ++d) part[d] = 0.f;
    for (int n = threadIdx.x * 4; n < PP; n += 1024) {
        float4 qv = *(const float4*)(qp + n);
#pragma unroll
        for (int d = 0; d < 24; ++d) {
            float4 kv = *(const float4*)(kbase + (long)d * PP + n);
            part[d] += qv.x * kv.x + qv.y * kv.y + qv.z * kv.z + qv.w * kv.w;
        }
    }
    __shared__ float lred[4][24];
    __shared__ float logits[24];
    int lane = threadIdx.x & 63, wv = threadIdx.x >> 6;
#pragma unroll
    for (int d = 0; d < 24; ++d) {
        float x = part[d];
        for (int off = 32; off > 0; off >>= 1) x += __shfl_down(x, off, 64);
        if (lane == 0) lred[wv][d] = x;
    }
    __syncthreads();
    if (threadIdx.x < 24) {
        int d = threadIdx.x;
        float tot = lred[0][d] + lred[1][d] + lred[2][d] + lred[3][d];
        float nq = norms[(long)b * CC + h * 24 + c];
        float nk = norms[(long)(BB + b) * CC + h * 24 + d];
        logits[d] = tot / (nq * nk) * temp[h];
    }
    __syncthreads();
    if (threadIdx.x < 24) {
        int d = threadIdx.x;
        float mx = -3.4e38f;
#pragma unroll
        for (int j = 0; j < 24; ++j) mx = fmaxf(mx, logits[j]);
        float sum = 0.f;
#pragma unroll
        for (int j = 0; j < 24; ++j) sum += expf(logits[j] - mx);
        attn[(((long)(b * 8 + h) * 24) + c) * 24 + d] = expf(logits[d] - mx) / sum;
    }
}

// ---------------- attn @ v ----------------------------------------------------------------
__global__ __launch_bounds__(256) void attn_apply_kernel(
    const float* __restrict__ attn, const float* __restrict__ qkv2, float* __restrict__ out)
{
    int b = blockIdx.z, ch = blockIdx.y;
    int h = ch / 24, c = ch - h * 24;
    int n = blockIdx.x * 1024 + threadIdx.x * 4;
    const float* arow = attn + (((long)(b * 8 + h) * 24) + c) * 24;
    const float* vbase = qkv2 + ((long)(b * C2) + CC + h * 24) * PP;
    float4 acc = make_float4(0.f, 0.f, 0.f, 0.f);
#pragma unroll
    for (int d = 0; d < 24; ++d) {
        float a = arow[d];
        float4 vv = *(const float4*)(vbase + (long)d * PP + n);
        acc.x += a * vv.x; acc.y += a * vv.y; acc.z += a * vv.z; acc.w += a * vv.w;
    }
    *(float4*)(out + ((long)(b * CC + ch)) * PP + n) = acc;
}

// =========================================================================================
extern "C" void kernel_launch(void* const* d_in, const int* in_sizes, int n_in,
                              void* d_out, int out_size, void* d_ws, size_t ws_size,
                              hipStream_t stream)
{
    const float* x          = (const float*)d_in[0];
    const float* y          = (const float*)d_in[1];
    const float* temp       = (const float*)d_in[2];
    const float* qkv_w      = (const float*)d_in[3];
    const float* qkv_conv_w = (const float*)d_in[4];
    const float* proj_w     = (const float*)d_in[5];
    const float* k2_w       = (const float*)d_in[6];
    const float* k3_w       = (const float*)d_in[7];
    const float* k4_w       = (const float*)d_in[8];
    const float* deform_w   = (const float*)d_in[9];
    const float* deform_b   = (const float*)d_in[10];
    const float* pw_w       = (const float*)d_in[11];
    const float* pw_b       = (const float*)d_in[12];

    float* ws = (float*)d_ws;
    const long SZ_FULL = (long)BB * C2 * PP;     // 14,155,776
    const long SZ_HALF = (long)BB * CC * PP;     //  7,077,888

    float* bufA   = ws;                                   // qkv1 / wb2 / sc / (kbuf | feat,attnout)
    float* qkv2   = ws + SZ_FULL;
    float* k2out  = ws + 2 * SZ_FULL;                     // B*384*2116 = 3,250,176
    float* ovl    = k2out + (long)BB * C2 * 2116;
    // overlay region (time-multiplexed):
    //   poolb (disp 3-5):  3,538,944 bf16
    //   catb  (disp 7-8):  14,155,776 bf16
    //   offs/norms/attnm (disp 9+)
    ushort_t* poolb = (ushort_t*)ovl;
    ushort_t* catb  = (ushort_t*)ovl;
    float* offs   = ovl;                                  // B*18*PP = 663,552
    float* norms  = offs + (long)BB * 18 * PP;
    float* attnm  = norms + 2 * BB * CC;
    ushort_t* wbuf = (ushort_t*)(ovl + SZ_HALF);          // k3 weights bf16

    float* qkv1    = bufA;
    ushort_t* wb2  = (ushort_t*)bufA;   // k2 weights bf16 (qkv1 dead after disp 2)
    float* sc      = bufA;
    float* kbuf    = bufA;
    float* feat    = bufA + SZ_HALF;
    float* attnout = bufA + SZ_HALF;

    // 1. qkv = conv1x1(x, qkv_w)
    conv1x1_kernel<CC, false, false><<<dim3(9, 24, BB), 256, 0, stream>>>(
        x, qkv_w, nullptr, qkv1, (long)CC * PP, (long)C2 * PP);
    // 2. qkv = grouped 3x3 (groups=192)
    dwconv_kernel<<<dim3(36, C2, BB), 256, 0, stream>>>(qkv1, qkv_conv_w, qkv2);
    // 3. poolb = bf16 px-major avgpool2(cat[q,y])   (qkv1 now dead)
    avgpool_bf16_kernel<<<dim3(36, BB), 256, 0, stream>>>(qkv2, y, poolb);
    // 4. wb2 = bf16 [tap][co][ci] k2 weights (into dead qkv1 space)
    prep_w_kernel<<<dim3(9 * 384 * 384 / 256), 256, 0, stream>>>(k2_w, wb2);
    // 5. k2out = conv3x3 valid (48->46)  -- MFMA
    conv48_mfma_kernel<<<dim3(12, 3, BB), 256, 0, stream>>>(poolb, wb2, k2out);
    // 6. wbuf = bf16 k3 weights
    prep_w_kernel<<<dim3(9 * 384 * 384 / 256), 256, 0, stream>>>(k3_w, wbuf);
    // 7. catb = bf16 transposed cat (overlays dead poolb)
    cvt_cat_kernel<<<dim3(144, BB), 256, 0, stream>>>(qkv2, y, catb);
    // 8. sc = conv3x3(cat,k3) * sigmoid(cat + resize(k2out))  -- MFMA (overwrites wb2)
    conv96_mfma_kernel<<<dim3(48, 3, BB), 256, 0, stream>>>(
        catb, wbuf, qkv2, y, k2out, sc);
    // 9. offset = conv3x3(sc, k4_w) (overlays dead catb)
    k4_kernel<<<dim3(36, BB), dim3(16, 16), 0, stream>>>(sc, k4_w, offs);
    // 10. feat = deform_conv(q, offset, mask, deform_w, deform_b)
    deform_kernel<<<dim3(36, 8, BB), 256, 0, stream>>>(qkv2, offs, deform_w, deform_b, feat);
    // 11. k = conv1x1(relu(feat), pw_w) + pw_b
    conv1x1_kernel<CC, true, true><<<dim3(9, 12, BB), 256, 0, stream>>>(
        feat, pw_w, pw_b, kbuf, (long)CC * PP, (long)CC * PP);
    // 12. norms
    norm_kernel<<<dim3(CC, BB, 2), 256, 0, stream>>>(qkv2, kbuf, norms);
    // 13. attn
    attn_kernel<<<dim3(24, 8, BB), 256, 0, stream>>>(qkv2, kbuf, norms, temp, attnm);
    // 14. attnout = attn @ v
    attn_apply_kernel<<<dim3(9, CC, BB), 256, 0, stream>>>(attnm, qkv2, attnout);
    // 15. out = conv1x1(attnout, proj_w)
    conv1x1_kernel<CC, false, false><<<dim3(9, 12, BB), 256, 0, stream>>>(
        attnout, proj_w, nullptr, (float*)d_out, (long)CC * PP, (long)CC * PP);
}

// Round 4
// 1312.549 us; speedup vs baseline: 6.1524x; 1.6411x over previous
//
#include <hip/hip_runtime.h>
#include <math.h>

// Problem constants
#define BB 4
#define CC 192
#define HH 96
#define WW 96
#define PP (HH*WW)          // 9216
#define C2 (2*CC)           // 384

typedef unsigned short ushort_t;
typedef __bf16 bf16_t;
typedef bf16_t bf16x8 __attribute__((ext_vector_type(8)));
typedef float floatx16 __attribute__((ext_vector_type(16)));

__device__ __forceinline__ float sigmoidf_(float x) { return 1.f / (1.f + expf(-x)); }

__device__ __forceinline__ ushort_t f2bf(float f) {
    unsigned u = __builtin_bit_cast(unsigned, f);
    unsigned r = (u + 0x7fffu + ((u >> 16) & 1u)) >> 16;
    return (ushort_t)r;
}

// ---------------- conv 1x1:  out[b,co,p] = bias + sum_ci w[co,ci] * f(in[b,ci,p]) ----------
template<int CIN, bool RELU, bool HASB>
__global__ __launch_bounds__(256) void conv1x1_kernel(
    const float* __restrict__ in, const float* __restrict__ w,
    const float* __restrict__ bias, float* __restrict__ out,
    long in_bs, long out_bs)
{
    int b = blockIdx.z;
    int co0 = blockIdx.y * 16;
    int p = blockIdx.x * 1024 + threadIdx.x * 4;
    const float* ip = in + (long)b * in_bs + p;
    float4 acc[16];
#pragma unroll
    for (int j = 0; j < 16; ++j) acc[j] = make_float4(0.f, 0.f, 0.f, 0.f);
#pragma unroll 4
    for (int ci = 0; ci < CIN; ++ci) {
        float4 xv = *(const float4*)(ip + (long)ci * PP);
        if (RELU) {
            xv.x = fmaxf(xv.x, 0.f); xv.y = fmaxf(xv.y, 0.f);
            xv.z = fmaxf(xv.z, 0.f); xv.w = fmaxf(xv.w, 0.f);
        }
#pragma unroll
        for (int j = 0; j < 16; ++j) {
            float wv = w[(long)(co0 + j) * CIN + ci];
            acc[j].x += wv * xv.x; acc[j].y += wv * xv.y;
            acc[j].z += wv * xv.z; acc[j].w += wv * xv.w;
        }
    }
#pragma unroll
    for (int j = 0; j < 16; ++j) {
        if (HASB) {
            float bb = bias[co0 + j];
            acc[j].x += bb; acc[j].y += bb; acc[j].z += bb; acc[j].w += bb;
        }
        *(float4*)(out + (long)b * out_bs + (long)(co0 + j) * PP + p) = acc[j];
    }
}

// ---------------- grouped conv 3x3, groups=192, 2in->2out, pad 1 -------------------------
__global__ __launch_bounds__(256) void dwconv_kernel(
    const float* __restrict__ in, const float* __restrict__ w, float* __restrict__ out)
{
    int b = blockIdx.z, co = blockIdx.y;
    int p = blockIdx.x * 256 + threadIdx.x;
    int oy = p / WW, ox = p - oy * WW;
    int g = co >> 1;
    const float* w18 = w + (long)co * 18;
    float acc = 0.f;
#pragma unroll
    for (int i = 0; i < 2; ++i) {
        const float* ipl = in + ((long)(b * C2 + 2 * g + i)) * PP;
#pragma unroll
        for (int ky = 0; ky < 3; ++ky) {
            int yy = oy - 1 + ky;
            if ((unsigned)yy < (unsigned)HH) {
#pragma unroll
                for (int kx = 0; kx < 3; ++kx) {
                    int xx = ox - 1 + kx;
                    if ((unsigned)xx < (unsigned)WW)
                        acc += w18[i * 9 + ky * 3 + kx] * ipl[yy * WW + xx];
                }
            }
        }
    }
    out[((long)(b * C2 + co)) * PP + p] = acc;
}

// ---------------- fused avgpool 2x2 + bf16 + transpose: poolb[b][px48][ci] ---------------
__global__ __launch_bounds__(256) void avgpool_bf16_kernel(
    const float* __restrict__ qkv2, const float* __restrict__ y, ushort_t* __restrict__ poolb)
{
    __shared__ __align__(16) ushort_t sT[64 * 392];
    int b = blockIdx.y;
    int px0 = blockIdx.x * 64;
    int t = threadIdx.x;
    for (int idx = t; idx < 384 * 64; idx += 256) {
        int ci = idx >> 6, px = idx & 63;
        int p = px0 + px;
        int oy = p / 48, ox = p - oy * 48;
        const float* base = (ci < CC) ? qkv2 + ((long)(b * C2 + ci)) * PP
                                      : y + ((long)(b * CC + ci - CC)) * PP;
        const float* ipl = base + (oy * 2) * WW + ox * 2;
        float v = 0.25f * (ipl[0] + ipl[1] + ipl[WW] + ipl[WW + 1]);
        sT[px * 392 + ci] = f2bf(v);
    }
    __syncthreads();
    int px = t >> 2, qr = t & 3;
    ushort_t* dst = poolb + ((long)b * 2304 + px0 + px) * C2 + qr * 96;
    const ushort_t* srcl = sT + px * 392 + qr * 96;
#pragma unroll
    for (int k = 0; k < 96; k += 8)
        *(uint4*)(dst + k) = *(const uint4*)(srcl + k);
}

// ---------------- conv48 MFMA: valid 3x3 on 48x48 -> 46x46, Cin=Cout=384 -----------------
__global__ __launch_bounds__(256) void conv48_mfma_kernel(
    const ushort_t* __restrict__ poolb, const ushort_t* __restrict__ wb,
    float* __restrict__ out)
{
    __shared__ __align__(16) ushort_t sB[288 * 20];
    __shared__ __align__(16) ushort_t sW[1152 * 20];
    int b = blockIdx.z;
    int co0 = blockIdx.y * 128;
    int y0 = blockIdx.x * 4;
    int t = threadIdx.x;
    int w = t >> 6, lane = t & 63;
    int n = lane & 31, q = lane >> 5;
    int wc = w & 1, wn = w >> 1;

    int pidx[3], rr[3], ccx[3];
#pragma unroll
    for (int xg = 0; xg < 3; ++xg) {
        int p = (wn * 3 + xg) * 32 + n;
        int pc = min(p, 183);
        pidx[xg] = p;
        rr[xg] = pc / 46;
        ccx[xg] = pc - rr[xg] * 46;
    }

    floatx16 acc[2][3];
#pragma unroll
    for (int a = 0; a < 2; ++a)
#pragma unroll
        for (int xg = 0; xg < 3; ++xg) acc[a][xg] = (floatx16)(0.f);

    const ushort_t* poolb_b = poolb + (long)b * 2304 * C2;

    for (int ci0 = 0; ci0 < C2; ci0 += 16) {
        __syncthreads();
        for (int c = t; c < 288; c += 256) {
            int r = c / 48, col = c - r * 48;
            int iy = y0 + r;
            ushort_t* d = sB + c * 20;
            if (iy < 48) {
                const ushort_t* s = poolb_b + ((long)(iy * 48 + col)) * C2 + ci0;
                uint4 v0 = *(const uint4*)(s);
                uint4 v1 = *(const uint4*)(s + 8);
                *(uint2*)(d + 0)  = make_uint2(v0.x, v0.y);
                *(uint2*)(d + 4)  = make_uint2(v0.z, v0.w);
                *(uint2*)(d + 8)  = make_uint2(v1.x, v1.y);
                *(uint2*)(d + 12) = make_uint2(v1.z, v1.w);
            } else {
                uint2 z = make_uint2(0u, 0u);
                *(uint2*)(d + 0) = z; *(uint2*)(d + 4) = z;
                *(uint2*)(d + 8) = z; *(uint2*)(d + 12) = z;
            }
        }
        for (int c = t; c < 1152; c += 256) {
            int tap = c >> 7, co = c & 127;
            const ushort_t* s = wb + ((long)(tap * C2 + co0 + co)) * C2 + ci0;
            ushort_t* d = sW + c * 20;
            uint4 v0 = *(const uint4*)(s);
            uint4 v1 = *(const uint4*)(s + 8);
            *(uint2*)(d + 0)  = make_uint2(v0.x, v0.y);
            *(uint2*)(d + 4)  = make_uint2(v0.z, v0.w);
            *(uint2*)(d + 8)  = make_uint2(v1.x, v1.y);
            *(uint2*)(d + 12) = make_uint2(v1.z, v1.w);
        }
        __syncthreads();
#pragma unroll
        for (int ky = 0; ky < 3; ++ky) {
#pragma unroll
            for (int kx = 0; kx < 3; ++kx) {
                int tap = ky * 3 + kx;
                bf16x8 af[2], bfm[3];
#pragma unroll
                for (int a = 0; a < 2; ++a) {
                    const ushort_t* p = sW + (tap * 128 + (wc * 2 + a) * 32 + n) * 20 + q * 8;
                    uint2 lo = *(const uint2*)(p);
                    uint2 hi = *(const uint2*)(p + 4);
                    af[a] = __builtin_bit_cast(bf16x8, make_uint4(lo.x, lo.y, hi.x, hi.y));
                }
#pragma unroll
                for (int xg = 0; xg < 3; ++xg) {
                    int cell = (rr[xg] + ky) * 48 + ccx[xg] + kx;
                    const ushort_t* p = sB + cell * 20 + q * 8;
                    uint2 lo = *(const uint2*)(p);
                    uint2 hi = *(const uint2*)(p + 4);
                    bfm[xg] = __builtin_bit_cast(bf16x8, make_uint4(lo.x, lo.y, hi.x, hi.y));
                }
#pragma unroll
                for (int a = 0; a < 2; ++a)
#pragma unroll
                    for (int xg = 0; xg < 3; ++xg)
                        acc[a][xg] = __builtin_amdgcn_mfma_f32_32x32x16_bf16(
                            af[a], bfm[xg], acc[a][xg], 0, 0, 0);
            }
        }
    }

#pragma unroll
    for (int a = 0; a < 2; ++a) {
        int cobase = co0 + (wc * 2 + a) * 32;
#pragma unroll
        for (int xg = 0; xg < 3; ++xg) {
            int oy = y0 + rr[xg], ox = ccx[xg];
            if (pidx[xg] >= 184 || oy >= 46) continue;
#pragma unroll
            for (int r = 0; r < 16; ++r) {
                int row = (r & 3) + 8 * (r >> 2) + 4 * q;
                out[((long)(b * C2 + cobase + row)) * 2116 + oy * 46 + ox] = acc[a][xg][r];
            }
        }
    }
}

// ---------------- cvt_cat: catb[b][px][ci] bf16 from cat(q=qkv2[0:192], y) ----------------
__global__ __launch_bounds__(256) void cvt_cat_kernel(
    const float* __restrict__ qkv2, const float* __restrict__ y, ushort_t* __restrict__ catb)
{
    __shared__ __align__(16) ushort_t sT[64 * 392];
    int b = blockIdx.y;
    int px0 = blockIdx.x * 64;
    int t = threadIdx.x;
    for (int idx = t; idx < 384 * 64; idx += 256) {
        int ci = idx >> 6, px = idx & 63;
        const float* src = (ci < CC) ? qkv2 + ((long)(b * C2 + ci)) * PP
                                     : y + ((long)(b * CC + ci - CC)) * PP;
        sT[px * 392 + ci] = f2bf(src[px0 + px]);
    }
    __syncthreads();
    int px = t >> 2, qr = t & 3;
    ushort_t* dst = catb + ((long)b * PP + px0 + px) * C2 + qr * 96;
    const ushort_t* srcl = sT + px * 392 + qr * 96;
#pragma unroll
    for (int k = 0; k < 96; k += 8)
        *(uint4*)(dst + k) = *(const uint4*)(srcl + k);
}

// ---------------- prep_w: Wb[tap][co][ci] bf16 from w[co][ci][tap]  (384x384x9) -----------
__global__ __launch_bounds__(256) void prep_w_kernel(
    const float* __restrict__ w, ushort_t* __restrict__ wb)
{
    int i = blockIdx.x * 256 + threadIdx.x;
    int ci = i % 384; int r = i / 384; int co = r % 384; int tap = r / 384;
    wb[i] = f2bf(w[((long)co * 384 + ci) * 9 + tap]);
}

// ---------------- prep_w4: Wb4[tap][co(32 pad)][ci] bf16 from k4_w[18][384][tap] ----------
__global__ __launch_bounds__(256) void prep_w4_kernel(
    const float* __restrict__ w, ushort_t* __restrict__ wb)
{
    int i = blockIdx.x * 256 + threadIdx.x;      // over 9*32*384
    int ci = i % 384; int r = i / 384; int co = r % 32; int tap = r / 32;
    wb[i] = (co < 18) ? f2bf(w[((long)co * 384 + ci) * 9 + tap]) : (ushort_t)0;
}

// ---------------- conv96 MFMA: scb = bf16 px-major [conv3x3(cat) * sigmoid(...)] ---------
__global__ __launch_bounds__(256) void conv96_mfma_kernel(
    const ushort_t* __restrict__ catb, const ushort_t* __restrict__ wb,
    const float* __restrict__ qkv2, const float* __restrict__ yy,
    const float* __restrict__ k2out, ushort_t* __restrict__ scb)
{
    __shared__ __align__(16) ushort_t sB[392 * 20];
    __shared__ __align__(16) ushort_t sW[1152 * 20];
    int b = blockIdx.z;
    int co0 = blockIdx.y * 128;
    int y0 = blockIdx.x * 2;
    int t = threadIdx.x;
    int w = t >> 6, lane = t & 63;
    int n = lane & 31, q = lane >> 5;
    int wc = w & 1;
    int wr = w >> 1;

    floatx16 acc[2][3];
#pragma unroll
    for (int a = 0; a < 2; ++a)
#pragma unroll
        for (int xg = 0; xg < 3; ++xg) acc[a][xg] = (floatx16)(0.f);

    const ushort_t* catb_b = catb + (long)b * PP * C2;

    for (int ci0 = 0; ci0 < C2; ci0 += 16) {
        __syncthreads();
        for (int c = t; c < 392; c += 256) {
            int r = c / 98, col = c - r * 98;
            int iy = y0 - 1 + r, ix = col - 1;
            ushort_t* d = sB + c * 20;
            if (iy >= 0 && iy < HH && ix >= 0 && ix < WW) {
                const ushort_t* s = catb_b + ((long)(iy * WW + ix)) * C2 + ci0;
                uint4 v0 = *(const uint4*)(s);
                uint4 v1 = *(const uint4*)(s + 8);
                *(uint2*)(d + 0)  = make_uint2(v0.x, v0.y);
                *(uint2*)(d + 4)  = make_uint2(v0.z, v0.w);
                *(uint2*)(d + 8)  = make_uint2(v1.x, v1.y);
                *(uint2*)(d + 12) = make_uint2(v1.z, v1.w);
            } else {
                uint2 z = make_uint2(0u, 0u);
                *(uint2*)(d + 0) = z; *(uint2*)(d + 4) = z;
                *(uint2*)(d + 8) = z; *(uint2*)(d + 12) = z;
            }
        }
        for (int c = t; c < 1152; c += 256) {
            int tap = c >> 7, co = c & 127;
            const ushort_t* s = wb + ((long)(tap * C2 + co0 + co)) * C2 + ci0;
            ushort_t* d = sW + c * 20;
            uint4 v0 = *(const uint4*)(s);
            uint4 v1 = *(const uint4*)(s + 8);
            *(uint2*)(d + 0)  = make_uint2(v0.x, v0.y);
            *(uint2*)(d + 4)  = make_uint2(v0.z, v0.w);
            *(uint2*)(d + 8)  = make_uint2(v1.x, v1.y);
            *(uint2*)(d + 12) = make_uint2(v1.z, v1.w);
        }
        __syncthreads();
#pragma unroll
        for (int ky = 0; ky < 3; ++ky) {
#pragma unroll
            for (int kx = 0; kx < 3; ++kx) {
                int tap = ky * 3 + kx;
                bf16x8 af[2], bfm[3];
#pragma unroll
                for (int a = 0; a < 2; ++a) {
                    const ushort_t* p = sW + (tap * 128 + (wc * 2 + a) * 32 + n) * 20 + q * 8;
                    uint2 lo = *(const uint2*)(p);
                    uint2 hi = *(const uint2*)(p + 4);
                    af[a] = __builtin_bit_cast(bf16x8, make_uint4(lo.x, lo.y, hi.x, hi.y));
                }
#pragma unroll
                for (int xg = 0; xg < 3; ++xg) {
                    int col = xg * 32 + n + kx;
                    const ushort_t* p = sB + ((wr + ky) * 98 + col) * 20 + q * 8;
                    uint2 lo = *(const uint2*)(p);
                    uint2 hi = *(const uint2*)(p + 4);
                    bfm[xg] = __builtin_bit_cast(bf16x8, make_uint4(lo.x, lo.y, hi.x, hi.y));
                }
#pragma unroll
                for (int a = 0; a < 2; ++a)
#pragma unroll
                    for (int xg = 0; xg < 3; ++xg)
                        acc[a][xg] = __builtin_amdgcn_mfma_f32_32x32x16_bf16(
                            af[a], bfm[xg], acc[a][xg], 0, 0, 0);
            }
        }
    }

    // epilogue: scb[b][px][co] = bf16( acc * sigmoid(cat + nearest(k2out)) )
    int yl = y0 + wr;
    int iy46 = (yl * 46) / 96;
#pragma unroll
    for (int a = 0; a < 2; ++a) {
        int cobase = co0 + (wc * 2 + a) * 32;
#pragma unroll
        for (int xg = 0; xg < 3; ++xg) {
            int x = xg * 32 + n;
            int ix46 = (x * 46) / 96;
            ushort_t* dst = scb + ((long)(b * PP + yl * WW + x)) * C2;
#pragma unroll
            for (int g = 0; g < 4; ++g) {
                int cog = cobase + 8 * g + 4 * q;
                ushort_t pk[4];
#pragma unroll
                for (int j = 0; j < 4; ++j) {
                    int co = cog + j;
                    const float* gsrc = (co < CC) ? qkv2 + ((long)(b * C2 + co)) * PP
                                                  : yy + ((long)(b * CC + co - CC)) * PP;
                    float kv = k2out[((long)(b * C2 + co)) * 2116 + iy46 * 46 + ix46];
                    float gg = gsrc[yl * WW + x] + kv;
                    pk[j] = f2bf(acc[a][xg][4 * g + j] * sigmoidf_(gg));
                }
                *(uint2*)(dst + cog) = *(uint2*)pk;
            }
        }
    }
}

// ---------------- k4 MFMA: offs(18ch fp32) = conv3x3(scb), M=32 pad ----------------------
// grid (48, B); block 384 (6 waves); wave w: row = w/3, xg = w%3
__global__ __launch_bounds__(384) void k4_mfma_kernel(
    const ushort_t* __restrict__ scb, const ushort_t* __restrict__ wb4,
    float* __restrict__ out)
{
    __shared__ __align__(16) ushort_t sB[392 * 20];   // rows y0-1..y0+2 x 98 cols
    __shared__ __align__(16) ushort_t sW[288 * 20];   // 9 taps x 32 co
    int b = blockIdx.y;
    int y0 = blockIdx.x * 2;
    int t = threadIdx.x;
    int w = t / 64, lane = t & 63;
    int n = lane & 31, q = lane >> 5;
    int wr = w / 3, xg = w - wr * 3;

    floatx16 acc = (floatx16)(0.f);
    const ushort_t* scb_b = scb + (long)b * PP * C2;

    for (int ci0 = 0; ci0 < C2; ci0 += 16) {
        __syncthreads();
        for (int c = t; c < 392; c += 384) {
            int r = c / 98, col = c - r * 98;
            int iy = y0 - 1 + r, ix = col - 1;
            ushort_t* d = sB + c * 20;
            if (iy >= 0 && iy < HH && ix >= 0 && ix < WW) {
                const ushort_t* s = scb_b + ((long)(iy * WW + ix)) * C2 + ci0;
                uint4 v0 = *(const uint4*)(s);
                uint4 v1 = *(const uint4*)(s + 8);
                *(uint2*)(d + 0)  = make_uint2(v0.x, v0.y);
                *(uint2*)(d + 4)  = make_uint2(v0.z, v0.w);
                *(uint2*)(d + 8)  = make_uint2(v1.x, v1.y);
                *(uint2*)(d + 12) = make_uint2(v1.z, v1.w);
            } else {
                uint2 z = make_uint2(0u, 0u);
                *(uint2*)(d + 0) = z; *(uint2*)(d + 4) = z;
                *(uint2*)(d + 8) = z; *(uint2*)(d + 12) = z;
            }
        }
        if (t < 288) {
            int c = t;
            const ushort_t* s = wb4 + (long)c * C2 + ci0;
            ushort_t* d = sW + c * 20;
            uint4 v0 = *(const uint4*)(s);
            uint4 v1 = *(const uint4*)(s + 8);
            *(uint2*)(d + 0)  = make_uint2(v0.x, v0.y);
            *(uint2*)(d + 4)  = make_uint2(v0.z, v0.w);
            *(uint2*)(d + 8)  = make_uint2(v1.x, v1.y);
            *(uint2*)(d + 12) = make_uint2(v1.z, v1.w);
        }
        __syncthreads();
#pragma unroll
        for (int ky = 0; ky < 3; ++ky) {
#pragma unroll
            for (int kx = 0; kx < 3; ++kx) {
                int tap = ky * 3 + kx;
                const ushort_t* pa = sW + (tap * 32 + n) * 20 + q * 8;
                uint2 alo = *(const uint2*)(pa);
                uint2 ahi = *(const uint2*)(pa + 4);
                bf16x8 af = __builtin_bit_cast(bf16x8, make_uint4(alo.x, alo.y, ahi.x, ahi.y));
                int col = xg * 32 + n + kx;
                const ushort_t* pb = sB + ((wr + ky) * 98 + col) * 20 + q * 8;
                uint2 blo = *(const uint2*)(pb);
                uint2 bhi = *(const uint2*)(pb + 4);
                bf16x8 bf = __builtin_bit_cast(bf16x8, make_uint4(blo.x, blo.y, bhi.x, bhi.y));
                acc = __builtin_amdgcn_mfma_f32_32x32x16_bf16(af, bf, acc, 0, 0, 0);
            }
        }
    }

    int yl = y0 + wr;
    int x = xg * 32 + n;
#pragma unroll
    for (int r = 0; r < 16; ++r) {
        int row = (r & 3) + 8 * (r >> 2) + 4 * q;
        if (row < 18)
            out[((long)(b * 18 + row)) * PP + yl * WW + x] = acc[r];
    }
}

// ---------------- deformable conv ---------------------------------------------------------
__global__ __launch_bounds__(256) void deform_kernel(
    const float* __restrict__ q, const float* __restrict__ offs,
    const float* __restrict__ w, const float* __restrict__ bias, float* __restrict__ out)
{
    int b = blockIdx.z, g = blockIdx.y;
    int p = blockIdx.x * 256 + threadIdx.x;
    int oy = p / WW, ox = p - oy * WW;
    const float* ob = offs + (long)b * 18 * PP;
    float acc[24];
#pragma unroll
    for (int o = 0; o < 24; ++o) acc[o] = 0.f;
    for (int k = 0; k < 9; ++k) {
        float dy = ob[(2 * k) * PP + p];
        float dx = ob[(2 * k + 1) * PP + p];
        float mk = sigmoidf_(ob[k * PP + p]);
        float py = dy + (float)(oy - 1 + k / 3);
        float px = dx + (float)(ox - 1 + (k % 3));
        float fy = floorf(py), fx = floorf(px);
        int y0 = (int)fy, x0 = (int)fx;
        float ly = py - fy, lx = px - fx;
        float w00 = (1.f - ly) * (1.f - lx), w01 = (1.f - ly) * lx;
        float w10 = ly * (1.f - lx), w11 = ly * lx;
        bool vy0 = (y0 >= 0 && y0 <= HH - 1), vy1 = (y0 + 1 >= 0 && y0 + 1 <= HH - 1);
        bool vx0 = (x0 >= 0 && x0 <= WW - 1), vx1 = (x0 + 1 >= 0 && x0 + 1 <= WW - 1);
        w00 *= (vy0 && vx0) ? 1.f : 0.f;
        w01 *= (vy0 && vx1) ? 1.f : 0.f;
        w10 *= (vy1 && vx0) ? 1.f : 0.f;
        w11 *= (vy1 && vx1) ? 1.f : 0.f;
        int y0c = min(max(y0, 0), HH - 1), y1c = min(max(y0 + 1, 0), HH - 1);
        int x0c = min(max(x0, 0), WW - 1), x1c = min(max(x0 + 1, 0), WW - 1);
        int i00 = y0c * WW + x0c, i01 = y0c * WW + x1c;
        int i10 = y1c * WW + x0c, i11 = y1c * WW + x1c;
        float vals[24];
#pragma unroll
        for (int ci = 0; ci < 24; ++ci) {
            const float* qp = q + ((long)(b * C2 + g * 24 + ci)) * PP;
            vals[ci] = (w00 * qp[i00] + w01 * qp[i01] + w10 * qp[i10] + w11 * qp[i11]) * mk;
        }
        const float* wg = w + (long)g * 24 * 216 + k;
#pragma unroll
        for (int o = 0; o < 24; ++o) {
            const float* wr = wg + (long)o * 216;
            float s = acc[o];
#pragma unroll
            for (int ci = 0; ci < 24; ++ci) s += wr[ci * 9] * vals[ci];
            acc[o] = s;
        }
    }
#pragma unroll
    for (int o = 0; o < 24; ++o)
        out[((long)(b * CC + g * 24 + o)) * PP + p] = acc[o] + bias[g * 24 + o];
}

// ---------------- L2 norms of q and k rows -----------------------------------------------
__global__ __launch_bounds__(256) void norm_kernel(
    const float* __restrict__ q, const float* __restrict__ kb, float* __restrict__ norms)
{
    int c = blockIdx.x, b = blockIdx.y, which = blockIdx.z;
    const float* src = (which == 0) ? q + ((long)(b * C2 + c)) * PP
                                    : kb + ((long)(b * CC + c)) * PP;
    float s = 0.f;
    for (int n = threadIdx.x * 4; n < PP; n += 1024) {
        float4 v = *(const float4*)(src + n);
        s += v.x * v.x + v.y * v.y + v.z * v.z + v.w * v.w;
    }
    __shared__ float red[256];
    red[threadIdx.x] = s;
    __syncthreads();
    for (int st = 128; st > 0; st >>= 1) {
        if (threadIdx.x < st) red[threadIdx.x] += red[threadIdx.x + st];
        __syncthreads();
    }
    if (threadIdx.x == 0)
        norms[((long)which * BB + b) * CC + c] = fmaxf(sqrtf(red[0]), 1e-12f);
}

// ---------------- attention logits + softmax ---------------------------------------------
__global__ __launch_bounds__(256) void attn_kernel(
    const float* __restrict__ q, const float* __restrict__ kb,
    const float* __restrict__ norms, const float* __restrict__ temp,
    float* __restrict__ attn)
{
    int c = blockIdx.x, h = blockIdx.y, b = blockIdx.z;
    const float* qp = q + ((long)(b * C2 + h * 24 + c)) * PP;
    const float* kbase = kb + ((long)(b * CC + h * 24)) * PP;
    float part[24];
#pragma unroll
    for (int d = 0; d < 24; ++d) part[d] = 0.f;
    for (int n = threadIdx.x * 4; n < PP; n += 1024) {
        float4 qv = *(const float4*)(qp + n);
#pragma unroll
        for (int d = 0; d < 24; ++d) {
            float4 kv = *(const float4*)(kbase + (long)d * PP + n);
            part[d] += qv.x * kv.x + qv.y * kv.y + qv.z * kv.z + qv.w * kv.w;
        }
    }
    __shared__ float lred[4][24];
    __shared__ float logits[24];
    int lane = threadIdx.x & 63, wv = threadIdx.x >> 6;
#pragma unroll
    for (int d = 0; d < 24; ++d) {
        float x = part[d];
        for (int off = 32; off > 0; off >>= 1) x += __shfl_down(x, off, 64);
        if (lane == 0) lred[wv][d] = x;
    }
    __syncthreads();
    if (threadIdx.x < 24) {
        int d = threadIdx.x;
        float tot = lred[0][d] + lred[1][d] + lred[2][d] + lred[3][d];
        float nq = norms[(long)b * CC + h * 24 + c];
        float nk = norms[(long)(BB + b) * CC + h * 24 + d];
        logits[d] = tot / (nq * nk) * temp[h];
    }
    __syncthreads();
    if (threadIdx.x < 24) {
        int d = threadIdx.x;
        float mx = -3.4e38f;
#pragma unroll
        for (int j = 0; j < 24; ++j) mx = fmaxf(mx, logits[j]);
        float sum = 0.f;
#pragma unroll
        for (int j = 0; j < 24; ++j) sum += expf(logits[j] - mx);
        attn[(((long)(b * 8 + h) * 24) + c) * 24 + d] = expf(logits[d] - mx) / sum;
    }
}

// ---------------- attn @ v ----------------------------------------------------------------
__global__ __launch_bounds__(256) void attn_apply_kernel(
    const float* __restrict__ attn, const float* __restrict__ qkv2, float* __restrict__ out)
{
    int b = blockIdx.z, ch = blockIdx.y;
    int h = ch / 24, c = ch - h * 24;
    int n = blockIdx.x * 1024 + threadIdx.x * 4;
    const float* arow = attn + (((long)(b * 8 + h) * 24) + c) * 24;
    const float* vbase = qkv2 + ((long)(b * C2) + CC + h * 24) * PP;
    float4 acc = make_float4(0.f, 0.f, 0.f, 0.f);
#pragma unroll
    for (int d = 0; d < 24; ++d) {
        float a = arow[d];
        float4 vv = *(const float4*)(vbase + (long)d * PP + n);
        acc.x += a * vv.x; acc.y += a * vv.y; acc.z += a * vv.z; acc.w += a * vv.w;
    }
    *(float4*)(out + ((long)(b * CC + ch)) * PP + n) = acc;
}

// =========================================================================================
extern "C" void kernel_launch(void* const* d_in, const int* in_sizes, int n_in,
                              void* d_out, int out_size, void* d_ws, size_t ws_size,
                              hipStream_t stream)
{
    const float* x          = (const float*)d_in[0];
    const float* y          = (const float*)d_in[1];
    const float* temp       = (const float*)d_in[2];
    const float* qkv_w      = (const float*)d_in[3];
    const float* qkv_conv_w = (const float*)d_in[4];
    const float* proj_w     = (const float*)d_in[5];
    const float* k2_w       = (const float*)d_in[6];
    const float* k3_w       = (const float*)d_in[7];
    const float* k4_w       = (const float*)d_in[8];
    const float* deform_w   = (const float*)d_in[9];
    const float* deform_b   = (const float*)d_in[10];
    const float* pw_w       = (const float*)d_in[11];
    const float* pw_b       = (const float*)d_in[12];

    float* ws = (float*)d_ws;
    const long SZ_FULL = (long)BB * C2 * PP;     // 14,155,776
    const long SZ_HALF = (long)BB * CC * PP;     //  7,077,888

    float* bufA   = ws;                                   // qkv1 / wb2 / scb / (kbuf | feat,attnout)
    float* qkv2   = ws + SZ_FULL;
    float* k2out  = ws + 2 * SZ_FULL;                     // B*384*2116
    float* ovl    = k2out + (long)BB * C2 * 2116;
    ushort_t* poolb = (ushort_t*)ovl;
    ushort_t* catb  = (ushort_t*)ovl;
    float* offs   = ovl;                                  // B*18*PP
    float* norms  = offs + (long)BB * 18 * PP;
    float* attnm  = norms + 2 * BB * CC;
    ushort_t* wbuf = (ushort_t*)(ovl + SZ_HALF);          // k3 weights bf16 (663,552 f)
    ushort_t* wb4  = (ushort_t*)(ovl + SZ_HALF + 663552); // k4 weights bf16 (55,296 f)

    float* qkv1    = bufA;
    ushort_t* wb2  = (ushort_t*)bufA;   // k2 weights bf16 (qkv1 dead after disp 2)
    ushort_t* scb  = (ushort_t*)bufA;   // sc bf16 px-major (first SZ_HALF floats)
    float* kbuf    = bufA;
    float* feat    = bufA + SZ_HALF;
    float* attnout = bufA + SZ_HALF;

    // 1. qkv = conv1x1(x, qkv_w)
    conv1x1_kernel<CC, false, false><<<dim3(9, 24, BB), 256, 0, stream>>>(
        x, qkv_w, nullptr, qkv1, (long)CC * PP, (long)C2 * PP);
    // 2. qkv = grouped 3x3 (groups=192)
    dwconv_kernel<<<dim3(36, C2, BB), 256, 0, stream>>>(qkv1, qkv_conv_w, qkv2);
    // 3. poolb = bf16 px-major avgpool2(cat[q,y])   (qkv1 now dead)
    avgpool_bf16_kernel<<<dim3(36, BB), 256, 0, stream>>>(qkv2, y, poolb);
    // 4. wb2 = bf16 [tap][co][ci] k2 weights (into dead qkv1 space)
    prep_w_kernel<<<dim3(9 * 384 * 384 / 256), 256, 0, stream>>>(k2_w, wb2);
    // 5. k2out = conv3x3 valid (48->46)  -- MFMA
    conv48_mfma_kernel<<<dim3(12, 3, BB), 256, 0, stream>>>(poolb, wb2, k2out);
    // 6. weight preps: k3 and k4
    prep_w_kernel<<<dim3(9 * 384 * 384 / 256), 256, 0, stream>>>(k3_w, wbuf);
    prep_w4_kernel<<<dim3(9 * 32 * 384 / 256), 256, 0, stream>>>(k4_w, wb4);
    // 7. catb = bf16 transposed cat (overlays dead poolb)
    cvt_cat_kernel<<<dim3(144, BB), 256, 0, stream>>>(qkv2, y, catb);
    // 8. scb = bf16 px-major [conv3x3(cat,k3) * sigmoid(cat + resize(k2out))]  -- MFMA
    conv96_mfma_kernel<<<dim3(48, 3, BB), 256, 0, stream>>>(
        catb, wbuf, qkv2, y, k2out, scb);
    // 9. offset = conv3x3(scb, k4)  -- MFMA (overlays dead catb)
    k4_mfma_kernel<<<dim3(48, BB), 384, 0, stream>>>(scb, wb4, offs);
    // 10. feat = deform_conv(q, offset, mask, deform_w, deform_b)
    deform_kernel<<<dim3(36, 8, BB), 256, 0, stream>>>(qkv2, offs, deform_w, deform_b, feat);
    // 11. k = conv1x1(relu(feat), pw_w) + pw_b   (overwrites scb — dead after disp 9)
    conv1x1_kernel<CC, true, true><<<dim3(9, 12, BB), 256, 0, stream>>>(
        feat, pw_w, pw_b, kbuf, (long)CC * PP, (long)CC * PP);
    // 12. norms
    norm_kernel<<<dim3(CC, BB, 2), 256, 0, stream>>>(qkv2, kbuf, norms);
    // 13. attn
    attn_kernel<<<dim3(24, 8, BB), 256, 0, stream>>>(qkv2, kbuf, norms, temp, attnm);
    // 14. attnout = attn @ v
    attn_apply_kernel<<<dim3(9, CC, BB), 256, 0, stream>>>(attnm, qkv2, attnout);
    // 15. out = conv1x1(attnout, proj_w)
    conv1x1_kernel<CC, false, false><<<dim3(9, 12, BB), 256, 0, stream>>>(
        attnout, proj_w, nullptr, (float*)d_out, (long)CC * PP, (long)CC * PP);
}

// Round 5
// 1205.053 us; speedup vs baseline: 6.7012x; 1.0892x over previous
//
#include <hip/hip_runtime.h>
#include <math.h>

// Problem constants
#define BB 4
#define CC 192
#define HH 96
#define WW 96
#define PP (HH*WW)          // 9216
#define C2 (2*CC)           // 384

typedef unsigned short ushort_t;
typedef __bf16 bf16_t;
typedef bf16_t bf16x8 __attribute__((ext_vector_type(8)));
typedef float floatx16 __attribute__((ext_vector_type(16)));

__device__ __forceinline__ float sigmoidf_(float x) { return 1.f / (1.f + expf(-x)); }

__device__ __forceinline__ ushort_t f2bf(float f) {
    unsigned u = __builtin_bit_cast(unsigned, f);
    unsigned r = (u + 0x7fffu + ((u >> 16) & 1u)) >> 16;
    return (ushort_t)r;
}

// ---------------- conv 1x1:  out[b,co,p] = bias + sum_ci w[co,ci] * f(in[b,ci,p]) ----------
template<int CIN, bool RELU, bool HASB>
__global__ __launch_bounds__(256) void conv1x1_kernel(
    const float* __restrict__ in, const float* __restrict__ w,
    const float* __restrict__ bias, float* __restrict__ out,
    long in_bs, long out_bs)
{
    int b = blockIdx.z;
    int co0 = blockIdx.y * 16;
    int p = blockIdx.x * 1024 + threadIdx.x * 4;
    const float* ip = in + (long)b * in_bs + p;
    float4 acc[16];
#pragma unroll
    for (int j = 0; j < 16; ++j) acc[j] = make_float4(0.f, 0.f, 0.f, 0.f);
#pragma unroll 4
    for (int ci = 0; ci < CIN; ++ci) {
        float4 xv = *(const float4*)(ip + (long)ci * PP);
        if (RELU) {
            xv.x = fmaxf(xv.x, 0.f); xv.y = fmaxf(xv.y, 0.f);
            xv.z = fmaxf(xv.z, 0.f); xv.w = fmaxf(xv.w, 0.f);
        }
#pragma unroll
        for (int j = 0; j < 16; ++j) {
            float wv = w[(long)(co0 + j) * CIN + ci];
            acc[j].x += wv * xv.x; acc[j].y += wv * xv.y;
            acc[j].z += wv * xv.z; acc[j].w += wv * xv.w;
        }
    }
#pragma unroll
    for (int j = 0; j < 16; ++j) {
        if (HASB) {
            float bb = bias[co0 + j];
            acc[j].x += bb; acc[j].y += bb; acc[j].z += bb; acc[j].w += bb;
        }
        *(float4*)(out + (long)b * out_bs + (long)(co0 + j) * PP + p) = acc[j];
    }
}

// ---------------- grouped conv 3x3, groups=192, 2in->2out, pad 1, 4px/thread -------------
__global__ __launch_bounds__(256) void dwconv_kernel(
    const float* __restrict__ in, const float* __restrict__ w, float* __restrict__ out)
{
    int b = blockIdx.z, co = blockIdx.y;
    int p = (blockIdx.x * 256 + threadIdx.x) * 4;   // 96 % 4 == 0: no row straddle
    int oy = p / WW, ox = p - oy * WW;
    int g = co >> 1;
    const float* w18 = w + (long)co * 18;
    float a0 = 0.f, a1 = 0.f, a2 = 0.f, a3 = 0.f;
#pragma unroll
    for (int i = 0; i < 2; ++i) {
        const float* ipl = in + ((long)(b * C2 + 2 * g + i)) * PP;
#pragma unroll
        for (int ky = 0; ky < 3; ++ky) {
            int yy = oy - 1 + ky;
            if ((unsigned)yy < (unsigned)HH) {
                const float* row = ipl + yy * WW;
                float v[6];
#pragma unroll
                for (int j = 0; j < 6; ++j) {
                    int xx = ox - 1 + j;
                    v[j] = ((unsigned)xx < (unsigned)WW) ? row[xx] : 0.f;
                }
#pragma unroll
                for (int kx = 0; kx < 3; ++kx) {
                    float wv = w18[i * 9 + ky * 3 + kx];
                    a0 += wv * v[kx]; a1 += wv * v[kx + 1];
                    a2 += wv * v[kx + 2]; a3 += wv * v[kx + 3];
                }
            }
        }
    }
    float4 r = make_float4(a0, a1, a2, a3);
    *(float4*)(out + ((long)(b * C2 + co)) * PP + p) = r;
}

// ---------------- fused avgpool 2x2 + bf16 + transpose: poolb[b][px48][ci] ---------------
__global__ __launch_bounds__(256) void avgpool_bf16_kernel(
    const float* __restrict__ qkv2, const float* __restrict__ y, ushort_t* __restrict__ poolb)
{
    __shared__ __align__(16) ushort_t sT[64 * 392];
    int b = blockIdx.y;
    int px0 = blockIdx.x * 64;
    int t = threadIdx.x;
    for (int idx = t; idx < 384 * 64; idx += 256) {
        int ci = idx >> 6, px = idx & 63;
        int p = px0 + px;
        int oy = p / 48, ox = p - oy * 48;
        const float* base = (ci < CC) ? qkv2 + ((long)(b * C2 + ci)) * PP
                                      : y + ((long)(b * CC + ci - CC)) * PP;
        const float* ipl = base + (oy * 2) * WW + ox * 2;
        float v = 0.25f * (ipl[0] + ipl[1] + ipl[WW] + ipl[WW + 1]);
        sT[px * 392 + ci] = f2bf(v);
    }
    __syncthreads();
    int px = t >> 2, qr = t & 3;
    ushort_t* dst = poolb + ((long)b * 2304 + px0 + px) * C2 + qr * 96;
    const ushort_t* srcl = sT + px * 392 + qr * 96;
#pragma unroll
    for (int k = 0; k < 96; k += 8)
        *(uint4*)(dst + k) = *(const uint4*)(srcl + k);
}

// ---------------- conv48 MFMA: valid 3x3 on 48x48 -> 46x46, Cin=Cout=384 -----------------
__global__ __launch_bounds__(256) void conv48_mfma_kernel(
    const ushort_t* __restrict__ poolb, const ushort_t* __restrict__ wb,
    float* __restrict__ out)
{
    __shared__ __align__(16) ushort_t sB[288 * 20];
    __shared__ __align__(16) ushort_t sW[1152 * 20];
    int b = blockIdx.z;
    int co0 = blockIdx.y * 128;
    int y0 = blockIdx.x * 4;
    int t = threadIdx.x;
    int w = t >> 6, lane = t & 63;
    int n = lane & 31, q = lane >> 5;
    int wc = w & 1, wn = w >> 1;

    int pidx[3], rr[3], ccx[3];
#pragma unroll
    for (int xg = 0; xg < 3; ++xg) {
        int p = (wn * 3 + xg) * 32 + n;
        int pc = min(p, 183);
        pidx[xg] = p;
        rr[xg] = pc / 46;
        ccx[xg] = pc - rr[xg] * 46;
    }

    floatx16 acc[2][3];
#pragma unroll
    for (int a = 0; a < 2; ++a)
#pragma unroll
        for (int xg = 0; xg < 3; ++xg) acc[a][xg] = (floatx16)(0.f);

    const ushort_t* poolb_b = poolb + (long)b * 2304 * C2;

    for (int ci0 = 0; ci0 < C2; ci0 += 16) {
        __syncthreads();
        for (int c = t; c < 288; c += 256) {
            int r = c / 48, col = c - r * 48;
            int iy = y0 + r;
            ushort_t* d = sB + c * 20;
            if (iy < 48) {
                const ushort_t* s = poolb_b + ((long)(iy * 48 + col)) * C2 + ci0;
                uint4 v0 = *(const uint4*)(s);
                uint4 v1 = *(const uint4*)(s + 8);
                *(uint2*)(d + 0)  = make_uint2(v0.x, v0.y);
                *(uint2*)(d + 4)  = make_uint2(v0.z, v0.w);
                *(uint2*)(d + 8)  = make_uint2(v1.x, v1.y);
                *(uint2*)(d + 12) = make_uint2(v1.z, v1.w);
            } else {
                uint2 z = make_uint2(0u, 0u);
                *(uint2*)(d + 0) = z; *(uint2*)(d + 4) = z;
                *(uint2*)(d + 8) = z; *(uint2*)(d + 12) = z;
            }
        }
        for (int c = t; c < 1152; c += 256) {
            int tap = c >> 7, co = c & 127;
            const ushort_t* s = wb + ((long)(tap * C2 + co0 + co)) * C2 + ci0;
            ushort_t* d = sW + c * 20;
            uint4 v0 = *(const uint4*)(s);
            uint4 v1 = *(const uint4*)(s + 8);
            *(uint2*)(d + 0)  = make_uint2(v0.x, v0.y);
            *(uint2*)(d + 4)  = make_uint2(v0.z, v0.w);
            *(uint2*)(d + 8)  = make_uint2(v1.x, v1.y);
            *(uint2*)(d + 12) = make_uint2(v1.z, v1.w);
        }
        __syncthreads();
#pragma unroll
        for (int ky = 0; ky < 3; ++ky) {
#pragma unroll
            for (int kx = 0; kx < 3; ++kx) {
                int tap = ky * 3 + kx;
                bf16x8 af[2], bfm[3];
#pragma unroll
                for (int a = 0; a < 2; ++a) {
                    const ushort_t* p = sW + (tap * 128 + (wc * 2 + a) * 32 + n) * 20 + q * 8;
                    uint2 lo = *(const uint2*)(p);
                    uint2 hi = *(const uint2*)(p + 4);
                    af[a] = __builtin_bit_cast(bf16x8, make_uint4(lo.x, lo.y, hi.x, hi.y));
                }
#pragma unroll
                for (int xg = 0; xg < 3; ++xg) {
                    int cell = (rr[xg] + ky) * 48 + ccx[xg] + kx;
                    const ushort_t* p = sB + cell * 20 + q * 8;
                    uint2 lo = *(const uint2*)(p);
                    uint2 hi = *(const uint2*)(p + 4);
                    bfm[xg] = __builtin_bit_cast(bf16x8, make_uint4(lo.x, lo.y, hi.x, hi.y));
                }
#pragma unroll
                for (int a = 0; a < 2; ++a)
#pragma unroll
                    for (int xg = 0; xg < 3; ++xg)
                        acc[a][xg] = __builtin_amdgcn_mfma_f32_32x32x16_bf16(
                            af[a], bfm[xg], acc[a][xg], 0, 0, 0);
            }
        }
    }

#pragma unroll
    for (int a = 0; a < 2; ++a) {
        int cobase = co0 + (wc * 2 + a) * 32;
#pragma unroll
        for (int xg = 0; xg < 3; ++xg) {
            int oy = y0 + rr[xg], ox = ccx[xg];
            if (pidx[xg] >= 184 || oy >= 46) continue;
#pragma unroll
            for (int r = 0; r < 16; ++r) {
                int row = (r & 3) + 8 * (r >> 2) + 4 * q;
                out[((long)(b * C2 + cobase + row)) * 2116 + oy * 46 + ox] = acc[a][xg][r];
            }
        }
    }
}

// ---------------- cvt_cat: catb[b][px][ci] bf16 from cat(q=qkv2[0:192], y) ----------------
__global__ __launch_bounds__(256) void cvt_cat_kernel(
    const float* __restrict__ qkv2, const float* __restrict__ y, ushort_t* __restrict__ catb)
{
    __shared__ __align__(16) ushort_t sT[64 * 392];
    int b = blockIdx.y;
    int px0 = blockIdx.x * 64;
    int t = threadIdx.x;
    for (int idx = t; idx < 384 * 64; idx += 256) {
        int ci = idx >> 6, px = idx & 63;
        const float* src = (ci < CC) ? qkv2 + ((long)(b * C2 + ci)) * PP
                                     : y + ((long)(b * CC + ci - CC)) * PP;
        sT[px * 392 + ci] = f2bf(src[px0 + px]);
    }
    __syncthreads();
    int px = t >> 2, qr = t & 3;
    ushort_t* dst = catb + ((long)b * PP + px0 + px) * C2 + qr * 96;
    const ushort_t* srcl = sT + px * 392 + qr * 96;
#pragma unroll
    for (int k = 0; k < 96; k += 8)
        *(uint4*)(dst + k) = *(const uint4*)(srcl + k);
}

// ---------------- prep_w: Wb[tap][co][ci] bf16 from w[co][ci][tap]  (384x384x9) -----------
__global__ __launch_bounds__(256) void prep_w_kernel(
    const float* __restrict__ w, ushort_t* __restrict__ wb)
{
    int i = blockIdx.x * 256 + threadIdx.x;
    int ci = i % 384; int r = i / 384; int co = r % 384; int tap = r / 384;
    wb[i] = f2bf(w[((long)co * 384 + ci) * 9 + tap]);
}

// ---------------- prep_w4: Wb4[tap][co(32 pad)][ci] bf16 from k4_w[18][384][tap] ----------
__global__ __launch_bounds__(256) void prep_w4_kernel(
    const float* __restrict__ w, ushort_t* __restrict__ wb)
{
    int i = blockIdx.x * 256 + threadIdx.x;      // over 9*32*384
    int ci = i % 384; int r = i / 384; int co = r % 32; int tap = r / 32;
    wb[i] = (co < 18) ? f2bf(w[((long)co * 384 + ci) * 9 + tap]) : (ushort_t)0;
}

// ---------------- conv96 MFMA: scb = bf16 px-major [conv3x3(cat) * sigmoid(...)] ---------
__global__ __launch_bounds__(256) void conv96_mfma_kernel(
    const ushort_t* __restrict__ catb, const ushort_t* __restrict__ wb,
    const float* __restrict__ qkv2, const float* __restrict__ yy,
    const float* __restrict__ k2out, ushort_t* __restrict__ scb)
{
    __shared__ __align__(16) ushort_t sB[392 * 20];
    __shared__ __align__(16) ushort_t sW[1152 * 20];
    int b = blockIdx.z;
    int co0 = blockIdx.y * 128;
    int y0 = blockIdx.x * 2;
    int t = threadIdx.x;
    int w = t >> 6, lane = t & 63;
    int n = lane & 31, q = lane >> 5;
    int wc = w & 1;
    int wr = w >> 1;

    floatx16 acc[2][3];
#pragma unroll
    for (int a = 0; a < 2; ++a)
#pragma unroll
        for (int xg = 0; xg < 3; ++xg) acc[a][xg] = (floatx16)(0.f);

    const ushort_t* catb_b = catb + (long)b * PP * C2;

    for (int ci0 = 0; ci0 < C2; ci0 += 16) {
        __syncthreads();
        for (int c = t; c < 392; c += 256) {
            int r = c / 98, col = c - r * 98;
            int iy = y0 - 1 + r, ix = col - 1;
            ushort_t* d = sB + c * 20;
            if (iy >= 0 && iy < HH && ix >= 0 && ix < WW) {
                const ushort_t* s = catb_b + ((long)(iy * WW + ix)) * C2 + ci0;
                uint4 v0 = *(const uint4*)(s);
                uint4 v1 = *(const uint4*)(s + 8);
                *(uint2*)(d + 0)  = make_uint2(v0.x, v0.y);
                *(uint2*)(d + 4)  = make_uint2(v0.z, v0.w);
                *(uint2*)(d + 8)  = make_uint2(v1.x, v1.y);
                *(uint2*)(d + 12) = make_uint2(v1.z, v1.w);
            } else {
                uint2 z = make_uint2(0u, 0u);
                *(uint2*)(d + 0) = z; *(uint2*)(d + 4) = z;
                *(uint2*)(d + 8) = z; *(uint2*)(d + 12) = z;
            }
        }
        for (int c = t; c < 1152; c += 256) {
            int tap = c >> 7, co = c & 127;
            const ushort_t* s = wb + ((long)(tap * C2 + co0 + co)) * C2 + ci0;
            ushort_t* d = sW + c * 20;
            uint4 v0 = *(const uint4*)(s);
            uint4 v1 = *(const uint4*)(s + 8);
            *(uint2*)(d + 0)  = make_uint2(v0.x, v0.y);
            *(uint2*)(d + 4)  = make_uint2(v0.z, v0.w);
            *(uint2*)(d + 8)  = make_uint2(v1.x, v1.y);
            *(uint2*)(d + 12) = make_uint2(v1.z, v1.w);
        }
        __syncthreads();
#pragma unroll
        for (int ky = 0; ky < 3; ++ky) {
#pragma unroll
            for (int kx = 0; kx < 3; ++kx) {
                int tap = ky * 3 + kx;
                bf16x8 af[2], bfm[3];
#pragma unroll
                for (int a = 0; a < 2; ++a) {
                    const ushort_t* p = sW + (tap * 128 + (wc * 2 + a) * 32 + n) * 20 + q * 8;
                    uint2 lo = *(const uint2*)(p);
                    uint2 hi = *(const uint2*)(p + 4);
                    af[a] = __builtin_bit_cast(bf16x8, make_uint4(lo.x, lo.y, hi.x, hi.y));
                }
#pragma unroll
                for (int xg = 0; xg < 3; ++xg) {
                    int col = xg * 32 + n + kx;
                    const ushort_t* p = sB + ((wr + ky) * 98 + col) * 20 + q * 8;
                    uint2 lo = *(const uint2*)(p);
                    uint2 hi = *(const uint2*)(p + 4);
                    bfm[xg] = __builtin_bit_cast(bf16x8, make_uint4(lo.x, lo.y, hi.x, hi.y));
                }
#pragma unroll
                for (int a = 0; a < 2; ++a)
#pragma unroll
                    for (int xg = 0; xg < 3; ++xg)
                        acc[a][xg] = __builtin_amdgcn_mfma_f32_32x32x16_bf16(
                            af[a], bfm[xg], acc[a][xg], 0, 0, 0);
            }
        }
    }

    // epilogue: scb[b][px][co] = bf16( acc * sigmoid(cat + nearest(k2out)) )
    int yl = y0 + wr;
    int iy46 = (yl * 46) / 96;
#pragma unroll
    for (int a = 0; a < 2; ++a) {
        int cobase = co0 + (wc * 2 + a) * 32;
#pragma unroll
        for (int xg = 0; xg < 3; ++xg) {
            int x = xg * 32 + n;
            int ix46 = (x * 46) / 96;
            ushort_t* dst = scb + ((long)(b * PP + yl * WW + x)) * C2;
#pragma unroll
            for (int g = 0; g < 4; ++g) {
                int cog = cobase + 8 * g + 4 * q;
                ushort_t pk[4];
#pragma unroll
                for (int j = 0; j < 4; ++j) {
                    int co = cog + j;
                    const float* gsrc = (co < CC) ? qkv2 + ((long)(b * C2 + co)) * PP
                                                  : yy + ((long)(b * CC + co - CC)) * PP;
                    float kv = k2out[((long)(b * C2 + co)) * 2116 + iy46 * 46 + ix46];
                    float gg = gsrc[yl * WW + x] + kv;
                    pk[j] = f2bf(acc[a][xg][4 * g + j] * sigmoidf_(gg));
                }
                *(uint2*)(dst + cog) = *(uint2*)pk;
            }
        }
    }
}

// ---------------- k4 MFMA: offs(18ch fp32) = conv3x3(scb), M=32 pad ----------------------
__global__ __launch_bounds__(384) void k4_mfma_kernel(
    const ushort_t* __restrict__ scb, const ushort_t* __restrict__ wb4,
    float* __restrict__ out)
{
    __shared__ __align__(16) ushort_t sB[392 * 20];
    __shared__ __align__(16) ushort_t sW[288 * 20];
    int b = blockIdx.y;
    int y0 = blockIdx.x * 2;
    int t = threadIdx.x;
    int w = t / 64, lane = t & 63;
    int n = lane & 31, q = lane >> 5;
    int wr = w / 3, xg = w - wr * 3;

    floatx16 acc = (floatx16)(0.f);
    const ushort_t* scb_b = scb + (long)b * PP * C2;

    for (int ci0 = 0; ci0 < C2; ci0 += 16) {
        __syncthreads();
        for (int c = t; c < 392; c += 384) {
            int r = c / 98, col = c - r * 98;
            int iy = y0 - 1 + r, ix = col - 1;
            ushort_t* d = sB + c * 20;
            if (iy >= 0 && iy < HH && ix >= 0 && ix < WW) {
                const ushort_t* s = scb_b + ((long)(iy * WW + ix)) * C2 + ci0;
                uint4 v0 = *(const uint4*)(s);
                uint4 v1 = *(const uint4*)(s + 8);
                *(uint2*)(d + 0)  = make_uint2(v0.x, v0.y);
                *(uint2*)(d + 4)  = make_uint2(v0.z, v0.w);
                *(uint2*)(d + 8)  = make_uint2(v1.x, v1.y);
                *(uint2*)(d + 12) = make_uint2(v1.z, v1.w);
            } else {
                uint2 z = make_uint2(0u, 0u);
                *(uint2*)(d + 0) = z; *(uint2*)(d + 4) = z;
                *(uint2*)(d + 8) = z; *(uint2*)(d + 12) = z;
            }
        }
        if (t < 288) {
            int c = t;
            const ushort_t* s = wb4 + (long)c * C2 + ci0;
            ushort_t* d = sW + c * 20;
            uint4 v0 = *(const uint4*)(s);
            uint4 v1 = *(const uint4*)(s + 8);
            *(uint2*)(d + 0)  = make_uint2(v0.x, v0.y);
            *(uint2*)(d + 4)  = make_uint2(v0.z, v0.w);
            *(uint2*)(d + 8)  = make_uint2(v1.x, v1.y);
            *(uint2*)(d + 12) = make_uint2(v1.z, v1.w);
        }
        __syncthreads();
#pragma unroll
        for (int ky = 0; ky < 3; ++ky) {
#pragma unroll
            for (int kx = 0; kx < 3; ++kx) {
                int tap = ky * 3 + kx;
                const ushort_t* pa = sW + (tap * 32 + n) * 20 + q * 8;
                uint2 alo = *(const uint2*)(pa);
                uint2 ahi = *(const uint2*)(pa + 4);
                bf16x8 af = __builtin_bit_cast(bf16x8, make_uint4(alo.x, alo.y, ahi.x, ahi.y));
                int col = xg * 32 + n + kx;
                const ushort_t* pb = sB + ((wr + ky) * 98 + col) * 20 + q * 8;
                uint2 blo = *(const uint2*)(pb);
                uint2 bhi = *(const uint2*)(pb + 4);
                bf16x8 bf = __builtin_bit_cast(bf16x8, make_uint4(blo.x, blo.y, bhi.x, bhi.y));
                acc = __builtin_amdgcn_mfma_f32_32x32x16_bf16(af, bf, acc, 0, 0, 0);
            }
        }
    }

    int yl = y0 + wr;
    int x = xg * 32 + n;
#pragma unroll
    for (int r = 0; r < 16; ++r) {
        int row = (r & 3) + 8 * (r >> 2) + 4 * q;
        if (row < 18)
            out[((long)(b * 18 + row)) * PP + yl * WW + x] = acc[r];
    }
}

// ---------------- deformable conv, LDS-tiled ---------------------------------------------
// grid (36 tiles 16x16, 8 g, B); block 256. Stage 24 ch x 22x22 halo window in LDS
// (edge-clamped values); per-corner fallback to global gather when offset escapes window.
#define DW 22
__global__ __launch_bounds__(256) void deform_kernel(
    const float* __restrict__ q, const float* __restrict__ offs,
    const float* __restrict__ w, const float* __restrict__ bias, float* __restrict__ out)
{
    __shared__ float sQ[24 * DW * DW];   // [ci][sy][sx], 46.5 KB
    int b = blockIdx.z, g = blockIdx.y;
    int tile = blockIdx.x;
    int ty0 = (tile / 6) * 16, tx0 = (tile % 6) * 16;
    int wy0 = ty0 - 3, wx0 = tx0 - 3;
    int t = threadIdx.x;
    int oy = ty0 + (t >> 4), ox = tx0 + (t & 15);
    int p = oy * WW + ox;

    const float* qg = q + ((long)(b * C2 + g * 24)) * PP;
    // stage window (edge-clamped)
    for (int idx = t; idx < 24 * DW * DW; idx += 256) {
        int ci = idx / (DW * DW);
        int r = idx - ci * (DW * DW);
        int sy = r / DW, sx = r - sy * DW;
        int syc = min(max(wy0 + sy, 0), HH - 1);
        int sxc = min(max(wx0 + sx, 0), WW - 1);
        sQ[idx] = qg[(long)ci * PP + syc * WW + sxc];
    }
    __syncthreads();

    const float* ob = offs + (long)b * 18 * PP;
    float acc[24];
#pragma unroll
    for (int o = 0; o < 24; ++o) acc[o] = 0.f;

    for (int k = 0; k < 9; ++k) {
        float dy = ob[(2 * k) * PP + p];
        float dx = ob[(2 * k + 1) * PP + p];
        float mk = sigmoidf_(ob[k * PP + p]);
        float py = dy + (float)(oy - 1 + k / 3);
        float px = dx + (float)(ox - 1 + (k % 3));
        float fy = floorf(py), fx = floorf(px);
        int y0 = (int)fy, x0 = (int)fx;
        float ly = py - fy, lx = px - fx;
        float w00 = (1.f - ly) * (1.f - lx), w01 = (1.f - ly) * lx;
        float w10 = ly * (1.f - lx), w11 = ly * lx;
        bool vy0 = (y0 >= 0 && y0 <= HH - 1), vy1 = (y0 + 1 <= HH - 1) && (y0 + 1 >= 0);
        bool vx0 = (x0 >= 0 && x0 <= WW - 1), vx1 = (x0 + 1 <= WW - 1) && (x0 + 1 >= 0);
        w00 = (vy0 && vx0) ? w00 * mk : 0.f;
        w01 = (vy0 && vx1) ? w01 * mk : 0.f;
        w10 = (vy1 && vx0) ? w10 * mk : 0.f;
        w11 = (vy1 && vx1) ? w11 * mk : 0.f;
        float vals[24];
        if (y0 >= wy0 && y0 - wy0 <= DW - 2 && x0 >= wx0 && x0 - wx0 <= DW - 2) {
            int base = (y0 - wy0) * DW + (x0 - wx0);
#pragma unroll
            for (int ci = 0; ci < 24; ++ci) {
                const float* s = sQ + ci * (DW * DW) + base;
                vals[ci] = w00 * s[0] + w01 * s[1] + w10 * s[DW] + w11 * s[DW + 1];
            }
        } else {
            int y0c = min(max(y0, 0), HH - 1), y1c = min(max(y0 + 1, 0), HH - 1);
            int x0c = min(max(x0, 0), WW - 1), x1c = min(max(x0 + 1, 0), WW - 1);
            int i00 = y0c * WW + x0c, i01 = y0c * WW + x1c;
            int i10 = y1c * WW + x0c, i11 = y1c * WW + x1c;
#pragma unroll
            for (int ci = 0; ci < 24; ++ci) {
                const float* qp = qg + (long)ci * PP;
                vals[ci] = w00 * qp[i00] + w01 * qp[i01] + w10 * qp[i10] + w11 * qp[i11];
            }
        }
        const float* wg = w + (long)g * 24 * 216 + k;
#pragma unroll
        for (int o = 0; o < 24; ++o) {
            const float* wr = wg + (long)o * 216;
            float s = acc[o];
#pragma unroll
            for (int ci = 0; ci < 24; ++ci) s += wr[ci * 9] * vals[ci];
            acc[o] = s;
        }
    }
#pragma unroll
    for (int o = 0; o < 24; ++o)
        out[((long)(b * CC + g * 24 + o)) * PP + p] = acc[o] + bias[g * 24 + o];
}

// ---------------- L2 norms of q and k rows -----------------------------------------------
__global__ __launch_bounds__(256) void norm_kernel(
    const float* __restrict__ q, const float* __restrict__ kb, float* __restrict__ norms)
{
    int c = blockIdx.x, b = blockIdx.y, which = blockIdx.z;
    const float* src = (which == 0) ? q + ((long)(b * C2 + c)) * PP
                                    : kb + ((long)(b * CC + c)) * PP;
    float s = 0.f;
    for (int n = threadIdx.x * 4; n < PP; n += 1024) {
        float4 v = *(const float4*)(src + n);
        s += v.x * v.x + v.y * v.y + v.z * v.z + v.w * v.w;
    }
    __shared__ float red[256];
    red[threadIdx.x] = s;
    __syncthreads();
    for (int st = 128; st > 0; st >>= 1) {
        if (threadIdx.x < st) red[threadIdx.x] += red[threadIdx.x + st];
        __syncthreads();
    }
    if (threadIdx.x == 0)
        norms[((long)which * BB + b) * CC + c] = fmaxf(sqrtf(red[0]), 1e-12f);
}

// ---------------- attention logits + softmax ---------------------------------------------
__global__ __launch_bounds__(256) void attn_kernel(
    const float* __restrict__ q, const float* __restrict__ kb,
    const float* __restrict__ norms, const float* __restrict__ temp,
    float* __restrict__ attn)
{
    int c = blockIdx.x, h = blockIdx.y, b = blockIdx.z;
    const float* qp = q + ((long)(b * C2 + h * 24 + c)) * PP;
    const float* kbase = kb + ((long)(b * CC + h * 24)) * PP;
    float part[24];
#pragma unroll
    for (int d = 0; d < 24; ++d) part[d] = 0.f;
    for (int n = threadIdx.x * 4; n < PP; n += 1024) {
        float4 qv = *(const float4*)(qp + n);
#pragma unroll
        for (int d = 0; d < 24; ++d) {
            float4 kv = *(const float4*)(kbase + (long)d * PP + n);
            part[d] += qv.x * kv.x + qv.y * kv.y + qv.z * kv.z + qv.w * kv.w;
        }
    }
    __shared__ float lred[4][24];
    __shared__ float logits[24];
    int lane = threadIdx.x & 63, wv = threadIdx.x >> 6;
#pragma unroll
    for (int d = 0; d < 24; ++d) {
        float x = part[d];
        for (int off = 32; off > 0; off >>= 1) x += __shfl_down(x, off, 64);
        if (lane == 0) lred[wv][d] = x;
    }
    __syncthreads();
    if (threadIdx.x < 24) {
        int d = threadIdx.x;
        float tot = lred[0][d] + lred[1][d] + lred[2][d] + lred[3][d];
        float nq = norms[(long)b * CC + h * 24 + c];
        float nk = norms[(long)(BB + b) * CC + h * 24 + d];
        logits[d] = tot / (nq * nk) * temp[h];
    }
    __syncthreads();
    if (threadIdx.x < 24) {
        int d = threadIdx.x;
        float mx = -3.4e38f;
#pragma unroll
        for (int j = 0; j < 24; ++j) mx = fmaxf(mx, logits[j]);
        float sum = 0.f;
#pragma unroll
        for (int j = 0; j < 24; ++j) sum += expf(logits[j] - mx);
        attn[(((long)(b * 8 + h) * 24) + c) * 24 + d] = expf(logits[d] - mx) / sum;
    }
}

// ---------------- attn @ v ----------------------------------------------------------------
__global__ __launch_bounds__(256) void attn_apply_kernel(
    const float* __restrict__ attn, const float* __restrict__ qkv2, float* __restrict__ out)
{
    int b = blockIdx.z, ch = blockIdx.y;
    int h = ch / 24, c = ch - h * 24;
    int n = blockIdx.x * 1024 + threadIdx.x * 4;
    const float* arow = attn + (((long)(b * 8 + h) * 24) + c) * 24;
    const float* vbase = qkv2 + ((long)(b * C2) + CC + h * 24) * PP;
    float4 acc = make_float4(0.f, 0.f, 0.f, 0.f);
#pragma unroll
    for (int d = 0; d < 24; ++d) {
        float a = arow[d];
        float4 vv = *(const float4*)(vbase + (long)d * PP + n);
        acc.x += a * vv.x; acc.y += a * vv.y; acc.z += a * vv.z; acc.w += a * vv.w;
    }
    *(float4*)(out + ((long)(b * CC + ch)) * PP + n) = acc;
}

// =========================================================================================
extern "C" void kernel_launch(void* const* d_in, const int* in_sizes, int n_in,
                              void* d_out, int out_size, void* d_ws, size_t ws_size,
                              hipStream_t stream)
{
    const float* x          = (const float*)d_in[0];
    const float* y          = (const float*)d_in[1];
    const float* temp       = (const float*)d_in[2];
    const float* qkv_w      = (const float*)d_in[3];
    const float* qkv_conv_w = (const float*)d_in[4];
    const float* proj_w     = (const float*)d_in[5];
    const float* k2_w       = (const float*)d_in[6];
    const float* k3_w       = (const float*)d_in[7];
    const float* k4_w       = (const float*)d_in[8];
    const float* deform_w   = (const float*)d_in[9];
    const float* deform_b   = (const float*)d_in[10];
    const float* pw_w       = (const float*)d_in[11];
    const float* pw_b       = (const float*)d_in[12];

    float* ws = (float*)d_ws;
    const long SZ_FULL = (long)BB * C2 * PP;     // 14,155,776
    const long SZ_HALF = (long)BB * CC * PP;     //  7,077,888

    float* bufA   = ws;                                   // qkv1 / wb2 / scb / (kbuf | feat,attnout)
    float* qkv2   = ws + SZ_FULL;
    float* k2out  = ws + 2 * SZ_FULL;                     // B*384*2116
    float* ovl    = k2out + (long)BB * C2 * 2116;
    ushort_t* poolb = (ushort_t*)ovl;
    ushort_t* catb  = (ushort_t*)ovl;
    float* offs   = ovl;                                  // B*18*PP
    float* norms  = offs + (long)BB * 18 * PP;
    float* attnm  = norms + 2 * BB * CC;
    ushort_t* wbuf = (ushort_t*)(ovl + SZ_HALF);          // k3 weights bf16 (663,552 f)
    ushort_t* wb4  = (ushort_t*)(ovl + SZ_HALF + 663552); // k4 weights bf16 (55,296 f)

    float* qkv1    = bufA;
    ushort_t* wb2  = (ushort_t*)bufA;   // k2 weights bf16 (qkv1 dead after disp 2)
    ushort_t* scb  = (ushort_t*)bufA;   // sc bf16 px-major (first SZ_HALF floats)
    float* kbuf    = bufA;
    float* feat    = bufA + SZ_HALF;
    float* attnout = bufA + SZ_HALF;

    // 1. qkv = conv1x1(x, qkv_w)
    conv1x1_kernel<CC, false, false><<<dim3(9, 24, BB), 256, 0, stream>>>(
        x, qkv_w, nullptr, qkv1, (long)CC * PP, (long)C2 * PP);
    // 2. qkv = grouped 3x3 (groups=192), 4 px/thread
    dwconv_kernel<<<dim3(9, C2, BB), 256, 0, stream>>>(qkv1, qkv_conv_w, qkv2);
    // 3. poolb = bf16 px-major avgpool2(cat[q,y])   (qkv1 now dead)
    avgpool_bf16_kernel<<<dim3(36, BB), 256, 0, stream>>>(qkv2, y, poolb);
    // 4. wb2 = bf16 [tap][co][ci] k2 weights (into dead qkv1 space)
    prep_w_kernel<<<dim3(9 * 384 * 384 / 256), 256, 0, stream>>>(k2_w, wb2);
    // 5. k2out = conv3x3 valid (48->46)  -- MFMA
    conv48_mfma_kernel<<<dim3(12, 3, BB), 256, 0, stream>>>(poolb, wb2, k2out);
    // 6. weight preps: k3 and k4
    prep_w_kernel<<<dim3(9 * 384 * 384 / 256), 256, 0, stream>>>(k3_w, wbuf);
    prep_w4_kernel<<<dim3(9 * 32 * 384 / 256), 256, 0, stream>>>(k4_w, wb4);
    // 7. catb = bf16 transposed cat (overlays dead poolb)
    cvt_cat_kernel<<<dim3(144, BB), 256, 0, stream>>>(qkv2, y, catb);
    // 8. scb = bf16 px-major [conv3x3(cat,k3) * sigmoid(cat + resize(k2out))]  -- MFMA
    conv96_mfma_kernel<<<dim3(48, 3, BB), 256, 0, stream>>>(
        catb, wbuf, qkv2, y, k2out, scb);
    // 9. offset = conv3x3(scb, k4)  -- MFMA (overlays dead catb)
    k4_mfma_kernel<<<dim3(48, BB), 384, 0, stream>>>(scb, wb4, offs);
    // 10. feat = deform_conv(q, offset, mask, deform_w, deform_b) — LDS-tiled
    deform_kernel<<<dim3(36, 8, BB), 256, 0, stream>>>(qkv2, offs, deform_w, deform_b, feat);
    // 11. k = conv1x1(relu(feat), pw_w) + pw_b   (overwrites scb — dead after disp 9)
    conv1x1_kernel<CC, true, true><<<dim3(9, 12, BB), 256, 0, stream>>>(
        feat, pw_w, pw_b, kbuf, (long)CC * PP, (long)CC * PP);
    // 12. norms
    norm_kernel<<<dim3(CC, BB, 2), 256, 0, stream>>>(qkv2, kbuf, norms);
    // 13. attn
    attn_kernel<<<dim3(24, 8, BB), 256, 0, stream>>>(qkv2, kbuf, norms, temp, attnm);
    // 14. attnout = attn @ v
    attn_apply_kernel<<<dim3(9, CC, BB), 256, 0, stream>>>(attnm, qkv2, attnout);
    // 15. out = conv1x1(attnout, proj_w)
    conv1x1_kernel<CC, false, false><<<dim3(9, 12, BB), 256, 0, stream>>>(
        attnout, proj_w, nullptr, (float*)d_out, (long)CC * PP, (long)CC * PP);
}

// Round 6
// 1142.439 us; speedup vs baseline: 7.0685x; 1.0548x over previous
//
#include <hip/hip_runtime.h>
#include <math.h>

// Problem constants
#define BB 4
#define CC 192
#define HH 96
#define WW 96
#define PP (HH*WW)          // 9216
#define C2 (2*CC)           // 384

typedef unsigned short ushort_t;
typedef __bf16 bf16_t;
typedef bf16_t bf16x8 __attribute__((ext_vector_type(8)));
typedef float floatx16 __attribute__((ext_vector_type(16)));

__device__ __forceinline__ float sigmoidf_(float x) { return 1.f / (1.f + expf(-x)); }

__device__ __forceinline__ ushort_t f2bf(float f) {
    unsigned u = __builtin_bit_cast(unsigned, f);
    unsigned r = (u + 0x7fffu + ((u >> 16) & 1u)) >> 16;
    return (ushort_t)r;
}
__device__ __forceinline__ float bflo(unsigned u) {
    return __builtin_bit_cast(float, u << 16);
}
__device__ __forceinline__ float bfhi(unsigned u) {
    return __builtin_bit_cast(float, u & 0xffff0000u);
}

// ---------------- conv 1x1 ----------------------------------------------------------------
template<int CIN, bool RELU, bool HASB>
__global__ __launch_bounds__(256) void conv1x1_kernel(
    const float* __restrict__ in, const float* __restrict__ w,
    const float* __restrict__ bias, float* __restrict__ out,
    long in_bs, long out_bs)
{
    int b = blockIdx.z;
    int co0 = blockIdx.y * 16;
    int p = blockIdx.x * 1024 + threadIdx.x * 4;
    const float* ip = in + (long)b * in_bs + p;
    float4 acc[16];
#pragma unroll
    for (int j = 0; j < 16; ++j) acc[j] = make_float4(0.f, 0.f, 0.f, 0.f);
#pragma unroll 4
    for (int ci = 0; ci < CIN; ++ci) {
        float4 xv = *(const float4*)(ip + (long)ci * PP);
        if (RELU) {
            xv.x = fmaxf(xv.x, 0.f); xv.y = fmaxf(xv.y, 0.f);
            xv.z = fmaxf(xv.z, 0.f); xv.w = fmaxf(xv.w, 0.f);
        }
#pragma unroll
        for (int j = 0; j < 16; ++j) {
            float wv = w[(long)(co0 + j) * CIN + ci];
            acc[j].x += wv * xv.x; acc[j].y += wv * xv.y;
            acc[j].z += wv * xv.z; acc[j].w += wv * xv.w;
        }
    }
#pragma unroll
    for (int j = 0; j < 16; ++j) {
        if (HASB) {
            float bb = bias[co0 + j];
            acc[j].x += bb; acc[j].y += bb; acc[j].z += bb; acc[j].w += bb;
        }
        *(float4*)(out + (long)b * out_bs + (long)(co0 + j) * PP + p) = acc[j];
    }
}

// ---------------- grouped conv 3x3, groups=192, 2in->2out, pad 1, 4px/thread -------------
__global__ __launch_bounds__(256) void dwconv_kernel(
    const float* __restrict__ in, const float* __restrict__ w, float* __restrict__ out)
{
    int b = blockIdx.z, co = blockIdx.y;
    int p = (blockIdx.x * 256 + threadIdx.x) * 4;
    int oy = p / WW, ox = p - oy * WW;
    int g = co >> 1;
    const float* w18 = w + (long)co * 18;
    float a0 = 0.f, a1 = 0.f, a2 = 0.f, a3 = 0.f;
#pragma unroll
    for (int i = 0; i < 2; ++i) {
        const float* ipl = in + ((long)(b * C2 + 2 * g + i)) * PP;
#pragma unroll
        for (int ky = 0; ky < 3; ++ky) {
            int yy = oy - 1 + ky;
            if ((unsigned)yy < (unsigned)HH) {
                const float* row = ipl + yy * WW;
                float v[6];
#pragma unroll
                for (int j = 0; j < 6; ++j) {
                    int xx = ox - 1 + j;
                    v[j] = ((unsigned)xx < (unsigned)WW) ? row[xx] : 0.f;
                }
#pragma unroll
                for (int kx = 0; kx < 3; ++kx) {
                    float wv = w18[i * 9 + ky * 3 + kx];
                    a0 += wv * v[kx]; a1 += wv * v[kx + 1];
                    a2 += wv * v[kx + 2]; a3 += wv * v[kx + 3];
                }
            }
        }
    }
    float4 r = make_float4(a0, a1, a2, a3);
    *(float4*)(out + ((long)(b * C2 + co)) * PP + p) = r;
}

// ---------------- fused avgpool 2x2 + bf16 + transpose: poolb[b][px48][ci] ---------------
__global__ __launch_bounds__(256) void avgpool_bf16_kernel(
    const float* __restrict__ qkv2, const float* __restrict__ y, ushort_t* __restrict__ poolb)
{
    __shared__ __align__(16) ushort_t sT[64 * 392];
    int b = blockIdx.y;
    int px0 = blockIdx.x * 64;
    int t = threadIdx.x;
    for (int idx = t; idx < 384 * 64; idx += 256) {
        int ci = idx >> 6, px = idx & 63;
        int p = px0 + px;
        int oy = p / 48, ox = p - oy * 48;
        const float* base = (ci < CC) ? qkv2 + ((long)(b * C2 + ci)) * PP
                                      : y + ((long)(b * CC + ci - CC)) * PP;
        const float* ipl = base + (oy * 2) * WW + ox * 2;
        float v = 0.25f * (ipl[0] + ipl[1] + ipl[WW] + ipl[WW + 1]);
        sT[px * 392 + ci] = f2bf(v);
    }
    __syncthreads();
    int px = t >> 2, qr = t & 3;
    ushort_t* dst = poolb + ((long)b * 2304 + px0 + px) * C2 + qr * 96;
    const ushort_t* srcl = sT + px * 392 + qr * 96;
#pragma unroll
    for (int k = 0; k < 96; k += 8)
        *(uint4*)(dst + k) = *(const uint4*)(srcl + k);
}

// ---------------- packed weight prep: wpk[((tap*NG+cg)*24+chunk)*64 + n*2+q][8] -----------
// fragment element: co = cg*32+n, ci = chunk*16 + q*8 + j  (from w[co][ci][tap], 384 ci)
template<int NG>   // NG = COUT/32 groups; COUT rows valid = COUTV
__global__ __launch_bounds__(256) void prep_wpk_kernel(
    const float* __restrict__ w, ushort_t* __restrict__ wpk, int coutv)
{
    int i = blockIdx.x * 256 + threadIdx.x;      // over 9*NG*24*64*8
    int j = i & 7;
    int q = (i >> 3) & 1;
    int n = (i >> 4) & 31;
    int r = i >> 9;                               // tap*NG*24 + cg*24 + chunk
    int chunk = r % 24;
    int r2 = r / 24;
    int cg = r2 % NG;
    int tap = r2 / NG;
    int co = cg * 32 + n;
    int ci = chunk * 16 + q * 8 + j;
    wpk[i] = (co < coutv) ? f2bf(w[((long)co * 384 + ci) * 9 + tap]) : (ushort_t)0;
}

// ---------------- conv48 MFMA: valid 3x3 on 48x48 -> 46x46 (weights direct-global) -------
__global__ __launch_bounds__(256) void conv48_mfma_kernel(
    const ushort_t* __restrict__ poolb, const ushort_t* __restrict__ wpk,
    float* __restrict__ out)
{
    __shared__ __align__(16) ushort_t sB[288 * 20];
    int b = blockIdx.z;
    int co0 = blockIdx.y * 128;
    int cgb = blockIdx.y * 4;
    int y0 = blockIdx.x * 4;
    int t = threadIdx.x;
    int w = t >> 6, lane = t & 63;
    int n = lane & 31, q = lane >> 5;
    int wc = w & 1, wn = w >> 1;
    const uint4* wq = (const uint4*)wpk;

    int pidx[3], rr[3], ccx[3];
#pragma unroll
    for (int xg = 0; xg < 3; ++xg) {
        int p = (wn * 3 + xg) * 32 + n;
        int pc = min(p, 183);
        pidx[xg] = p;
        rr[xg] = pc / 46;
        ccx[xg] = pc - rr[xg] * 46;
    }

    floatx16 acc[2][3];
#pragma unroll
    for (int a = 0; a < 2; ++a)
#pragma unroll
        for (int xg = 0; xg < 3; ++xg) acc[a][xg] = (floatx16)(0.f);

    const ushort_t* poolb_b = poolb + (long)b * 2304 * C2;

    for (int m = 0; m < 24; ++m) {
        int ci0 = m * 16;
        __syncthreads();
        for (int c = t; c < 288; c += 256) {
            int r = c / 48, col = c - r * 48;
            int iy = y0 + r;
            ushort_t* d = sB + c * 20;
            if (iy < 48) {
                const ushort_t* s = poolb_b + ((long)(iy * 48 + col)) * C2 + ci0;
                uint4 v0 = *(const uint4*)(s);
                uint4 v1 = *(const uint4*)(s + 8);
                *(uint2*)(d + 0)  = make_uint2(v0.x, v0.y);
                *(uint2*)(d + 4)  = make_uint2(v0.z, v0.w);
                *(uint2*)(d + 8)  = make_uint2(v1.x, v1.y);
                *(uint2*)(d + 12) = make_uint2(v1.z, v1.w);
            } else {
                uint2 z = make_uint2(0u, 0u);
                *(uint2*)(d + 0) = z; *(uint2*)(d + 4) = z;
                *(uint2*)(d + 8) = z; *(uint2*)(d + 12) = z;
            }
        }
        __syncthreads();
#pragma unroll
        for (int ky = 0; ky < 3; ++ky) {
#pragma unroll
            for (int kx = 0; kx < 3; ++kx) {
                int tap = ky * 3 + kx;
                bf16x8 af[2], bfm[3];
#pragma unroll
                for (int a = 0; a < 2; ++a) {
                    uint4 v = wq[(long)((tap * 12 + cgb + wc * 2 + a) * 24 + m) * 64 + lane];
                    af[a] = __builtin_bit_cast(bf16x8, v);
                }
#pragma unroll
                for (int xg = 0; xg < 3; ++xg) {
                    int cell = (rr[xg] + ky) * 48 + ccx[xg] + kx;
                    const ushort_t* p = sB + cell * 20 + q * 8;
                    uint2 lo = *(const uint2*)(p);
                    uint2 hi = *(const uint2*)(p + 4);
                    bfm[xg] = __builtin_bit_cast(bf16x8, make_uint4(lo.x, lo.y, hi.x, hi.y));
                }
#pragma unroll
                for (int a = 0; a < 2; ++a)
#pragma unroll
                    for (int xg = 0; xg < 3; ++xg)
                        acc[a][xg] = __builtin_amdgcn_mfma_f32_32x32x16_bf16(
                            af[a], bfm[xg], acc[a][xg], 0, 0, 0);
            }
        }
    }

#pragma unroll
    for (int a = 0; a < 2; ++a) {
        int cobase = co0 + (wc * 2 + a) * 32;
#pragma unroll
        for (int xg = 0; xg < 3; ++xg) {
            int oy = y0 + rr[xg], ox = ccx[xg];
            if (pidx[xg] >= 184 || oy >= 46) continue;
#pragma unroll
            for (int r = 0; r < 16; ++r) {
                int row = (r & 3) + 8 * (r >> 2) + 4 * q;
                out[((long)(b * C2 + cobase + row)) * 2116 + oy * 46 + ox] = acc[a][xg][r];
            }
        }
    }
}

// ---------------- cvt_cat: catb[b][px][ci] bf16 from cat(q=qkv2[0:192], y) ----------------
__global__ __launch_bounds__(256) void cvt_cat_kernel(
    const float* __restrict__ qkv2, const float* __restrict__ y, ushort_t* __restrict__ catb)
{
    __shared__ __align__(16) ushort_t sT[64 * 392];
    int b = blockIdx.y;
    int px0 = blockIdx.x * 64;
    int t = threadIdx.x;
    for (int idx = t; idx < 384 * 64; idx += 256) {
        int ci = idx >> 6, px = idx & 63;
        const float* src = (ci < CC) ? qkv2 + ((long)(b * C2 + ci)) * PP
                                     : y + ((long)(b * CC + ci - CC)) * PP;
        sT[px * 392 + ci] = f2bf(src[px0 + px]);
    }
    __syncthreads();
    int px = t >> 2, qr = t & 3;
    ushort_t* dst = catb + ((long)b * PP + px0 + px) * C2 + qr * 96;
    const ushort_t* srcl = sT + px * 392 + qr * 96;
#pragma unroll
    for (int k = 0; k < 96; k += 8)
        *(uint4*)(dst + k) = *(const uint4*)(srcl + k);
}

// ---------------- conv96 MFMA: scb = bf16 px-major [conv3x3(cat) * sigmoid(...)] ---------
// weights direct-from-global packed fragments
__global__ __launch_bounds__(256) void conv96_mfma_kernel(
    const ushort_t* __restrict__ catb, const ushort_t* __restrict__ wpk,
    const float* __restrict__ qkv2, const float* __restrict__ yy,
    const float* __restrict__ k2out, ushort_t* __restrict__ scb)
{
    __shared__ __align__(16) ushort_t sB[392 * 20];
    int b = blockIdx.z;
    int co0 = blockIdx.y * 128;
    int cgb = blockIdx.y * 4;
    int y0 = blockIdx.x * 2;
    int t = threadIdx.x;
    int w = t >> 6, lane = t & 63;
    int n = lane & 31, q = lane >> 5;
    int wc = w & 1;
    int wr = w >> 1;
    const uint4* wq = (const uint4*)wpk;

    floatx16 acc[2][3];
#pragma unroll
    for (int a = 0; a < 2; ++a)
#pragma unroll
        for (int xg = 0; xg < 3; ++xg) acc[a][xg] = (floatx16)(0.f);

    const ushort_t* catb_b = catb + (long)b * PP * C2;

    for (int m = 0; m < 24; ++m) {
        int ci0 = m * 16;
        __syncthreads();
        for (int c = t; c < 392; c += 256) {
            int r = c / 98, col = c - r * 98;
            int iy = y0 - 1 + r, ix = col - 1;
            ushort_t* d = sB + c * 20;
            if (iy >= 0 && iy < HH && ix >= 0 && ix < WW) {
                const ushort_t* s = catb_b + ((long)(iy * WW + ix)) * C2 + ci0;
                uint4 v0 = *(const uint4*)(s);
                uint4 v1 = *(const uint4*)(s + 8);
                *(uint2*)(d + 0)  = make_uint2(v0.x, v0.y);
                *(uint2*)(d + 4)  = make_uint2(v0.z, v0.w);
                *(uint2*)(d + 8)  = make_uint2(v1.x, v1.y);
                *(uint2*)(d + 12) = make_uint2(v1.z, v1.w);
            } else {
                uint2 z = make_uint2(0u, 0u);
                *(uint2*)(d + 0) = z; *(uint2*)(d + 4) = z;
                *(uint2*)(d + 8) = z; *(uint2*)(d + 12) = z;
            }
        }
        __syncthreads();
#pragma unroll
        for (int ky = 0; ky < 3; ++ky) {
#pragma unroll
            for (int kx = 0; kx < 3; ++kx) {
                int tap = ky * 3 + kx;
                bf16x8 af[2], bfm[3];
#pragma unroll
                for (int a = 0; a < 2; ++a) {
                    uint4 v = wq[(long)((tap * 12 + cgb + wc * 2 + a) * 24 + m) * 64 + lane];
                    af[a] = __builtin_bit_cast(bf16x8, v);
                }
#pragma unroll
                for (int xg = 0; xg < 3; ++xg) {
                    int col = xg * 32 + n + kx;
                    const ushort_t* p = sB + ((wr + ky) * 98 + col) * 20 + q * 8;
                    uint2 lo = *(const uint2*)(p);
                    uint2 hi = *(const uint2*)(p + 4);
                    bfm[xg] = __builtin_bit_cast(bf16x8, make_uint4(lo.x, lo.y, hi.x, hi.y));
                }
#pragma unroll
                for (int a = 0; a < 2; ++a)
#pragma unroll
                    for (int xg = 0; xg < 3; ++xg)
                        acc[a][xg] = __builtin_amdgcn_mfma_f32_32x32x16_bf16(
                            af[a], bfm[xg], acc[a][xg], 0, 0, 0);
            }
        }
    }

    int yl = y0 + wr;
    int iy46 = (yl * 46) / 96;
#pragma unroll
    for (int a = 0; a < 2; ++a) {
        int cobase = co0 + (wc * 2 + a) * 32;
#pragma unroll
        for (int xg = 0; xg < 3; ++xg) {
            int x = xg * 32 + n;
            int ix46 = (x * 46) / 96;
            ushort_t* dst = scb + ((long)(b * PP + yl * WW + x)) * C2;
#pragma unroll
            for (int g = 0; g < 4; ++g) {
                int cog = cobase + 8 * g + 4 * q;
                ushort_t pk[4];
#pragma unroll
                for (int j = 0; j < 4; ++j) {
                    int co = cog + j;
                    const float* gsrc = (co < CC) ? qkv2 + ((long)(b * C2 + co)) * PP
                                                  : yy + ((long)(b * CC + co - CC)) * PP;
                    float kv = k2out[((long)(b * C2 + co)) * 2116 + iy46 * 46 + ix46];
                    float gg = gsrc[yl * WW + x] + kv;
                    pk[j] = f2bf(acc[a][xg][4 * g + j] * sigmoidf_(gg));
                }
                *(uint2*)(dst + cog) = *(uint2*)pk;
            }
        }
    }
}

// ---------------- k4 MFMA: offs(18ch fp32) = conv3x3(scb), M=32 pad ----------------------
__global__ __launch_bounds__(384) void k4_mfma_kernel(
    const ushort_t* __restrict__ scb, const ushort_t* __restrict__ wpk4,
    float* __restrict__ out)
{
    __shared__ __align__(16) ushort_t sB[392 * 20];
    int b = blockIdx.y;
    int y0 = blockIdx.x * 2;
    int t = threadIdx.x;
    int w = t / 64, lane = t & 63;
    int n = lane & 31, q = lane >> 5;
    int wr = w / 3, xg = w - wr * 3;
    const uint4* wq = (const uint4*)wpk4;

    floatx16 acc = (floatx16)(0.f);
    const ushort_t* scb_b = scb + (long)b * PP * C2;

    for (int m = 0; m < 24; ++m) {
        int ci0 = m * 16;
        __syncthreads();
        for (int c = t; c < 392; c += 384) {
            int r = c / 98, col = c - r * 98;
            int iy = y0 - 1 + r, ix = col - 1;
            ushort_t* d = sB + c * 20;
            if (iy >= 0 && iy < HH && ix >= 0 && ix < WW) {
                const ushort_t* s = scb_b + ((long)(iy * WW + ix)) * C2 + ci0;
                uint4 v0 = *(const uint4*)(s);
                uint4 v1 = *(const uint4*)(s + 8);
                *(uint2*)(d + 0)  = make_uint2(v0.x, v0.y);
                *(uint2*)(d + 4)  = make_uint2(v0.z, v0.w);
                *(uint2*)(d + 8)  = make_uint2(v1.x, v1.y);
                *(uint2*)(d + 12) = make_uint2(v1.z, v1.w);
            } else {
                uint2 z = make_uint2(0u, 0u);
                *(uint2*)(d + 0) = z; *(uint2*)(d + 4) = z;
                *(uint2*)(d + 8) = z; *(uint2*)(d + 12) = z;
            }
        }
        __syncthreads();
#pragma unroll
        for (int ky = 0; ky < 3; ++ky) {
#pragma unroll
            for (int kx = 0; kx < 3; ++kx) {
                int tap = ky * 3 + kx;
                uint4 v = wq[(long)((tap * 24) + m) * 64 + lane];
                bf16x8 af = __builtin_bit_cast(bf16x8, v);
                int col = xg * 32 + n + kx;
                const ushort_t* pb = sB + ((wr + ky) * 98 + col) * 20 + q * 8;
                uint2 blo = *(const uint2*)(pb);
                uint2 bhi = *(const uint2*)(pb + 4);
                bf16x8 bf = __builtin_bit_cast(bf16x8, make_uint4(blo.x, blo.y, bhi.x, bhi.y));
                acc = __builtin_amdgcn_mfma_f32_32x32x16_bf16(af, bf, acc, 0, 0, 0);
            }
        }
    }

    int yl = y0 + wr;
    int x = xg * 32 + n;
#pragma unroll
    for (int r = 0; r < 16; ++r) {
        int row = (r & 3) + 8 * (r >> 2) + 4 * q;
        if (row < 18)
            out[((long)(b * 18 + row)) * PP + yl * WW + x] = acc[r];
    }
}

// ---------------- deformable conv, bf16 LDS tile from catb -------------------------------
// grid (36 tiles 16x16, 8 g, B); block 256. Stage 24 ch (bf16, cell-major from catb) over
// 22x22 halo; per-corner fallback to global catb gather when offset escapes window.
#define DW 22
__global__ __launch_bounds__(256) void deform_kernel(
    const ushort_t* __restrict__ catb, const float* __restrict__ offs,
    const float* __restrict__ w, const float* __restrict__ bias, float* __restrict__ out)
{
    __shared__ __align__(16) ushort_t sQ[DW * DW * 24];   // [cell][ci], 23.2 KB
    int b = blockIdx.z, g = blockIdx.y;
    int tile = blockIdx.x;
    int ty0 = (tile / 6) * 16, tx0 = (tile % 6) * 16;
    int wy0 = ty0 - 3, wx0 = tx0 - 3;
    int t = threadIdx.x;
    int oy = ty0 + (t >> 4), ox = tx0 + (t & 15);
    int p = oy * WW + ox;

    const ushort_t* cb = catb + (long)b * PP * C2 + g * 24;
    // stage: 484 cells x 24 ci (48 B each) as 3 uint4 per cell
    for (int idx = t; idx < 484 * 3; idx += 256) {
        int cell = idx / 3, part = idx - cell * 3;
        int sy = cell / DW, sx = cell - sy * DW;
        int syc = min(max(wy0 + sy, 0), HH - 1);
        int sxc = min(max(wx0 + sx, 0), WW - 1);
        uint4 v = *(const uint4*)(cb + ((long)(syc * WW + sxc)) * C2 + part * 8);
        *(uint4*)(sQ + cell * 24 + part * 8) = v;
    }
    __syncthreads();

    const float* ob = offs + (long)b * 18 * PP;
    float acc[24];
#pragma unroll
    for (int o = 0; o < 24; ++o) acc[o] = 0.f;

    for (int k = 0; k < 9; ++k) {
        float dy = ob[(2 * k) * PP + p];
        float dx = ob[(2 * k + 1) * PP + p];
        float mk = sigmoidf_(ob[k * PP + p]);
        float py = dy + (float)(oy - 1 + k / 3);
        float px = dx + (float)(ox - 1 + (k % 3));
        float fy = floorf(py), fx = floorf(px);
        int y0 = (int)fy, x0 = (int)fx;
        float ly = py - fy, lx = px - fx;
        float w00 = (1.f - ly) * (1.f - lx), w01 = (1.f - ly) * lx;
        float w10 = ly * (1.f - lx), w11 = ly * lx;
        bool vy0 = (y0 >= 0 && y0 <= HH - 1), vy1 = (y0 + 1 <= HH - 1) && (y0 + 1 >= 0);
        bool vx0 = (x0 >= 0 && x0 <= WW - 1), vx1 = (x0 + 1 <= WW - 1) && (x0 + 1 >= 0);
        w00 = (vy0 && vx0) ? w00 * mk : 0.f;
        w01 = (vy0 && vx1) ? w01 * mk : 0.f;
        w10 = (vy1 && vx0) ? w10 * mk : 0.f;
        w11 = (vy1 && vx1) ? w11 * mk : 0.f;
        float vals[24];
        bool inwin = (y0 >= wy0) && (y0 - wy0 <= DW - 2) && (x0 >= wx0) && (x0 - wx0 <= DW - 2);
        if (inwin) {
            int c00 = (y0 - wy0) * DW + (x0 - wx0);
            const ushort_t* s00 = sQ + c00 * 24;
#pragma unroll
            for (int part = 0; part < 3; ++part) {
                uint4 A = *(const uint4*)(s00 + part * 8);
                uint4 Bv = *(const uint4*)(s00 + 24 + part * 8);
                uint4 Cv = *(const uint4*)(s00 + DW * 24 + part * 8);
                uint4 Dv = *(const uint4*)(s00 + DW * 24 + 24 + part * 8);
                const unsigned* au = (const unsigned*)&A;
                const unsigned* bu = (const unsigned*)&Bv;
                const unsigned* cu = (const unsigned*)&Cv;
                const unsigned* du = (const unsigned*)&Dv;
#pragma unroll
                for (int u = 0; u < 4; ++u) {
                    int ci = part * 8 + u * 2;
                    vals[ci]     = w00 * bflo(au[u]) + w01 * bflo(bu[u])
                                 + w10 * bflo(cu[u]) + w11 * bflo(du[u]);
                    vals[ci + 1] = w00 * bfhi(au[u]) + w01 * bfhi(bu[u])
                                 + w10 * bfhi(cu[u]) + w11 * bfhi(du[u]);
                }
            }
        } else {
            int y0c = min(max(y0, 0), HH - 1), y1c = min(max(y0 + 1, 0), HH - 1);
            int x0c = min(max(x0, 0), WW - 1), x1c = min(max(x0 + 1, 0), WW - 1);
            const ushort_t* p00 = cb + ((long)(y0c * WW + x0c)) * C2;
            const ushort_t* p01 = cb + ((long)(y0c * WW + x1c)) * C2;
            const ushort_t* p10 = cb + ((long)(y1c * WW + x0c)) * C2;
            const ushort_t* p11 = cb + ((long)(y1c * WW + x1c)) * C2;
#pragma unroll
            for (int part = 0; part < 3; ++part) {
                uint4 A = *(const uint4*)(p00 + part * 8);
                uint4 Bv = *(const uint4*)(p01 + part * 8);
                uint4 Cv = *(const uint4*)(p10 + part * 8);
                uint4 Dv = *(const uint4*)(p11 + part * 8);
                const unsigned* au = (const unsigned*)&A;
                const unsigned* bu = (const unsigned*)&Bv;
                const unsigned* cu = (const unsigned*)&Cv;
                const unsigned* du = (const unsigned*)&Dv;
#pragma unroll
                for (int u = 0; u < 4; ++u) {
                    int ci = part * 8 + u * 2;
                    vals[ci]     = w00 * bflo(au[u]) + w01 * bflo(bu[u])
                                 + w10 * bflo(cu[u]) + w11 * bflo(du[u]);
                    vals[ci + 1] = w00 * bfhi(au[u]) + w01 * bfhi(bu[u])
                                 + w10 * bfhi(cu[u]) + w11 * bfhi(du[u]);
                }
            }
        }
        const float* wg = w + (long)g * 24 * 216 + k;
#pragma unroll
        for (int o = 0; o < 24; ++o) {
            const float* wr = wg + (long)o * 216;
            float s = acc[o];
#pragma unroll
            for (int ci = 0; ci < 24; ++ci) s += wr[ci * 9] * vals[ci];
            acc[o] = s;
        }
    }
#pragma unroll
    for (int o = 0; o < 24; ++o)
        out[((long)(b * CC + g * 24 + o)) * PP + p] = acc[o] + bias[g * 24 + o];
}

// ---------------- L2 norms of q and k rows -----------------------------------------------
__global__ __launch_bounds__(256) void norm_kernel(
    const float* __restrict__ q, const float* __restrict__ kb, float* __restrict__ norms)
{
    int c = blockIdx.x, b = blockIdx.y, which = blockIdx.z;
    const float* src = (which == 0) ? q + ((long)(b * C2 + c)) * PP
                                    : kb + ((long)(b * CC + c)) * PP;
    float s = 0.f;
    for (int n = threadIdx.x * 4; n < PP; n += 1024) {
        float4 v = *(const float4*)(src + n);
        s += v.x * v.x + v.y * v.y + v.z * v.z + v.w * v.w;
    }
    __shared__ float red[256];
    red[threadIdx.x] = s;
    __syncthreads();
    for (int st = 128; st > 0; st >>= 1) {
        if (threadIdx.x < st) red[threadIdx.x] += red[threadIdx.x + st];
        __syncthreads();
    }
    if (threadIdx.x == 0)
        norms[((long)which * BB + b) * CC + c] = fmaxf(sqrtf(red[0]), 1e-12f);
}

// ---------------- attention logits + softmax ---------------------------------------------
__global__ __launch_bounds__(256) void attn_kernel(
    const float* __restrict__ q, const float* __restrict__ kb,
    const float* __restrict__ norms, const float* __restrict__ temp,
    float* __restrict__ attn)
{
    int c = blockIdx.x, h = blockIdx.y, b = blockIdx.z;
    const float* qp = q + ((long)(b * C2 + h * 24 + c)) * PP;
    const float* kbase = kb + ((long)(b * CC + h * 24)) * PP;
    float part[24];
#pragma unroll
    for (int d = 0; d < 24; ++d) part[d] = 0.f;
    for (int n = threadIdx.x * 4; n < PP; n += 1024) {
        float4 qv = *(const float4*)(qp + n);
#pragma unroll
        for (int d = 0; d < 24; ++d) {
            float4 kv = *(const float4*)(kbase + (long)d * PP + n);
            part[d] += qv.x * kv.x + qv.y * kv.y + qv.z * kv.z + qv.w * kv.w;
        }
    }
    __shared__ float lred[4][24];
    __shared__ float logits[24];
    int lane = threadIdx.x & 63, wv = threadIdx.x >> 6;
#pragma unroll
    for (int d = 0; d < 24; ++d) {
        float x = part[d];
        for (int off = 32; off > 0; off >>= 1) x += __shfl_down(x, off, 64);
        if (lane == 0) lred[wv][d] = x;
    }
    __syncthreads();
    if (threadIdx.x < 24) {
        int d = threadIdx.x;
        float tot = lred[0][d] + lred[1][d] + lred[2][d] + lred[3][d];
        float nq = norms[(long)b * CC + h * 24 + c];
        float nk = norms[(long)(BB + b) * CC + h * 24 + d];
        logits[d] = tot / (nq * nk) * temp[h];
    }
    __syncthreads();
    if (threadIdx.x < 24) {
        int d = threadIdx.x;
        float mx = -3.4e38f;
#pragma unroll
        for (int j = 0; j < 24; ++j) mx = fmaxf(mx, logits[j]);
        float sum = 0.f;
#pragma unroll
        for (int j = 0; j < 24; ++j) sum += expf(logits[j] - mx);
        attn[(((long)(b * 8 + h) * 24) + c) * 24 + d] = expf(logits[d] - mx) / sum;
    }
}

// ---------------- attn @ v ----------------------------------------------------------------
__global__ __launch_bounds__(256) void attn_apply_kernel(
    const float* __restrict__ attn, const float* __restrict__ qkv2, float* __restrict__ out)
{
    int b = blockIdx.z, ch = blockIdx.y;
    int h = ch / 24, c = ch - h * 24;
    int n = blockIdx.x * 1024 + threadIdx.x * 4;
    const float* arow = attn + (((long)(b * 8 + h) * 24) + c) * 24;
    const float* vbase = qkv2 + ((long)(b * C2) + CC + h * 24) * PP;
    float4 acc = make_float4(0.f, 0.f, 0.f, 0.f);
#pragma unroll
    for (int d = 0; d < 24; ++d) {
        float a = arow[d];
        float4 vv = *(const float4*)(vbase + (long)d * PP + n);
        acc.x += a * vv.x; acc.y += a * vv.y; acc.z += a * vv.z; acc.w += a * vv.w;
    }
    *(float4*)(out + ((long)(b * CC + ch)) * PP + n) = acc;
}

// =========================================================================================
extern "C" void kernel_launch(void* const* d_in, const int* in_sizes, int n_in,
                              void* d_out, int out_size, void* d_ws, size_t ws_size,
                              hipStream_t stream)
{
    const float* x          = (const float*)d_in[0];
    const float* y          = (const float*)d_in[1];
    const float* temp       = (const float*)d_in[2];
    const float* qkv_w      = (const float*)d_in[3];
    const float* qkv_conv_w = (const float*)d_in[4];
    const float* proj_w     = (const float*)d_in[5];
    const float* k2_w       = (const float*)d_in[6];
    const float* k3_w       = (const float*)d_in[7];
    const float* k4_w       = (const float*)d_in[8];
    const float* deform_w   = (const float*)d_in[9];
    const float* deform_b   = (const float*)d_in[10];
    const float* pw_w       = (const float*)d_in[11];
    const float* pw_b       = (const float*)d_in[12];

    float* ws = (float*)d_ws;
    const long SZ_FULL = (long)BB * C2 * PP;     // 14,155,776
    const long SZ_HALF = (long)BB * CC * PP;     //  7,077,888

    float* bufA   = ws;                                   // qkv1 / wb2 / scb / (kbuf | feat)
    float* qkv2   = ws + SZ_FULL;
    float* k2out  = ws + 2 * SZ_FULL;                     // B*384*2116
    float* ovl    = k2out + (long)BB * C2 * 2116;
    // ovl region: poolb (disp3-5) then catb (disp7-10); after catb: wbuf/wb4/offs/norms/attnm
    ushort_t* poolb = (ushort_t*)ovl;
    ushort_t* catb  = (ushort_t*)ovl;
    ushort_t* wbuf = (ushort_t*)(ovl + SZ_HALF);          // k3 packed (1,327,104 us = 663,552 f)
    ushort_t* wb4  = (ushort_t*)(ovl + SZ_HALF + 663552); // k4 packed (110,592 us = 55,296 f)
    float* offs   = ovl + SZ_HALF + 663552 + 55296;       // B*18*PP = 663,552 f
    float* norms  = offs + (long)BB * 18 * PP;
    float* attnm  = norms + 2 * BB * CC;

    float* qkv1    = bufA;
    ushort_t* wb2  = (ushort_t*)bufA;   // k2 packed (qkv1 dead after disp 2)
    ushort_t* scb  = (ushort_t*)bufA;   // sc bf16 px-major
    float* kbuf    = bufA;
    float* feat    = bufA + SZ_HALF;
    float* attnout = bufA + SZ_HALF;

    // 1. qkv = conv1x1(x, qkv_w)
    conv1x1_kernel<CC, false, false><<<dim3(9, 24, BB), 256, 0, stream>>>(
        x, qkv_w, nullptr, qkv1, (long)CC * PP, (long)C2 * PP);
    // 2. qkv = grouped 3x3 (groups=192), 4 px/thread
    dwconv_kernel<<<dim3(9, C2, BB), 256, 0, stream>>>(qkv1, qkv_conv_w, qkv2);
    // 3. poolb = bf16 px-major avgpool2(cat[q,y])   (qkv1 now dead)
    avgpool_bf16_kernel<<<dim3(36, BB), 256, 0, stream>>>(qkv2, y, poolb);
    // 4. wb2 = packed k2 weight fragments (into dead qkv1 space)
    prep_wpk_kernel<12><<<dim3(9 * 12 * 24 * 64 * 8 / 256), 256, 0, stream>>>(k2_w, wb2, 384);
    // 5. k2out = conv3x3 valid (48->46)  -- MFMA, direct-global weights
    conv48_mfma_kernel<<<dim3(12, 3, BB), 256, 0, stream>>>(poolb, wb2, k2out);
    // 6. packed weight preps: k3 and k4
    prep_wpk_kernel<12><<<dim3(9 * 12 * 24 * 64 * 8 / 256), 256, 0, stream>>>(k3_w, wbuf, 384);
    prep_wpk_kernel<1><<<dim3(9 * 1 * 24 * 64 * 8 / 256), 256, 0, stream>>>(k4_w, wb4, 18);
    // 7. catb = bf16 transposed cat (overlays dead poolb; stays live through disp 10)
    cvt_cat_kernel<<<dim3(144, BB), 256, 0, stream>>>(qkv2, y, catb);
    // 8. scb = bf16 px-major [conv3x3(cat,k3) * sigmoid(cat + resize(k2out))]  -- MFMA
    conv96_mfma_kernel<<<dim3(48, 3, BB), 256, 0, stream>>>(
        catb, wbuf, qkv2, y, k2out, scb);
    // 9. offset = conv3x3(scb, k4)  -- MFMA (offs no longer overlays catb)
    k4_mfma_kernel<<<dim3(48, BB), 384, 0, stream>>>(scb, wb4, offs);
    // 10. feat = deform_conv(q-from-catb bf16, offset, mask)
    deform_kernel<<<dim3(36, 8, BB), 256, 0, stream>>>(catb, offs, deform_w, deform_b, feat);
    // 11. k = conv1x1(relu(feat), pw_w) + pw_b   (overwrites scb — dead after disp 9)
    conv1x1_kernel<CC, true, true><<<dim3(9, 12, BB), 256, 0, stream>>>(
        feat, pw_w, pw_b, kbuf, (long)CC * PP, (long)CC * PP);
    // 12. norms
    norm_kernel<<<dim3(CC, BB, 2), 256, 0, stream>>>(qkv2, kbuf, norms);
    // 13. attn
    attn_kernel<<<dim3(24, 8, BB), 256, 0, stream>>>(qkv2, kbuf, norms, temp, attnm);
    // 14. attnout = attn @ v
    attn_apply_kernel<<<dim3(9, CC, BB), 256, 0, stream>>>(attnm, qkv2, attnout);
    // 15. out = conv1x1(attnout, proj_w)
    conv1x1_kernel<CC, false, false><<<dim3(9, 12, BB), 256, 0, stream>>>(
        attnout, proj_w, nullptr, (float*)d_out, (long)CC * PP, (long)CC * PP);
}

// Round 7
// 1133.061 us; speedup vs baseline: 7.1270x; 1.0083x over previous
//
#include <hip/hip_runtime.h>
#include <math.h>

// Problem constants
#define BB 4
#define CC 192
#define HH 96
#define WW 96
#define PP (HH*WW)          // 9216
#define C2 (2*CC)           // 384

typedef unsigned short ushort_t;
typedef __bf16 bf16_t;
typedef bf16_t bf16x8 __attribute__((ext_vector_type(8)));
typedef float floatx16 __attribute__((ext_vector_type(16)));

__device__ __forceinline__ float sigmoidf_(float x) { return 1.f / (1.f + expf(-x)); }

__device__ __forceinline__ ushort_t f2bf(float f) {
    unsigned u = __builtin_bit_cast(unsigned, f);
    unsigned r = (u + 0x7fffu + ((u >> 16) & 1u)) >> 16;
    return (ushort_t)r;
}
__device__ __forceinline__ float bflo(unsigned u) {
    return __builtin_bit_cast(float, u << 16);
}
__device__ __forceinline__ float bfhi(unsigned u) {
    return __builtin_bit_cast(float, u & 0xffff0000u);
}

// ---------------- conv 1x1 ----------------------------------------------------------------
template<int CIN, bool RELU, bool HASB>
__global__ __launch_bounds__(256) void conv1x1_kernel(
    const float* __restrict__ in, const float* __restrict__ w,
    const float* __restrict__ bias, float* __restrict__ out,
    long in_bs, long out_bs)
{
    int b = blockIdx.z;
    int co0 = blockIdx.y * 16;
    int p = blockIdx.x * 1024 + threadIdx.x * 4;
    const float* ip = in + (long)b * in_bs + p;
    float4 acc[16];
#pragma unroll
    for (int j = 0; j < 16; ++j) acc[j] = make_float4(0.f, 0.f, 0.f, 0.f);
#pragma unroll 4
    for (int ci = 0; ci < CIN; ++ci) {
        float4 xv = *(const float4*)(ip + (long)ci * PP);
        if (RELU) {
            xv.x = fmaxf(xv.x, 0.f); xv.y = fmaxf(xv.y, 0.f);
            xv.z = fmaxf(xv.z, 0.f); xv.w = fmaxf(xv.w, 0.f);
        }
#pragma unroll
        for (int j = 0; j < 16; ++j) {
            float wv = w[(long)(co0 + j) * CIN + ci];
            acc[j].x += wv * xv.x; acc[j].y += wv * xv.y;
            acc[j].z += wv * xv.z; acc[j].w += wv * xv.w;
        }
    }
#pragma unroll
    for (int j = 0; j < 16; ++j) {
        if (HASB) {
            float bb = bias[co0 + j];
            acc[j].x += bb; acc[j].y += bb; acc[j].z += bb; acc[j].w += bb;
        }
        *(float4*)(out + (long)b * out_bs + (long)(co0 + j) * PP + p) = acc[j];
    }
}

// ---------------- grouped conv 3x3, groups=192, 2in->2out, pad 1, 4px/thread -------------
__global__ __launch_bounds__(256) void dwconv_kernel(
    const float* __restrict__ in, const float* __restrict__ w, float* __restrict__ out)
{
    int b = blockIdx.z, co = blockIdx.y;
    int p = (blockIdx.x * 256 + threadIdx.x) * 4;
    int oy = p / WW, ox = p - oy * WW;
    int g = co >> 1;
    const float* w18 = w + (long)co * 18;
    float a0 = 0.f, a1 = 0.f, a2 = 0.f, a3 = 0.f;
#pragma unroll
    for (int i = 0; i < 2; ++i) {
        const float* ipl = in + ((long)(b * C2 + 2 * g + i)) * PP;
#pragma unroll
        for (int ky = 0; ky < 3; ++ky) {
            int yy = oy - 1 + ky;
            if ((unsigned)yy < (unsigned)HH) {
                const float* row = ipl + yy * WW;
                float v[6];
#pragma unroll
                for (int j = 0; j < 6; ++j) {
                    int xx = ox - 1 + j;
                    v[j] = ((unsigned)xx < (unsigned)WW) ? row[xx] : 0.f;
                }
#pragma unroll
                for (int kx = 0; kx < 3; ++kx) {
                    float wv = w18[i * 9 + ky * 3 + kx];
                    a0 += wv * v[kx]; a1 += wv * v[kx + 1];
                    a2 += wv * v[kx + 2]; a3 += wv * v[kx + 3];
                }
            }
        }
    }
    float4 r = make_float4(a0, a1, a2, a3);
    *(float4*)(out + ((long)(b * C2 + co)) * PP + p) = r;
}

// ---------------- fused avgpool 2x2 + bf16 + transpose: poolb[b][px48][ci] ---------------
__global__ __launch_bounds__(256) void avgpool_bf16_kernel(
    const float* __restrict__ qkv2, const float* __restrict__ y, ushort_t* __restrict__ poolb)
{
    __shared__ __align__(16) ushort_t sT[64 * 392];
    int b = blockIdx.y;
    int px0 = blockIdx.x * 64;
    int t = threadIdx.x;
    for (int idx = t; idx < 384 * 64; idx += 256) {
        int ci = idx >> 6, px = idx & 63;
        int p = px0 + px;
        int oy = p / 48, ox = p - oy * 48;
        const float* base = (ci < CC) ? qkv2 + ((long)(b * C2 + ci)) * PP
                                      : y + ((long)(b * CC + ci - CC)) * PP;
        const float* ipl = base + (oy * 2) * WW + ox * 2;
        float v = 0.25f * (ipl[0] + ipl[1] + ipl[WW] + ipl[WW + 1]);
        sT[px * 392 + ci] = f2bf(v);
    }
    __syncthreads();
    int px = t >> 2, qr = t & 3;
    ushort_t* dst = poolb + ((long)b * 2304 + px0 + px) * C2 + qr * 96;
    const ushort_t* srcl = sT + px * 392 + qr * 96;
#pragma unroll
    for (int k = 0; k < 96; k += 8)
        *(uint4*)(dst + k) = *(const uint4*)(srcl + k);
}

// ---------------- packed weight prep: wpk[((tap*NG+cg)*24+chunk)*64 + n*2+q][8] -----------
template<int NG>
__global__ __launch_bounds__(256) void prep_wpk_kernel(
    const float* __restrict__ w, ushort_t* __restrict__ wpk, int coutv)
{
    int i = blockIdx.x * 256 + threadIdx.x;
    int j = i & 7;
    int q = (i >> 3) & 1;
    int n = (i >> 4) & 31;
    int r = i >> 9;
    int chunk = r % 24;
    int r2 = r / 24;
    int cg = r2 % NG;
    int tap = r2 / NG;
    int co = cg * 32 + n;
    int ci = chunk * 16 + q * 8 + j;
    wpk[i] = (co < coutv) ? f2bf(w[((long)co * 384 + ci) * 9 + tap]) : (ushort_t)0;
}

// ---------------- conv48 MFMA: valid 3x3 48->46, double-buffered input staging -----------
__global__ __launch_bounds__(256) void conv48_mfma_kernel(
    const ushort_t* __restrict__ poolb, const ushort_t* __restrict__ wpk,
    float* __restrict__ out)
{
    __shared__ __align__(16) ushort_t sB[2][288 * 20];
    int b = blockIdx.z;
    int co0 = blockIdx.y * 128;
    int cgb = blockIdx.y * 4;
    int y0 = blockIdx.x * 4;
    int t = threadIdx.x;
    int w = t >> 6, lane = t & 63;
    int n = lane & 31, q = lane >> 5;
    int wc = w & 1, wn = w >> 1;
    const uint4* wq = (const uint4*)wpk;

    int pidx[3], rr[3], ccx[3];
#pragma unroll
    for (int xg = 0; xg < 3; ++xg) {
        int p = (wn * 3 + xg) * 32 + n;
        int pc = min(p, 183);
        pidx[xg] = p;
        rr[xg] = pc / 46;
        ccx[xg] = pc - rr[xg] * 46;
    }

    floatx16 acc[2][3];
#pragma unroll
    for (int a = 0; a < 2; ++a)
#pragma unroll
        for (int xg = 0; xg < 3; ++xg) acc[a][xg] = (floatx16)(0.f);

    const ushort_t* poolb_b = poolb + (long)b * 2304 * C2;

    // per-slot staging geometry (m-invariant)
    bool sok[2]; long gof[2]; int lof[2]; bool sval[2];
#pragma unroll
    for (int s = 0; s < 2; ++s) {
        int c = t + s * 256;
        sval[s] = (c < 288);
        int cc = min(c, 287);
        int r = cc / 48, col = cc - r * 48;
        int iy = y0 + r;
        sok[s] = (iy < 48);
        gof[s] = ((long)(min(iy, 47) * 48 + col)) * C2;
        lof[s] = cc * 20;
    }
    uint4 sv[2][2];

#define C48_ISSUE(mm)                                                        \
    {                                                                        \
        int ci0 = (mm) * 16;                                                 \
        _Pragma("unroll")                                                    \
        for (int s = 0; s < 2; ++s) {                                        \
            if (sval[s] && sok[s]) {                                         \
                const ushort_t* sp = poolb_b + gof[s] + ci0;                 \
                sv[s][0] = *(const uint4*)(sp);                              \
                sv[s][1] = *(const uint4*)(sp + 8);                          \
            } else {                                                         \
                sv[s][0] = make_uint4(0u,0u,0u,0u);                          \
                sv[s][1] = make_uint4(0u,0u,0u,0u);                          \
            }                                                                \
        }                                                                    \
    }
#define C48_COMMIT(buf)                                                      \
    {                                                                        \
        _Pragma("unroll")                                                    \
        for (int s = 0; s < 2; ++s) {                                        \
            if (sval[s]) {                                                   \
                ushort_t* d = sB[buf] + lof[s];                              \
                *(uint2*)(d + 0)  = make_uint2(sv[s][0].x, sv[s][0].y);      \
                *(uint2*)(d + 4)  = make_uint2(sv[s][0].z, sv[s][0].w);      \
                *(uint2*)(d + 8)  = make_uint2(sv[s][1].x, sv[s][1].y);      \
                *(uint2*)(d + 12) = make_uint2(sv[s][1].z, sv[s][1].w);      \
            }                                                                \
        }                                                                    \
    }

    C48_ISSUE(0); C48_COMMIT(0);
    __syncthreads();

    for (int m = 0; m < 24; ++m) {
        int cur = m & 1;
        if (m < 23) C48_ISSUE(m + 1);
#pragma unroll
        for (int ky = 0; ky < 3; ++ky) {
            uint4 wv[6];
#pragma unroll
            for (int kx = 0; kx < 3; ++kx)
#pragma unroll
                for (int a = 0; a < 2; ++a)
                    wv[kx * 2 + a] = wq[(long)(((ky * 3 + kx) * 12 + cgb + wc * 2 + a) * 24 + m) * 64 + lane];
#pragma unroll
            for (int kx = 0; kx < 3; ++kx) {
                bf16x8 af[2], bfm[3];
#pragma unroll
                for (int a = 0; a < 2; ++a)
                    af[a] = __builtin_bit_cast(bf16x8, wv[kx * 2 + a]);
#pragma unroll
                for (int xg = 0; xg < 3; ++xg) {
                    int cell = (rr[xg] + ky) * 48 + ccx[xg] + kx;
                    const ushort_t* p = sB[cur] + cell * 20 + q * 8;
                    uint2 lo = *(const uint2*)(p);
                    uint2 hi = *(const uint2*)(p + 4);
                    bfm[xg] = __builtin_bit_cast(bf16x8, make_uint4(lo.x, lo.y, hi.x, hi.y));
                }
#pragma unroll
                for (int a = 0; a < 2; ++a)
#pragma unroll
                    for (int xg = 0; xg < 3; ++xg)
                        acc[a][xg] = __builtin_amdgcn_mfma_f32_32x32x16_bf16(
                            af[a], bfm[xg], acc[a][xg], 0, 0, 0);
            }
        }
        if (m < 23) C48_COMMIT(cur ^ 1);
        __syncthreads();
    }

#pragma unroll
    for (int a = 0; a < 2; ++a) {
        int cobase = co0 + (wc * 2 + a) * 32;
#pragma unroll
        for (int xg = 0; xg < 3; ++xg) {
            int oy = y0 + rr[xg], ox = ccx[xg];
            if (pidx[xg] >= 184 || oy >= 46) continue;
#pragma unroll
            for (int r = 0; r < 16; ++r) {
                int row = (r & 3) + 8 * (r >> 2) + 4 * q;
                out[((long)(b * C2 + cobase + row)) * 2116 + oy * 46 + ox] = acc[a][xg][r];
            }
        }
    }
}

// ---------------- cvt_cat: catb[b][px][ci] bf16 from cat(q=qkv2[0:192], y) ----------------
__global__ __launch_bounds__(256) void cvt_cat_kernel(
    const float* __restrict__ qkv2, const float* __restrict__ y, ushort_t* __restrict__ catb)
{
    __shared__ __align__(16) ushort_t sT[64 * 392];
    int b = blockIdx.y;
    int px0 = blockIdx.x * 64;
    int t = threadIdx.x;
    for (int idx = t; idx < 384 * 64; idx += 256) {
        int ci = idx >> 6, px = idx & 63;
        const float* src = (ci < CC) ? qkv2 + ((long)(b * C2 + ci)) * PP
                                     : y + ((long)(b * CC + ci - CC)) * PP;
        sT[px * 392 + ci] = f2bf(src[px0 + px]);
    }
    __syncthreads();
    int px = t >> 2, qr = t & 3;
    ushort_t* dst = catb + ((long)b * PP + px0 + px) * C2 + qr * 96;
    const ushort_t* srcl = sT + px * 392 + qr * 96;
#pragma unroll
    for (int k = 0; k < 96; k += 8)
        *(uint4*)(dst + k) = *(const uint4*)(srcl + k);
}

// ---------------- conv96 MFMA: double-buffered input staging + row-batched weights -------
__global__ __launch_bounds__(256) void conv96_mfma_kernel(
    const ushort_t* __restrict__ catb, const ushort_t* __restrict__ wpk,
    const float* __restrict__ qkv2, const float* __restrict__ yy,
    const float* __restrict__ k2out, ushort_t* __restrict__ scb)
{
    __shared__ __align__(16) ushort_t sB[2][392 * 20];
    int b = blockIdx.z;
    int co0 = blockIdx.y * 128;
    int cgb = blockIdx.y * 4;
    int y0 = blockIdx.x * 2;
    int t = threadIdx.x;
    int w = t >> 6, lane = t & 63;
    int n = lane & 31, q = lane >> 5;
    int wc = w & 1;
    int wr = w >> 1;
    const uint4* wq = (const uint4*)wpk;

    floatx16 acc[2][3];
#pragma unroll
    for (int a = 0; a < 2; ++a)
#pragma unroll
        for (int xg = 0; xg < 3; ++xg) acc[a][xg] = (floatx16)(0.f);

    const ushort_t* catb_b = catb + (long)b * PP * C2;

    bool sok[2]; long gof[2]; int lof[2]; bool sval[2];
#pragma unroll
    for (int s = 0; s < 2; ++s) {
        int c = t + s * 256;
        sval[s] = (c < 392);
        int cc = min(c, 391);
        int r = cc / 98, col = cc - r * 98;
        int iy = y0 - 1 + r, ix = col - 1;
        sok[s] = (iy >= 0 && iy < HH && ix >= 0 && ix < WW);
        gof[s] = ((long)(min(max(iy, 0), HH - 1) * WW + min(max(ix, 0), WW - 1))) * C2;
        lof[s] = cc * 20;
    }
    uint4 sv[2][2];

#define C96_ISSUE(mm)                                                        \
    {                                                                        \
        int ci0 = (mm) * 16;                                                 \
        _Pragma("unroll")                                                    \
        for (int s = 0; s < 2; ++s) {                                        \
            if (sval[s] && sok[s]) {                                         \
                const ushort_t* sp = catb_b + gof[s] + ci0;                  \
                sv[s][0] = *(const uint4*)(sp);                              \
                sv[s][1] = *(const uint4*)(sp + 8);                          \
            } else {                                                         \
                sv[s][0] = make_uint4(0u,0u,0u,0u);                          \
                sv[s][1] = make_uint4(0u,0u,0u,0u);                          \
            }                                                                \
        }                                                                    \
    }
#define C96_COMMIT(buf)                                                      \
    {                                                                        \
        _Pragma("unroll")                                                    \
        for (int s = 0; s < 2; ++s) {                                        \
            if (sval[s]) {                                                   \
                ushort_t* d = sB[buf] + lof[s];                              \
                *(uint2*)(d + 0)  = make_uint2(sv[s][0].x, sv[s][0].y);      \
                *(uint2*)(d + 4)  = make_uint2(sv[s][0].z, sv[s][0].w);      \
                *(uint2*)(d + 8)  = make_uint2(sv[s][1].x, sv[s][1].y);      \
                *(uint2*)(d + 12) = make_uint2(sv[s][1].z, sv[s][1].w);      \
            }                                                                \
        }                                                                    \
    }

    C96_ISSUE(0); C96_COMMIT(0);
    __syncthreads();

    for (int m = 0; m < 24; ++m) {
        int cur = m & 1;
        if (m < 23) C96_ISSUE(m + 1);
#pragma unroll
        for (int ky = 0; ky < 3; ++ky) {
            uint4 wv[6];
#pragma unroll
            for (int kx = 0; kx < 3; ++kx)
#pragma unroll
                for (int a = 0; a < 2; ++a)
                    wv[kx * 2 + a] = wq[(long)(((ky * 3 + kx) * 12 + cgb + wc * 2 + a) * 24 + m) * 64 + lane];
#pragma unroll
            for (int kx = 0; kx < 3; ++kx) {
                bf16x8 af[2], bfm[3];
#pragma unroll
                for (int a = 0; a < 2; ++a)
                    af[a] = __builtin_bit_cast(bf16x8, wv[kx * 2 + a]);
#pragma unroll
                for (int xg = 0; xg < 3; ++xg) {
                    int col = xg * 32 + n + kx;
                    const ushort_t* p = sB[cur] + ((wr + ky) * 98 + col) * 20 + q * 8;
                    uint2 lo = *(const uint2*)(p);
                    uint2 hi = *(const uint2*)(p + 4);
                    bfm[xg] = __builtin_bit_cast(bf16x8, make_uint4(lo.x, lo.y, hi.x, hi.y));
                }
#pragma unroll
                for (int a = 0; a < 2; ++a)
#pragma unroll
                    for (int xg = 0; xg < 3; ++xg)
                        acc[a][xg] = __builtin_amdgcn_mfma_f32_32x32x16_bf16(
                            af[a], bfm[xg], acc[a][xg], 0, 0, 0);
            }
        }
        if (m < 23) C96_COMMIT(cur ^ 1);
        __syncthreads();
    }

    // epilogue: scb[b][px][co] = bf16( acc * sigmoid(cat + nearest(k2out)) )
    int yl = y0 + wr;
    int iy46 = (yl * 46) / 96;
#pragma unroll
    for (int a = 0; a < 2; ++a) {
        int cobase = co0 + (wc * 2 + a) * 32;
#pragma unroll
        for (int xg = 0; xg < 3; ++xg) {
            int x = xg * 32 + n;
            int ix46 = (x * 46) / 96;
            ushort_t* dst = scb + ((long)(b * PP + yl * WW + x)) * C2;
#pragma unroll
            for (int g = 0; g < 4; ++g) {
                int cog = cobase + 8 * g + 4 * q;
                ushort_t pk[4];
#pragma unroll
                for (int j = 0; j < 4; ++j) {
                    int co = cog + j;
                    const float* gsrc = (co < CC) ? qkv2 + ((long)(b * C2 + co)) * PP
                                                  : yy + ((long)(b * CC + co - CC)) * PP;
                    float kv = k2out[((long)(b * C2 + co)) * 2116 + iy46 * 46 + ix46];
                    float gg = gsrc[yl * WW + x] + kv;
                    pk[j] = f2bf(acc[a][xg][4 * g + j] * sigmoidf_(gg));
                }
                *(uint2*)(dst + cog) = *(uint2*)pk;
            }
        }
    }
}

// ---------------- k4 MFMA: offs = conv3x3(scb), M=32 pad, double-buffered ----------------
__global__ __launch_bounds__(384) void k4_mfma_kernel(
    const ushort_t* __restrict__ scb, const ushort_t* __restrict__ wpk4,
    float* __restrict__ out)
{
    __shared__ __align__(16) ushort_t sB[2][392 * 20];
    int b = blockIdx.y;
    int y0 = blockIdx.x * 2;
    int t = threadIdx.x;
    int w = t / 64, lane = t & 63;
    int n = lane & 31, q = lane >> 5;
    int wr = w / 3, xg = w - wr * 3;
    const uint4* wq = (const uint4*)wpk4;

    floatx16 acc = (floatx16)(0.f);
    const ushort_t* scb_b = scb + (long)b * PP * C2;

    bool sok[2]; long gof[2]; int lof[2]; bool sval[2];
#pragma unroll
    for (int s = 0; s < 2; ++s) {
        int c = t + s * 384;
        sval[s] = (c < 392);
        int cc = min(c, 391);
        int r = cc / 98, col = cc - r * 98;
        int iy = y0 - 1 + r, ix = col - 1;
        sok[s] = (iy >= 0 && iy < HH && ix >= 0 && ix < WW);
        gof[s] = ((long)(min(max(iy, 0), HH - 1) * WW + min(max(ix, 0), WW - 1))) * C2;
        lof[s] = cc * 20;
    }
    uint4 sv[2][2];

#define K4_ISSUE(mm)                                                         \
    {                                                                        \
        int ci0 = (mm) * 16;                                                 \
        _Pragma("unroll")                                                    \
        for (int s = 0; s < 2; ++s) {                                        \
            if (sval[s] && sok[s]) {                                         \
                const ushort_t* sp = scb_b + gof[s] + ci0;                   \
                sv[s][0] = *(const uint4*)(sp);                              \
                sv[s][1] = *(const uint4*)(sp + 8);                          \
            } else {                                                         \
                sv[s][0] = make_uint4(0u,0u,0u,0u);                          \
                sv[s][1] = make_uint4(0u,0u,0u,0u);                          \
            }                                                                \
        }                                                                    \
    }
#define K4_COMMIT(buf)                                                       \
    {                                                                        \
        _Pragma("unroll")                                                    \
        for (int s = 0; s < 2; ++s) {                                        \
            if (sval[s]) {                                                   \
                ushort_t* d = sB[buf] + lof[s];                              \
                *(uint2*)(d + 0)  = make_uint2(sv[s][0].x, sv[s][0].y);      \
                *(uint2*)(d + 4)  = make_uint2(sv[s][0].z, sv[s][0].w);      \
                *(uint2*)(d + 8)  = make_uint2(sv[s][1].x, sv[s][1].y);      \
                *(uint2*)(d + 12) = make_uint2(sv[s][1].z, sv[s][1].w);      \
            }                                                                \
        }                                                                    \
    }

    K4_ISSUE(0); K4_COMMIT(0);
    __syncthreads();

    for (int m = 0; m < 24; ++m) {
        int cur = m & 1;
        if (m < 23) K4_ISSUE(m + 1);
#pragma unroll
        for (int ky = 0; ky < 3; ++ky) {
            uint4 wv[3];
#pragma unroll
            for (int kx = 0; kx < 3; ++kx)
                wv[kx] = wq[(long)(((ky * 3 + kx) * 24) + m) * 64 + lane];
#pragma unroll
            for (int kx = 0; kx < 3; ++kx) {
                bf16x8 af = __builtin_bit_cast(bf16x8, wv[kx]);
                int col = xg * 32 + n + kx;
                const ushort_t* pb = sB[cur] + ((wr + ky) * 98 + col) * 20 + q * 8;
                uint2 blo = *(const uint2*)(pb);
                uint2 bhi = *(const uint2*)(pb + 4);
                bf16x8 bf = __builtin_bit_cast(bf16x8, make_uint4(blo.x, blo.y, bhi.x, bhi.y));
                acc = __builtin_amdgcn_mfma_f32_32x32x16_bf16(af, bf, acc, 0, 0, 0);
            }
        }
        if (m < 23) K4_COMMIT(cur ^ 1);
        __syncthreads();
    }

    int yl = y0 + wr;
    int x = xg * 32 + n;
#pragma unroll
    for (int r = 0; r < 16; ++r) {
        int row = (r & 3) + 8 * (r >> 2) + 4 * q;
        if (row < 18)
            out[((long)(b * 18 + row)) * PP + yl * WW + x] = acc[r];
    }
}

// ---------------- deformable conv, bf16 LDS tile from catb -------------------------------
#define DW 22
__global__ __launch_bounds__(256) void deform_kernel(
    const ushort_t* __restrict__ catb, const float* __restrict__ offs,
    const float* __restrict__ w, const float* __restrict__ bias, float* __restrict__ out)
{
    __shared__ __align__(16) ushort_t sQ[DW * DW * 24];
    int b = blockIdx.z, g = blockIdx.y;
    int tile = blockIdx.x;
    int ty0 = (tile / 6) * 16, tx0 = (tile % 6) * 16;
    int wy0 = ty0 - 3, wx0 = tx0 - 3;
    int t = threadIdx.x;
    int oy = ty0 + (t >> 4), ox = tx0 + (t & 15);
    int p = oy * WW + ox;

    const ushort_t* cb = catb + (long)b * PP * C2 + g * 24;
    for (int idx = t; idx < 484 * 3; idx += 256) {
        int cell = idx / 3, part = idx - cell * 3;
        int sy = cell / DW, sx = cell - sy * DW;
        int syc = min(max(wy0 + sy, 0), HH - 1);
        int sxc = min(max(wx0 + sx, 0), WW - 1);
        uint4 v = *(const uint4*)(cb + ((long)(syc * WW + sxc)) * C2 + part * 8);
        *(uint4*)(sQ + cell * 24 + part * 8) = v;
    }
    __syncthreads();

    const float* ob = offs + (long)b * 18 * PP;
    float acc[24];
#pragma unroll
    for (int o = 0; o < 24; ++o) acc[o] = 0.f;

    for (int k = 0; k < 9; ++k) {
        float dy = ob[(2 * k) * PP + p];
        float dx = ob[(2 * k + 1) * PP + p];
        float mk = sigmoidf_(ob[k * PP + p]);
        float py = dy + (float)(oy - 1 + k / 3);
        float px = dx + (float)(ox - 1 + (k % 3));
        float fy = floorf(py), fx = floorf(px);
        int y0 = (int)fy, x0 = (int)fx;
        float ly = py - fy, lx = px - fx;
        float w00 = (1.f - ly) * (1.f - lx), w01 = (1.f - ly) * lx;
        float w10 = ly * (1.f - lx), w11 = ly * lx;
        bool vy0 = (y0 >= 0 && y0 <= HH - 1), vy1 = (y0 + 1 <= HH - 1) && (y0 + 1 >= 0);
        bool vx0 = (x0 >= 0 && x0 <= WW - 1), vx1 = (x0 + 1 <= WW - 1) && (x0 + 1 >= 0);
        w00 = (vy0 && vx0) ? w00 * mk : 0.f;
        w01 = (vy0 && vx1) ? w01 * mk : 0.f;
        w10 = (vy1 && vx0) ? w10 * mk : 0.f;
        w11 = (vy1 && vx1) ? w11 * mk : 0.f;
        float vals[24];
        bool inwin = (y0 >= wy0) && (y0 - wy0 <= DW - 2) && (x0 >= wx0) && (x0 - wx0 <= DW - 2);
        if (inwin) {
            int c00 = (y0 - wy0) * DW + (x0 - wx0);
            const ushort_t* s00 = sQ + c00 * 24;
#pragma unroll
            for (int part = 0; part < 3; ++part) {
                uint4 A = *(const uint4*)(s00 + part * 8);
                uint4 Bv = *(const uint4*)(s00 + 24 + part * 8);
                uint4 Cv = *(const uint4*)(s00 + DW * 24 + part * 8);
                uint4 Dv = *(const uint4*)(s00 + DW * 24 + 24 + part * 8);
                const unsigned* au = (const unsigned*)&A;
                const unsigned* bu = (const unsigned*)&Bv;
                const unsigned* cu = (const unsigned*)&Cv;
                const unsigned* du = (const unsigned*)&Dv;
#pragma unroll
                for (int u = 0; u < 4; ++u) {
                    int ci = part * 8 + u * 2;
                    vals[ci]     = w00 * bflo(au[u]) + w01 * bflo(bu[u])
                                 + w10 * bflo(cu[u]) + w11 * bflo(du[u]);
                    vals[ci + 1] = w00 * bfhi(au[u]) + w01 * bfhi(bu[u])
                                 + w10 * bfhi(cu[u]) + w11 * bfhi(du[u]);
                }
            }
        } else {
            int y0c = min(max(y0, 0), HH - 1), y1c = min(max(y0 + 1, 0), HH - 1);
            int x0c = min(max(x0, 0), WW - 1), x1c = min(max(x0 + 1, 0), WW - 1);
            const ushort_t* p00 = cb + ((long)(y0c * WW + x0c)) * C2;
            const ushort_t* p01 = cb + ((long)(y0c * WW + x1c)) * C2;
            const ushort_t* p10 = cb + ((long)(y1c * WW + x0c)) * C2;
            const ushort_t* p11 = cb + ((long)(y1c * WW + x1c)) * C2;
#pragma unroll
            for (int part = 0; part < 3; ++part) {
                uint4 A = *(const uint4*)(p00 + part * 8);
                uint4 Bv = *(const uint4*)(p01 + part * 8);
                uint4 Cv = *(const uint4*)(p10 + part * 8);
                uint4 Dv = *(const uint4*)(p11 + part * 8);
                const unsigned* au = (const unsigned*)&A;
                const unsigned* bu = (const unsigned*)&Bv;
                const unsigned* cu = (const unsigned*)&Cv;
                const unsigned* du = (const unsigned*)&Dv;
#pragma unroll
                for (int u = 0; u < 4; ++u) {
                    int ci = part * 8 + u * 2;
                    vals[ci]     = w00 * bflo(au[u]) + w01 * bflo(bu[u])
                                 + w10 * bflo(cu[u]) + w11 * bflo(du[u]);
                    vals[ci + 1] = w00 * bfhi(au[u]) + w01 * bfhi(bu[u])
                                 + w10 * bfhi(cu[u]) + w11 * bfhi(du[u]);
                }
            }
        }
        const float* wg = w + (long)g * 24 * 216 + k;
#pragma unroll
        for (int o = 0; o < 24; ++o) {
            const float* wr = wg + (long)o * 216;
            float s = acc[o];
#pragma unroll
            for (int ci = 0; ci < 24; ++ci) s += wr[ci * 9] * vals[ci];
            acc[o] = s;
        }
    }
#pragma unroll
    for (int o = 0; o < 24; ++o)
        out[((long)(b * CC + g * 24 + o)) * PP + p] = acc[o] + bias[g * 24 + o];
}

// ---------------- L2 norms of q and k rows -----------------------------------------------
__global__ __launch_bounds__(256) void norm_kernel(
    const float* __restrict__ q, const float* __restrict__ kb, float* __restrict__ norms)
{
    int c = blockIdx.x, b = blockIdx.y, which = blockIdx.z;
    const float* src = (which == 0) ? q + ((long)(b * C2 + c)) * PP
                                    : kb + ((long)(b * CC + c)) * PP;
    float s = 0.f;
    for (int n = threadIdx.x * 4; n < PP; n += 1024) {
        float4 v = *(const float4*)(src + n);
        s += v.x * v.x + v.y * v.y + v.z * v.z + v.w * v.w;
    }
    __shared__ float red[256];
    red[threadIdx.x] = s;
    __syncthreads();
    for (int st = 128; st > 0; st >>= 1) {
        if (threadIdx.x < st) red[threadIdx.x] += red[threadIdx.x + st];
        __syncthreads();
    }
    if (threadIdx.x == 0)
        norms[((long)which * BB + b) * CC + c] = fmaxf(sqrtf(red[0]), 1e-12f);
}

// ---------------- attention logits + softmax ---------------------------------------------
__global__ __launch_bounds__(256) void attn_kernel(
    const float* __restrict__ q, const float* __restrict__ kb,
    const float* __restrict__ norms, const float* __restrict__ temp,
    float* __restrict__ attn)
{
    int c = blockIdx.x, h = blockIdx.y, b = blockIdx.z;
    const float* qp = q + ((long)(b * C2 + h * 24 + c)) * PP;
    const float* kbase = kb + ((long)(b * CC + h * 24)) * PP;
    float part[24];
#pragma unroll
    for (int d = 0; d < 24; ++d) part[d] = 0.f;
    for (int n = threadIdx.x * 4; n < PP; n += 1024) {
        float4 qv = *(const float4*)(qp + n);
#pragma unroll
        for (int d = 0; d < 24; ++d) {
            float4 kv = *(const float4*)(kbase + (long)d * PP + n);
            part[d] += qv.x * kv.x + qv.y * kv.y + qv.z * kv.z + qv.w * kv.w;
        }
    }
    __shared__ float lred[4][24];
    __shared__ float logits[24];
    int lane = threadIdx.x & 63, wv = threadIdx.x >> 6;
#pragma unroll
    for (int d = 0; d < 24; ++d) {
        float x = part[d];
        for (int off = 32; off > 0; off >>= 1) x += __shfl_down(x, off, 64);
        if (lane == 0) lred[wv][d] = x;
    }
    __syncthreads();
    if (threadIdx.x < 24) {
        int d = threadIdx.x;
        float tot = lred[0][d] + lred[1][d] + lred[2][d] + lred[3][d];
        float nq = norms[(long)b * CC + h * 24 + c];
        float nk = norms[(long)(BB + b) * CC + h * 24 + d];
        logits[d] = tot / (nq * nk) * temp[h];
    }
    __syncthreads();
    if (threadIdx.x < 24) {
        int d = threadIdx.x;
        float mx = -3.4e38f;
#pragma unroll
        for (int j = 0; j < 24; ++j) mx = fmaxf(mx, logits[j]);
        float sum = 0.f;
#pragma unroll
        for (int j = 0; j < 24; ++j) sum += expf(logits[j] - mx);
        attn[(((long)(b * 8 + h) * 24) + c) * 24 + d] = expf(logits[d] - mx) / sum;
    }
}

// ---------------- attn @ v ----------------------------------------------------------------
__global__ __launch_bounds__(256) void attn_apply_kernel(
    const float* __restrict__ attn, const float* __restrict__ qkv2, float* __restrict__ out)
{
    int b = blockIdx.z, ch = blockIdx.y;
    int h = ch / 24, c = ch - h * 24;
    int n = blockIdx.x * 1024 + threadIdx.x * 4;
    const float* arow = attn + (((long)(b * 8 + h) * 24) + c) * 24;
    const float* vbase = qkv2 + ((long)(b * C2) + CC + h * 24) * PP;
    float4 acc = make_float4(0.f, 0.f, 0.f, 0.f);
#pragma unroll
    for (int d = 0; d < 24; ++d) {
        float a = arow[d];
        float4 vv = *(const float4*)(vbase + (long)d * PP + n);
        acc.x += a * vv.x; acc.y += a * vv.y; acc.z += a * vv.z; acc.w += a * vv.w;
    }
    *(float4*)(out + ((long)(b * CC + ch)) * PP + n) = acc;
}

// =========================================================================================
extern "C" void kernel_launch(void* const* d_in, const int* in_sizes, int n_in,
                              void* d_out, int out_size, void* d_ws, size_t ws_size,
                              hipStream_t stream)
{
    const float* x          = (const float*)d_in[0];
    const float* y          = (const float*)d_in[1];
    const float* temp       = (const float*)d_in[2];
    const float* qkv_w      = (const float*)d_in[3];
    const float* qkv_conv_w = (const float*)d_in[4];
    const float* proj_w     = (const float*)d_in[5];
    const float* k2_w       = (const float*)d_in[6];
    const float* k3_w       = (const float*)d_in[7];
    const float* k4_w       = (const float*)d_in[8];
    const float* deform_w   = (const float*)d_in[9];
    const float* deform_b   = (const float*)d_in[10];
    const float* pw_w       = (const float*)d_in[11];
    const float* pw_b       = (const float*)d_in[12];

    float* ws = (float*)d_ws;
    const long SZ_FULL = (long)BB * C2 * PP;     // 14,155,776
    const long SZ_HALF = (long)BB * CC * PP;     //  7,077,888

    float* bufA   = ws;
    float* qkv2   = ws + SZ_FULL;
    float* k2out  = ws + 2 * SZ_FULL;
    float* ovl    = k2out + (long)BB * C2 * 2116;
    ushort_t* poolb = (ushort_t*)ovl;
    ushort_t* catb  = (ushort_t*)ovl;
    ushort_t* wbuf = (ushort_t*)(ovl + SZ_HALF);
    ushort_t* wb4  = (ushort_t*)(ovl + SZ_HALF + 663552);
    float* offs   = ovl + SZ_HALF + 663552 + 55296;
    float* norms  = offs + (long)BB * 18 * PP;
    float* attnm  = norms + 2 * BB * CC;

    float* qkv1    = bufA;
    ushort_t* wb2  = (ushort_t*)bufA;
    ushort_t* scb  = (ushort_t*)bufA;
    float* kbuf    = bufA;
    float* feat    = bufA + SZ_HALF;
    float* attnout = bufA + SZ_HALF;

    // 1. qkv = conv1x1(x, qkv_w)
    conv1x1_kernel<CC, false, false><<<dim3(9, 24, BB), 256, 0, stream>>>(
        x, qkv_w, nullptr, qkv1, (long)CC * PP, (long)C2 * PP);
    // 2. qkv = grouped 3x3 (groups=192), 4 px/thread
    dwconv_kernel<<<dim3(9, C2, BB), 256, 0, stream>>>(qkv1, qkv_conv_w, qkv2);
    // 3. poolb = bf16 px-major avgpool2(cat[q,y])   (qkv1 now dead)
    avgpool_bf16_kernel<<<dim3(36, BB), 256, 0, stream>>>(qkv2, y, poolb);
    // 4. wb2 = packed k2 weight fragments (into dead qkv1 space)
    prep_wpk_kernel<12><<<dim3(9 * 12 * 24 * 64 * 8 / 256), 256, 0, stream>>>(k2_w, wb2, 384);
    // 5. k2out = conv3x3 valid (48->46)  -- MFMA, double-buffered
    conv48_mfma_kernel<<<dim3(12, 3, BB), 256, 0, stream>>>(poolb, wb2, k2out);
    // 6. packed weight preps: k3 and k4
    prep_wpk_kernel<12><<<dim3(9 * 12 * 24 * 64 * 8 / 256), 256, 0, stream>>>(k3_w, wbuf, 384);
    prep_wpk_kernel<1><<<dim3(9 * 1 * 24 * 64 * 8 / 256), 256, 0, stream>>>(k4_w, wb4, 18);
    // 7. catb = bf16 transposed cat (overlays dead poolb; live through disp 10)
    cvt_cat_kernel<<<dim3(144, BB), 256, 0, stream>>>(qkv2, y, catb);
    // 8. scb = bf16 px-major gated conv  -- MFMA, double-buffered
    conv96_mfma_kernel<<<dim3(48, 3, BB), 256, 0, stream>>>(
        catb, wbuf, qkv2, y, k2out, scb);
    // 9. offset = conv3x3(scb, k4)  -- MFMA, double-buffered
    k4_mfma_kernel<<<dim3(48, BB), 384, 0, stream>>>(scb, wb4, offs);
    // 10. feat = deform_conv(q-from-catb bf16, offset, mask)
    deform_kernel<<<dim3(36, 8, BB), 256, 0, stream>>>(catb, offs, deform_w, deform_b, feat);
    // 11. k = conv1x1(relu(feat), pw_w) + pw_b
    conv1x1_kernel<CC, true, true><<<dim3(9, 12, BB), 256, 0, stream>>>(
        feat, pw_w, pw_b, kbuf, (long)CC * PP, (long)CC * PP);
    // 12. norms
    norm_kernel<<<dim3(CC, BB, 2), 256, 0, stream>>>(qkv2, kbuf, norms);
    // 13. attn
    attn_kernel<<<dim3(24, 8, BB), 256, 0, stream>>>(qkv2, kbuf, norms, temp, attnm);
    // 14. attnout = attn @ v
    attn_apply_kernel<<<dim3(9, CC, BB), 256, 0, stream>>>(attnm, qkv2, attnout);
    // 15. out = conv1x1(attnout, proj_w)
    conv1x1_kernel<CC, false, false><<<dim3(9, 12, BB), 256, 0, stream>>>(
        attnout, proj_w, nullptr, (float*)d_out, (long)CC * PP, (long)CC * PP);
}

// Round 8
// 1009.007 us; speedup vs baseline: 8.0032x; 1.1229x over previous
//
#include <hip/hip_runtime.h>
#include <math.h>

// Problem constants
#define BB 4
#define CC 192
#define HH 96
#define WW 96
#define PP (HH*WW)          // 9216
#define C2 (2*CC)           // 384

typedef unsigned short ushort_t;
typedef __bf16 bf16_t;
typedef bf16_t bf16x8 __attribute__((ext_vector_type(8)));
typedef float floatx16 __attribute__((ext_vector_type(16)));

__device__ __forceinline__ float sigmoidf_(float x) { return 1.f / (1.f + expf(-x)); }

__device__ __forceinline__ ushort_t f2bf(float f) {
    unsigned u = __builtin_bit_cast(unsigned, f);
    unsigned r = (u + 0x7fffu + ((u >> 16) & 1u)) >> 16;
    return (ushort_t)r;
}
__device__ __forceinline__ float bflo(unsigned u) {
    return __builtin_bit_cast(float, u << 16);
}
__device__ __forceinline__ float bfhi(unsigned u) {
    return __builtin_bit_cast(float, u & 0xffff0000u);
}

// ---------------- conv 1x1 ----------------------------------------------------------------
template<int CIN, bool RELU, bool HASB>
__global__ __launch_bounds__(256) void conv1x1_kernel(
    const float* __restrict__ in, const float* __restrict__ w,
    const float* __restrict__ bias, float* __restrict__ out,
    long in_bs, long out_bs)
{
    int b = blockIdx.z;
    int co0 = blockIdx.y * 16;
    int p = blockIdx.x * 1024 + threadIdx.x * 4;
    const float* ip = in + (long)b * in_bs + p;
    float4 acc[16];
#pragma unroll
    for (int j = 0; j < 16; ++j) acc[j] = make_float4(0.f, 0.f, 0.f, 0.f);
#pragma unroll 4
    for (int ci = 0; ci < CIN; ++ci) {
        float4 xv = *(const float4*)(ip + (long)ci * PP);
        if (RELU) {
            xv.x = fmaxf(xv.x, 0.f); xv.y = fmaxf(xv.y, 0.f);
            xv.z = fmaxf(xv.z, 0.f); xv.w = fmaxf(xv.w, 0.f);
        }
#pragma unroll
        for (int j = 0; j < 16; ++j) {
            float wv = w[(long)(co0 + j) * CIN + ci];
            acc[j].x += wv * xv.x; acc[j].y += wv * xv.y;
            acc[j].z += wv * xv.z; acc[j].w += wv * xv.w;
        }
    }
#pragma unroll
    for (int j = 0; j < 16; ++j) {
        if (HASB) {
            float bb = bias[co0 + j];
            acc[j].x += bb; acc[j].y += bb; acc[j].z += bb; acc[j].w += bb;
        }
        *(float4*)(out + (long)b * out_bs + (long)(co0 + j) * PP + p) = acc[j];
    }
}

// ---------------- grouped conv 3x3, groups=192, 2in->2out, pad 1, 4px/thread -------------
__global__ __launch_bounds__(256) void dwconv_kernel(
    const float* __restrict__ in, const float* __restrict__ w, float* __restrict__ out)
{
    int b = blockIdx.z, co = blockIdx.y;
    int p = (blockIdx.x * 256 + threadIdx.x) * 4;
    int oy = p / WW, ox = p - oy * WW;
    int g = co >> 1;
    const float* w18 = w + (long)co * 18;
    float a0 = 0.f, a1 = 0.f, a2 = 0.f, a3 = 0.f;
#pragma unroll
    for (int i = 0; i < 2; ++i) {
        const float* ipl = in + ((long)(b * C2 + 2 * g + i)) * PP;
#pragma unroll
        for (int ky = 0; ky < 3; ++ky) {
            int yy = oy - 1 + ky;
            if ((unsigned)yy < (unsigned)HH) {
                const float* row = ipl + yy * WW;
                float v[6];
#pragma unroll
                for (int j = 0; j < 6; ++j) {
                    int xx = ox - 1 + j;
                    v[j] = ((unsigned)xx < (unsigned)WW) ? row[xx] : 0.f;
                }
#pragma unroll
                for (int kx = 0; kx < 3; ++kx) {
                    float wv = w18[i * 9 + ky * 3 + kx];
                    a0 += wv * v[kx]; a1 += wv * v[kx + 1];
                    a2 += wv * v[kx + 2]; a3 += wv * v[kx + 3];
                }
            }
        }
    }
    float4 r = make_float4(a0, a1, a2, a3);
    *(float4*)(out + ((long)(b * C2 + co)) * PP + p) = r;
}

// ---------------- fused avgpool 2x2 + bf16 + transpose: poolb[b][px48][ci] ---------------
__global__ __launch_bounds__(256) void avgpool_bf16_kernel(
    const float* __restrict__ qkv2, const float* __restrict__ y, ushort_t* __restrict__ poolb)
{
    __shared__ __align__(16) ushort_t sT[64 * 392];
    int b = blockIdx.y;
    int px0 = blockIdx.x * 64;
    int t = threadIdx.x;
    for (int idx = t; idx < 384 * 64; idx += 256) {
        int ci = idx >> 6, px = idx & 63;
        int p = px0 + px;
        int oy = p / 48, ox = p - oy * 48;
        const float* base = (ci < CC) ? qkv2 + ((long)(b * C2 + ci)) * PP
                                      : y + ((long)(b * CC + ci - CC)) * PP;
        const float* ipl = base + (oy * 2) * WW + ox * 2;
        float v = 0.25f * (ipl[0] + ipl[1] + ipl[WW] + ipl[WW + 1]);
        sT[px * 392 + ci] = f2bf(v);
    }
    __syncthreads();
    int px = t >> 2, qr = t & 3;
    ushort_t* dst = poolb + ((long)b * 2304 + px0 + px) * C2 + qr * 96;
    const ushort_t* srcl = sT + px * 392 + qr * 96;
#pragma unroll
    for (int k = 0; k < 96; k += 8)
        *(uint4*)(dst + k) = *(const uint4*)(srcl + k);
}

// ---------------- packed weight prep: wpk[((tap*NG+cg)*24+chunk)*64 + n*2+q][8] -----------
template<int NG>
__global__ __launch_bounds__(256) void prep_wpk_kernel(
    const float* __restrict__ w, ushort_t* __restrict__ wpk, int coutv)
{
    int i = blockIdx.x * 256 + threadIdx.x;
    int j = i & 7;
    int q = (i >> 3) & 1;
    int n = (i >> 4) & 31;
    int r = i >> 9;
    int chunk = r % 24;
    int r2 = r / 24;
    int cg = r2 % NG;
    int tap = r2 / NG;
    int co = cg * 32 + n;
    int ci = chunk * 16 + q * 8 + j;
    wpk[i] = (co < coutv) ? f2bf(w[((long)co * 384 + ci) * 9 + tap]) : (ushort_t)0;
}

// ---------------- conv48 MFMA: valid 3x3 48->46, double-buffered input staging -----------
__global__ __launch_bounds__(256) void conv48_mfma_kernel(
    const ushort_t* __restrict__ poolb, const ushort_t* __restrict__ wpk,
    float* __restrict__ out)
{
    __shared__ __align__(16) ushort_t sB[2][288 * 20];
    int b = blockIdx.z;
    int co0 = blockIdx.y * 128;
    int cgb = blockIdx.y * 4;
    int y0 = blockIdx.x * 4;
    int t = threadIdx.x;
    int w = t >> 6, lane = t & 63;
    int n = lane & 31, q = lane >> 5;
    int wc = w & 1, wn = w >> 1;
    const uint4* wq = (const uint4*)wpk;

    int pidx[3], rr[3], ccx[3];
#pragma unroll
    for (int xg = 0; xg < 3; ++xg) {
        int p = (wn * 3 + xg) * 32 + n;
        int pc = min(p, 183);
        pidx[xg] = p;
        rr[xg] = pc / 46;
        ccx[xg] = pc - rr[xg] * 46;
    }

    floatx16 acc[2][3];
#pragma unroll
    for (int a = 0; a < 2; ++a)
#pragma unroll
        for (int xg = 0; xg < 3; ++xg) acc[a][xg] = (floatx16)(0.f);

    const ushort_t* poolb_b = poolb + (long)b * 2304 * C2;

    bool sok[2]; long gof[2]; int lof[2]; bool sval[2];
#pragma unroll
    for (int s = 0; s < 2; ++s) {
        int c = t + s * 256;
        sval[s] = (c < 288);
        int cc = min(c, 287);
        int r = cc / 48, col = cc - r * 48;
        int iy = y0 + r;
        sok[s] = (iy < 48);
        gof[s] = ((long)(min(iy, 47) * 48 + col)) * C2;
        lof[s] = cc * 20;
    }
    uint4 sv[2][2];

#define C48_ISSUE(mm)                                                        \
    {                                                                        \
        int ci0 = (mm) * 16;                                                 \
        _Pragma("unroll")                                                    \
        for (int s = 0; s < 2; ++s) {                                        \
            if (sval[s] && sok[s]) {                                         \
                const ushort_t* sp = poolb_b + gof[s] + ci0;                 \
                sv[s][0] = *(const uint4*)(sp);                              \
                sv[s][1] = *(const uint4*)(sp + 8);                          \
            } else {                                                         \
                sv[s][0] = make_uint4(0u,0u,0u,0u);                          \
                sv[s][1] = make_uint4(0u,0u,0u,0u);                          \
            }                                                                \
        }                                                                    \
    }
#define C48_COMMIT(buf)                                                      \
    {                                                                        \
        _Pragma("unroll")                                                    \
        for (int s = 0; s < 2; ++s) {                                        \
            if (sval[s]) {                                                   \
                ushort_t* d = sB[buf] + lof[s];                              \
                *(uint2*)(d + 0)  = make_uint2(sv[s][0].x, sv[s][0].y);      \
                *(uint2*)(d + 4)  = make_uint2(sv[s][0].z, sv[s][0].w);      \
                *(uint2*)(d + 8)  = make_uint2(sv[s][1].x, sv[s][1].y);      \
                *(uint2*)(d + 12) = make_uint2(sv[s][1].z, sv[s][1].w);      \
            }                                                                \
        }                                                                    \
    }

    C48_ISSUE(0); C48_COMMIT(0);
    __syncthreads();

    for (int m = 0; m < 24; ++m) {
        int cur = m & 1;
        if (m < 23) C48_ISSUE(m + 1);
#pragma unroll
        for (int ky = 0; ky < 3; ++ky) {
            uint4 wv[6];
#pragma unroll
            for (int kx = 0; kx < 3; ++kx)
#pragma unroll
                for (int a = 0; a < 2; ++a)
                    wv[kx * 2 + a] = wq[(long)(((ky * 3 + kx) * 12 + cgb + wc * 2 + a) * 24 + m) * 64 + lane];
#pragma unroll
            for (int kx = 0; kx < 3; ++kx) {
                bf16x8 af[2], bfm[3];
#pragma unroll
                for (int a = 0; a < 2; ++a)
                    af[a] = __builtin_bit_cast(bf16x8, wv[kx * 2 + a]);
#pragma unroll
                for (int xg = 0; xg < 3; ++xg) {
                    int cell = (rr[xg] + ky) * 48 + ccx[xg] + kx;
                    const ushort_t* p = sB[cur] + cell * 20 + q * 8;
                    uint2 lo = *(const uint2*)(p);
                    uint2 hi = *(const uint2*)(p + 4);
                    bfm[xg] = __builtin_bit_cast(bf16x8, make_uint4(lo.x, lo.y, hi.x, hi.y));
                }
#pragma unroll
                for (int a = 0; a < 2; ++a)
#pragma unroll
                    for (int xg = 0; xg < 3; ++xg)
                        acc[a][xg] = __builtin_amdgcn_mfma_f32_32x32x16_bf16(
                            af[a], bfm[xg], acc[a][xg], 0, 0, 0);
            }
        }
        if (m < 23) C48_COMMIT(cur ^ 1);
        __syncthreads();
    }

#pragma unroll
    for (int a = 0; a < 2; ++a) {
        int cobase = co0 + (wc * 2 + a) * 32;
#pragma unroll
        for (int xg = 0; xg < 3; ++xg) {
            int oy = y0 + rr[xg], ox = ccx[xg];
            if (pidx[xg] >= 184 || oy >= 46) continue;
#pragma unroll
            for (int r = 0; r < 16; ++r) {
                int row = (r & 3) + 8 * (r >> 2) + 4 * q;
                out[((long)(b * C2 + cobase + row)) * 2116 + oy * 46 + ox] = acc[a][xg][r];
            }
        }
    }
}

// ---------------- cvt_cat: catb[b][px][ci] bf16 from cat(q=qkv2[0:192], y) ----------------
__global__ __launch_bounds__(256) void cvt_cat_kernel(
    const float* __restrict__ qkv2, const float* __restrict__ y, ushort_t* __restrict__ catb)
{
    __shared__ __align__(16) ushort_t sT[64 * 392];
    int b = blockIdx.y;
    int px0 = blockIdx.x * 64;
    int t = threadIdx.x;
    for (int idx = t; idx < 384 * 64; idx += 256) {
        int ci = idx >> 6, px = idx & 63;
        const float* src = (ci < CC) ? qkv2 + ((long)(b * C2 + ci)) * PP
                                     : y + ((long)(b * CC + ci - CC)) * PP;
        sT[px * 392 + ci] = f2bf(src[px0 + px]);
    }
    __syncthreads();
    int px = t >> 2, qr = t & 3;
    ushort_t* dst = catb + ((long)b * PP + px0 + px) * C2 + qr * 96;
    const ushort_t* srcl = sT + px * 392 + qr * 96;
#pragma unroll
    for (int k = 0; k < 96; k += 8)
        *(uint4*)(dst + k) = *(const uint4*)(srcl + k);
}

// ---------------- conv96 MFMA: 1 row/block, 1152 blocks, wave = 32co x 96px --------------
// grid (96, 3, B); block 256 (4 waves). LDS: 3 rows x 98 cols, double-buffered.
__global__ __launch_bounds__(256) void conv96_mfma_kernel(
    const ushort_t* __restrict__ catb, const ushort_t* __restrict__ wpk,
    const float* __restrict__ qkv2, const float* __restrict__ yy,
    const float* __restrict__ k2out, ushort_t* __restrict__ scb)
{
    __shared__ __align__(16) ushort_t sB[2][294 * 20];
    int b = blockIdx.z;
    int co0 = blockIdx.y * 128;
    int cgb = blockIdx.y * 4;
    int yl = blockIdx.x;                 // output row
    int t = threadIdx.x;
    int w = t >> 6, lane = t & 63;
    int n = lane & 31, q = lane >> 5;
    const uint4* wq = (const uint4*)wpk;

    floatx16 acc[3];
#pragma unroll
    for (int xg = 0; xg < 3; ++xg) acc[xg] = (floatx16)(0.f);

    const ushort_t* catb_b = catb + (long)b * PP * C2;

    // staging geometry: 294 cells = 3 rows (yl-1..yl+1) x 98 cols (x=-1..96)
    bool sok[2]; long gof[2]; int lof[2]; bool sval[2];
#pragma unroll
    for (int s = 0; s < 2; ++s) {
        int c = t + s * 256;
        sval[s] = (c < 294);
        int cc = min(c, 293);
        int r = cc / 98, col = cc - r * 98;
        int iy = yl - 1 + r, ix = col - 1;
        sok[s] = (iy >= 0 && iy < HH && ix >= 0 && ix < WW);
        gof[s] = ((long)(min(max(iy, 0), HH - 1) * WW + min(max(ix, 0), WW - 1))) * C2;
        lof[s] = cc * 20;
    }
    uint4 sv[2][2];

#define C96_ISSUE(mm)                                                        \
    {                                                                        \
        int ci0 = (mm) * 16;                                                 \
        _Pragma("unroll")                                                    \
        for (int s = 0; s < 2; ++s) {                                        \
            if (sval[s] && sok[s]) {                                         \
                const ushort_t* sp = catb_b + gof[s] + ci0;                  \
                sv[s][0] = *(const uint4*)(sp);                              \
                sv[s][1] = *(const uint4*)(sp + 8);                          \
            } else {                                                         \
                sv[s][0] = make_uint4(0u,0u,0u,0u);                          \
                sv[s][1] = make_uint4(0u,0u,0u,0u);                          \
            }                                                                \
        }                                                                    \
    }
#define C96_COMMIT(buf)                                                      \
    {                                                                        \
        _Pragma("unroll")                                                    \
        for (int s = 0; s < 2; ++s) {                                        \
            if (sval[s]) {                                                   \
                ushort_t* d = sB[buf] + lof[s];                              \
                *(uint2*)(d + 0)  = make_uint2(sv[s][0].x, sv[s][0].y);      \
                *(uint2*)(d + 4)  = make_uint2(sv[s][0].z, sv[s][0].w);      \
                *(uint2*)(d + 8)  = make_uint2(sv[s][1].x, sv[s][1].y);      \
                *(uint2*)(d + 12) = make_uint2(sv[s][1].z, sv[s][1].w);      \
            }                                                                \
        }                                                                    \
    }

    C96_ISSUE(0); C96_COMMIT(0);
    __syncthreads();

    for (int m = 0; m < 24; ++m) {
        int cur = m & 1;
        if (m < 23) C96_ISSUE(m + 1);
        // all 9 weight fragments for this wave's co-tile, one batch
        uint4 wv[9];
#pragma unroll
        for (int tap = 0; tap < 9; ++tap)
            wv[tap] = wq[(long)((tap * 12 + cgb + w) * 24 + m) * 64 + lane];
#pragma unroll
        for (int ky = 0; ky < 3; ++ky) {
#pragma unroll
            for (int kx = 0; kx < 3; ++kx) {
                bf16x8 af = __builtin_bit_cast(bf16x8, wv[ky * 3 + kx]);
#pragma unroll
                for (int xg = 0; xg < 3; ++xg) {
                    int cell = ky * 98 + xg * 32 + n + kx;
                    const ushort_t* p = sB[cur] + cell * 20 + q * 8;
                    uint2 lo = *(const uint2*)(p);
                    uint2 hi = *(const uint2*)(p + 4);
                    bf16x8 bfm = __builtin_bit_cast(bf16x8, make_uint4(lo.x, lo.y, hi.x, hi.y));
                    acc[xg] = __builtin_amdgcn_mfma_f32_32x32x16_bf16(af, bfm, acc[xg], 0, 0, 0);
                }
            }
        }
        if (m < 23) C96_COMMIT(cur ^ 1);
        __syncthreads();
    }

    // epilogue: scb[b][px][co] = bf16( acc * sigmoid(cat + nearest(k2out)) )
    int iy46 = (yl * 46) / 96;
    int cobase = co0 + w * 32;
#pragma unroll
    for (int xg = 0; xg < 3; ++xg) {
        int x = xg * 32 + n;
        int ix46 = (x * 46) / 96;
        ushort_t* dst = scb + ((long)(b * PP + yl * WW + x)) * C2;
#pragma unroll
        for (int g = 0; g < 4; ++g) {
            int cog = cobase + 8 * g + 4 * q;
            ushort_t pk[4];
#pragma unroll
            for (int j = 0; j < 4; ++j) {
                int co = cog + j;
                const float* gsrc = (co < CC) ? qkv2 + ((long)(b * C2 + co)) * PP
                                              : yy + ((long)(b * CC + co - CC)) * PP;
                float kv = k2out[((long)(b * C2 + co)) * 2116 + iy46 * 46 + ix46];
                float gg = gsrc[yl * WW + x] + kv;
                pk[j] = f2bf(acc[xg][4 * g + j] * sigmoidf_(gg));
            }
            *(uint2*)(dst + cog) = *(uint2*)pk;
        }
    }
}

// ---------------- k4 MFMA: offs = conv3x3(scb), M=32 pad, double-buffered ----------------
__global__ __launch_bounds__(384) void k4_mfma_kernel(
    const ushort_t* __restrict__ scb, const ushort_t* __restrict__ wpk4,
    float* __restrict__ out)
{
    __shared__ __align__(16) ushort_t sB[2][392 * 20];
    int b = blockIdx.y;
    int y0 = blockIdx.x * 2;
    int t = threadIdx.x;
    int w = t / 64, lane = t & 63;
    int n = lane & 31, q = lane >> 5;
    int wr = w / 3, xg = w - wr * 3;
    const uint4* wq = (const uint4*)wpk4;

    floatx16 acc = (floatx16)(0.f);
    const ushort_t* scb_b = scb + (long)b * PP * C2;

    bool sok[2]; long gof[2]; int lof[2]; bool sval[2];
#pragma unroll
    for (int s = 0; s < 2; ++s) {
        int c = t + s * 384;
        sval[s] = (c < 392);
        int cc = min(c, 391);
        int r = cc / 98, col = cc - r * 98;
        int iy = y0 - 1 + r, ix = col - 1;
        sok[s] = (iy >= 0 && iy < HH && ix >= 0 && ix < WW);
        gof[s] = ((long)(min(max(iy, 0), HH - 1) * WW + min(max(ix, 0), WW - 1))) * C2;
        lof[s] = cc * 20;
    }
    uint4 sv[2][2];

#define K4_ISSUE(mm)                                                         \
    {                                                                        \
        int ci0 = (mm) * 16;                                                 \
        _Pragma("unroll")                                                    \
        for (int s = 0; s < 2; ++s) {                                        \
            if (sval[s] && sok[s]) {                                         \
                const ushort_t* sp = scb_b + gof[s] + ci0;                   \
                sv[s][0] = *(const uint4*)(sp);                              \
                sv[s][1] = *(const uint4*)(sp + 8);                          \
            } else {                                                         \
                sv[s][0] = make_uint4(0u,0u,0u,0u);                          \
                sv[s][1] = make_uint4(0u,0u,0u,0u);                          \
            }                                                                \
        }                                                                    \
    }
#define K4_COMMIT(buf)                                                       \
    {                                                                        \
        _Pragma("unroll")                                                    \
        for (int s = 0; s < 2; ++s) {                                        \
            if (sval[s]) {                                                   \
                ushort_t* d = sB[buf] + lof[s];                              \
                *(uint2*)(d + 0)  = make_uint2(sv[s][0].x, sv[s][0].y);      \
                *(uint2*)(d + 4)  = make_uint2(sv[s][0].z, sv[s][0].w);      \
                *(uint2*)(d + 8)  = make_uint2(sv[s][1].x, sv[s][1].y);      \
                *(uint2*)(d + 12) = make_uint2(sv[s][1].z, sv[s][1].w);      \
            }                                                                \
        }                                                                    \
    }

    K4_ISSUE(0); K4_COMMIT(0);
    __syncthreads();

    for (int m = 0; m < 24; ++m) {
        int cur = m & 1;
        if (m < 23) K4_ISSUE(m + 1);
#pragma unroll
        for (int ky = 0; ky < 3; ++ky) {
            uint4 wv[3];
#pragma unroll
            for (int kx = 0; kx < 3; ++kx)
                wv[kx] = wq[(long)(((ky * 3 + kx) * 24) + m) * 64 + lane];
#pragma unroll
            for (int kx = 0; kx < 3; ++kx) {
                bf16x8 af = __builtin_bit_cast(bf16x8, wv[kx]);
                int col = xg * 32 + n + kx;
                const ushort_t* pb = sB[cur] + ((wr + ky) * 98 + col) * 20 + q * 8;
                uint2 blo = *(const uint2*)(pb);
                uint2 bhi = *(const uint2*)(pb + 4);
                bf16x8 bf = __builtin_bit_cast(bf16x8, make_uint4(blo.x, blo.y, bhi.x, bhi.y));
                acc = __builtin_amdgcn_mfma_f32_32x32x16_bf16(af, bf, acc, 0, 0, 0);
            }
        }
        if (m < 23) K4_COMMIT(cur ^ 1);
        __syncthreads();
    }

    int yl = y0 + wr;
    int x = xg * 32 + n;
#pragma unroll
    for (int r = 0; r < 16; ++r) {
        int row = (r & 3) + 8 * (r >> 2) + 4 * q;
        if (row < 18)
            out[((long)(b * 18 + row)) * PP + yl * WW + x] = acc[r];
    }
}

// ---------------- deformable conv, bf16 LDS tile from catb -------------------------------
#define DW 22
__global__ __launch_bounds__(256) void deform_kernel(
    const ushort_t* __restrict__ catb, const float* __restrict__ offs,
    const float* __restrict__ w, const float* __restrict__ bias, float* __restrict__ out)
{
    __shared__ __align__(16) ushort_t sQ[DW * DW * 24];
    int b = blockIdx.z, g = blockIdx.y;
    int tile = blockIdx.x;
    int ty0 = (tile / 6) * 16, tx0 = (tile % 6) * 16;
    int wy0 = ty0 - 3, wx0 = tx0 - 3;
    int t = threadIdx.x;
    int oy = ty0 + (t >> 4), ox = tx0 + (t & 15);
    int p = oy * WW + ox;

    const ushort_t* cb = catb + (long)b * PP * C2 + g * 24;
    for (int idx = t; idx < 484 * 3; idx += 256) {
        int cell = idx / 3, part = idx - cell * 3;
        int sy = cell / DW, sx = cell - sy * DW;
        int syc = min(max(wy0 + sy, 0), HH - 1);
        int sxc = min(max(wx0 + sx, 0), WW - 1);
        uint4 v = *(const uint4*)(cb + ((long)(syc * WW + sxc)) * C2 + part * 8);
        *(uint4*)(sQ + cell * 24 + part * 8) = v;
    }
    __syncthreads();

    const float* ob = offs + (long)b * 18 * PP;
    float acc[24];
#pragma unroll
    for (int o = 0; o < 24; ++o) acc[o] = 0.f;

    for (int k = 0; k < 9; ++k) {
        float dy = ob[(2 * k) * PP + p];
        float dx = ob[(2 * k + 1) * PP + p];
        float mk = sigmoidf_(ob[k * PP + p]);
        float py = dy + (float)(oy - 1 + k / 3);
        float px = dx + (float)(ox - 1 + (k % 3));
        float fy = floorf(py), fx = floorf(px);
        int y0 = (int)fy, x0 = (int)fx;
        float ly = py - fy, lx = px - fx;
        float w00 = (1.f - ly) * (1.f - lx), w01 = (1.f - ly) * lx;
        float w10 = ly * (1.f - lx), w11 = ly * lx;
        bool vy0 = (y0 >= 0 && y0 <= HH - 1), vy1 = (y0 + 1 <= HH - 1) && (y0 + 1 >= 0);
        bool vx0 = (x0 >= 0 && x0 <= WW - 1), vx1 = (x0 + 1 <= WW - 1) && (x0 + 1 >= 0);
        w00 = (vy0 && vx0) ? w00 * mk : 0.f;
        w01 = (vy0 && vx1) ? w01 * mk : 0.f;
        w10 = (vy1 && vx0) ? w10 * mk : 0.f;
        w11 = (vy1 && vx1) ? w11 * mk : 0.f;
        float vals[24];
        bool inwin = (y0 >= wy0) && (y0 - wy0 <= DW - 2) && (x0 >= wx0) && (x0 - wx0 <= DW - 2);
        if (inwin) {
            int c00 = (y0 - wy0) * DW + (x0 - wx0);
            const ushort_t* s00 = sQ + c00 * 24;
#pragma unroll
            for (int part = 0; part < 3; ++part) {
                uint4 A = *(const uint4*)(s00 + part * 8);
                uint4 Bv = *(const uint4*)(s00 + 24 + part * 8);
                uint4 Cv = *(const uint4*)(s00 + DW * 24 + part * 8);
                uint4 Dv = *(const uint4*)(s00 + DW * 24 + 24 + part * 8);
                const unsigned* au = (const unsigned*)&A;
                const unsigned* bu = (const unsigned*)&Bv;
                const unsigned* cu = (const unsigned*)&Cv;
                const unsigned* du = (const unsigned*)&Dv;
#pragma unroll
                for (int u = 0; u < 4; ++u) {
                    int ci = part * 8 + u * 2;
                    vals[ci]     = w00 * bflo(au[u]) + w01 * bflo(bu[u])
                                 + w10 * bflo(cu[u]) + w11 * bflo(du[u]);
                    vals[ci + 1] = w00 * bfhi(au[u]) + w01 * bfhi(bu[u])
                                 + w10 * bfhi(cu[u]) + w11 * bfhi(du[u]);
                }
            }
        } else {
            int y0c = min(max(y0, 0), HH - 1), y1c = min(max(y0 + 1, 0), HH - 1);
            int x0c = min(max(x0, 0), WW - 1), x1c = min(max(x0 + 1, 0), WW - 1);
            const ushort_t* p00 = cb + ((long)(y0c * WW + x0c)) * C2;
            const ushort_t* p01 = cb + ((long)(y0c * WW + x1c)) * C2;
            const ushort_t* p10 = cb + ((long)(y1c * WW + x0c)) * C2;
            const ushort_t* p11 = cb + ((long)(y1c * WW + x1c)) * C2;
#pragma unroll
            for (int part = 0; part < 3; ++part) {
                uint4 A = *(const uint4*)(p00 + part * 8);
                uint4 Bv = *(const uint4*)(p01 + part * 8);
                uint4 Cv = *(const uint4*)(p10 + part * 8);
                uint4 Dv = *(const uint4*)(p11 + part * 8);
                const unsigned* au = (const unsigned*)&A;
                const unsigned* bu = (const unsigned*)&Bv;
                const unsigned* cu = (const unsigned*)&Cv;
                const unsigned* du = (const unsigned*)&Dv;
#pragma unroll
                for (int u = 0; u < 4; ++u) {
                    int ci = part * 8 + u * 2;
                    vals[ci]     = w00 * bflo(au[u]) + w01 * bflo(bu[u])
                                 + w10 * bflo(cu[u]) + w11 * bflo(du[u]);
                    vals[ci + 1] = w00 * bfhi(au[u]) + w01 * bfhi(bu[u])
                                 + w10 * bfhi(cu[u]) + w11 * bfhi(du[u]);
                }
            }
        }
        const float* wg = w + (long)g * 24 * 216 + k;
#pragma unroll
        for (int o = 0; o < 24; ++o) {
            const float* wr = wg + (long)o * 216;
            float s = acc[o];
#pragma unroll
            for (int ci = 0; ci < 24; ++ci) s += wr[ci * 9] * vals[ci];
            acc[o] = s;
        }
    }
#pragma unroll
    for (int o = 0; o < 24; ++o)
        out[((long)(b * CC + g * 24 + o)) * PP + p] = acc[o] + bias[g * 24 + o];
}

// ---------------- L2 norms of q and k rows -----------------------------------------------
__global__ __launch_bounds__(256) void norm_kernel(
    const float* __restrict__ q, const float* __restrict__ kb, float* __restrict__ norms)
{
    int c = blockIdx.x, b = blockIdx.y, which = blockIdx.z;
    const float* src = (which == 0) ? q + ((long)(b * C2 + c)) * PP
                                    : kb + ((long)(b * CC + c)) * PP;
    float s = 0.f;
    for (int n = threadIdx.x * 4; n < PP; n += 1024) {
        float4 v = *(const float4*)(src + n);
        s += v.x * v.x + v.y * v.y + v.z * v.z + v.w * v.w;
    }
    __shared__ float red[256];
    red[threadIdx.x] = s;
    __syncthreads();
    for (int st = 128; st > 0; st >>= 1) {
        if (threadIdx.x < st) red[threadIdx.x] += red[threadIdx.x + st];
        __syncthreads();
    }
    if (threadIdx.x == 0)
        norms[((long)which * BB + b) * CC + c] = fmaxf(sqrtf(red[0]), 1e-12f);
}

// ---------------- attention logits + softmax ---------------------------------------------
__global__ __launch_bounds__(256) void attn_kernel(
    const float* __restrict__ q, const float* __restrict__ kb,
    const float* __restrict__ norms, const float* __restrict__ temp,
    float* __restrict__ attn)
{
    int c = blockIdx.x, h = blockIdx.y, b = blockIdx.z;
    const float* qp = q + ((long)(b * C2 + h * 24 + c)) * PP;
    const float* kbase = kb + ((long)(b * CC + h * 24)) * PP;
    float part[24];
#pragma unroll
    for (int d = 0; d < 24; ++d) part[d] = 0.f;
    for (int n = threadIdx.x * 4; n < PP; n += 1024) {
        float4 qv = *(const float4*)(qp + n);
#pragma unroll
        for (int d = 0; d < 24; ++d) {
            float4 kv = *(const float4*)(kbase + (long)d * PP + n);
            part[d] += qv.x * kv.x + qv.y * kv.y + qv.z * kv.z + qv.w * kv.w;
        }
    }
    __shared__ float lred[4][24];
    __shared__ float logits[24];
    int lane = threadIdx.x & 63, wv = threadIdx.x >> 6;
#pragma unroll
    for (int d = 0; d < 24; ++d) {
        float x = part[d];
        for (int off = 32; off > 0; off >>= 1) x += __shfl_down(x, off, 64);
        if (lane == 0) lred[wv][d] = x;
    }
    __syncthreads();
    if (threadIdx.x < 24) {
        int d = threadIdx.x;
        float tot = lred[0][d] + lred[1][d] + lred[2][d] + lred[3][d];
        float nq = norms[(long)b * CC + h * 24 + c];
        float nk = norms[(long)(BB + b) * CC + h * 24 + d];
        logits[d] = tot / (nq * nk) * temp[h];
    }
    __syncthreads();
    if (threadIdx.x < 24) {
        int d = threadIdx.x;
        float mx = -3.4e38f;
#pragma unroll
        for (int j = 0; j < 24; ++j) mx = fmaxf(mx, logits[j]);
        float sum = 0.f;
#pragma unroll
        for (int j = 0; j < 24; ++j) sum += expf(logits[j] - mx);
        attn[(((long)(b * 8 + h) * 24) + c) * 24 + d] = expf(logits[d] - mx) / sum;
    }
}

// ---------------- attn @ v ----------------------------------------------------------------
__global__ __launch_bounds__(256) void attn_apply_kernel(
    const float* __restrict__ attn, const float* __restrict__ qkv2, float* __restrict__ out)
{
    int b = blockIdx.z, ch = blockIdx.y;
    int h = ch / 24, c = ch - h * 24;
    int n = blockIdx.x * 1024 + threadIdx.x * 4;
    const float* arow = attn + (((long)(b * 8 + h) * 24) + c) * 24;
    const float* vbase = qkv2 + ((long)(b * C2) + CC + h * 24) * PP;
    float4 acc = make_float4(0.f, 0.f, 0.f, 0.f);
#pragma unroll
    for (int d = 0; d < 24; ++d) {
        float a = arow[d];
        float4 vv = *(const float4*)(vbase + (long)d * PP + n);
        acc.x += a * vv.x; acc.y += a * vv.y; acc.z += a * vv.z; acc.w += a * vv.w;
    }
    *(float4*)(out + ((long)(b * CC + ch)) * PP + n) = acc;
}

// =========================================================================================
extern "C" void kernel_launch(void* const* d_in, const int* in_sizes, int n_in,
                              void* d_out, int out_size, void* d_ws, size_t ws_size,
                              hipStream_t stream)
{
    const float* x          = (const float*)d_in[0];
    const float* y          = (const float*)d_in[1];
    const float* temp       = (const float*)d_in[2];
    const float* qkv_w      = (const float*)d_in[3];
    const float* qkv_conv_w = (const float*)d_in[4];
    const float* proj_w     = (const float*)d_in[5];
    const float* k2_w       = (const float*)d_in[6];
    const float* k3_w       = (const float*)d_in[7];
    const float* k4_w       = (const float*)d_in[8];
    const float* deform_w   = (const float*)d_in[9];
    const float* deform_b   = (const float*)d_in[10];
    const float* pw_w       = (const float*)d_in[11];
    const float* pw_b       = (const float*)d_in[12];

    float* ws = (float*)d_ws;
    const long SZ_FULL = (long)BB * C2 * PP;     // 14,155,776
    const long SZ_HALF = (long)BB * CC * PP;     //  7,077,888

    float* bufA   = ws;
    float* qkv2   = ws + SZ_FULL;
    float* k2out  = ws + 2 * SZ_FULL;
    float* ovl    = k2out + (long)BB * C2 * 2116;
    ushort_t* poolb = (ushort_t*)ovl;
    ushort_t* catb  = (ushort_t*)ovl;
    ushort_t* wbuf = (ushort_t*)(ovl + SZ_HALF);
    ushort_t* wb4  = (ushort_t*)(ovl + SZ_HALF + 663552);
    float* offs   = ovl + SZ_HALF + 663552 + 55296;
    float* norms  = offs + (long)BB * 18 * PP;
    float* attnm  = norms + 2 * BB * CC;

    float* qkv1    = bufA;
    ushort_t* wb2  = (ushort_t*)bufA;
    ushort_t* scb  = (ushort_t*)bufA;
    float* kbuf    = bufA;
    float* feat    = bufA + SZ_HALF;
    float* attnout = bufA + SZ_HALF;

    // 1. qkv = conv1x1(x, qkv_w)
    conv1x1_kernel<CC, false, false><<<dim3(9, 24, BB), 256, 0, stream>>>(
        x, qkv_w, nullptr, qkv1, (long)CC * PP, (long)C2 * PP);
    // 2. qkv = grouped 3x3 (groups=192), 4 px/thread
    dwconv_kernel<<<dim3(9, C2, BB), 256, 0, stream>>>(qkv1, qkv_conv_w, qkv2);
    // 3. poolb = bf16 px-major avgpool2(cat[q,y])   (qkv1 now dead)
    avgpool_bf16_kernel<<<dim3(36, BB), 256, 0, stream>>>(qkv2, y, poolb);
    // 4. wb2 = packed k2 weight fragments (into dead qkv1 space)
    prep_wpk_kernel<12><<<dim3(9 * 12 * 24 * 64 * 8 / 256), 256, 0, stream>>>(k2_w, wb2, 384);
    // 5. k2out = conv3x3 valid (48->46)  -- MFMA, double-buffered
    conv48_mfma_kernel<<<dim3(12, 3, BB), 256, 0, stream>>>(poolb, wb2, k2out);
    // 6. packed weight preps: k3 and k4
    prep_wpk_kernel<12><<<dim3(9 * 12 * 24 * 64 * 8 / 256), 256, 0, stream>>>(k3_w, wbuf, 384);
    prep_wpk_kernel<1><<<dim3(9 * 1 * 24 * 64 * 8 / 256), 256, 0, stream>>>(k4_w, wb4, 18);
    // 7. catb = bf16 transposed cat (overlays dead poolb; live through disp 10)
    cvt_cat_kernel<<<dim3(144, BB), 256, 0, stream>>>(qkv2, y, catb);
    // 8. scb = bf16 px-major gated conv  -- MFMA, 1152 blocks
    conv96_mfma_kernel<<<dim3(96, 3, BB), 256, 0, stream>>>(
        catb, wbuf, qkv2, y, k2out, scb);
    // 9. offset = conv3x3(scb, k4)  -- MFMA, double-buffered
    k4_mfma_kernel<<<dim3(48, BB), 384, 0, stream>>>(scb, wb4, offs);
    // 10. feat = deform_conv(q-from-catb bf16, offset, mask)
    deform_kernel<<<dim3(36, 8, BB), 256, 0, stream>>>(catb, offs, deform_w, deform_b, feat);
    // 11. k = conv1x1(relu(feat), pw_w) + pw_b
    conv1x1_kernel<CC, true, true><<<dim3(9, 12, BB), 256, 0, stream>>>(
        feat, pw_w, pw_b, kbuf, (long)CC * PP, (long)CC * PP);
    // 12. norms
    norm_kernel<<<dim3(CC, BB, 2), 256, 0, stream>>>(qkv2, kbuf, norms);
    // 13. attn
    attn_kernel<<<dim3(24, 8, BB), 256, 0, stream>>>(qkv2, kbuf, norms, temp, attnm);
    // 14. attnout = attn @ v
    attn_apply_kernel<<<dim3(9, CC, BB), 256, 0, stream>>>(attnm, qkv2, attnout);
    // 15. out = conv1x1(attnout, proj_w)
    conv1x1_kernel<CC, false, false><<<dim3(9, 12, BB), 256, 0, stream>>>(
        attnout, proj_w, nullptr, (float*)d_out, (long)CC * PP, (long)CC * PP);
}